// Round 1
// 850.826 us; speedup vs baseline: 1.2004x; 1.2004x over previous
//
#include <hip/hip_runtime.h>
#include <hip/hip_bf16.h>
#include <math.h>

typedef unsigned short u16;
typedef __attribute__((ext_vector_type(4))) float floatx4;
typedef __attribute__((ext_vector_type(8))) short shortx8;

#define DEVI static __device__ __forceinline__

DEVI float b2f(u16 u) { union { unsigned int i; float f; } v; v.i = ((unsigned int)u) << 16; return v.f; }
DEVI u16 f2b(float f) {
  union { float f; unsigned int i; } v; v.f = f;
  unsigned int x = v.i;
  return (u16)((x + 0x7fffu + ((x >> 16) & 1u)) >> 16);
}

constexpr int T_ = 1024, D_ = 1024, HD_ = 64, KV_ = 512, DH_ = 4096, M_ = 2048;
#define NEGBIG (-1e30f)

#define FMA16(ACC, A, B) \
  ACC[0][0] += A.x*B.x; ACC[0][1] += A.x*B.y; ACC[0][2] += A.x*B.z; ACC[0][3] += A.x*B.w; \
  ACC[1][0] += A.y*B.x; ACC[1][1] += A.y*B.y; ACC[1][2] += A.y*B.z; ACC[1][3] += A.y*B.w; \
  ACC[2][0] += A.z*B.x; ACC[2][1] += A.z*B.y; ACC[2][2] += A.z*B.z; ACC[2][3] += A.z*B.w; \
  ACC[3][0] += A.w*B.x; ACC[3][1] += A.w*B.y; ACC[3][2] += A.w*B.z; ACC[3][3] += A.w*B.w;

// ---------------- RMSNorm (f32 in -> f32 out) ----------------
__global__ __launch_bounds__(256) void k_rms1(const float* __restrict__ x, const float* __restrict__ w,
                                              float* __restrict__ out) {
  int row = blockIdx.x, tid = threadIdx.x;
  float4 v = *(const float4*)&x[(size_t)row * D_ + tid * 4];
  float ss = v.x*v.x + v.y*v.y + v.z*v.z + v.w*v.w;
  #pragma unroll
  for (int m = 32; m >= 1; m >>= 1) ss += __shfl_xor(ss, m, 64);
  __shared__ float red[4];
  if ((tid & 63) == 0) red[tid >> 6] = ss;
  __syncthreads();
  ss = red[0] + red[1] + red[2] + red[3];
  float sc = 1.0f / sqrtf(ss * (1.0f / 1024.0f) + 1e-6f);
  float4 wv = *(const float4*)&w[tid * 4];
  float4 o; o.x = wv.x*v.x*sc; o.y = wv.y*v.y*sc; o.z = wv.z*v.z*sc; o.w = wv.w*v.w*sc;
  *(float4*)&out[(size_t)row * D_ + tid * 4] = o;
}

// ---------------- RMSNorm (f32 in -> f32 out + bf16 out) ----------------
__global__ __launch_bounds__(256) void k_rms2b(const float* __restrict__ x, const float* __restrict__ w,
                                               float* __restrict__ outf, u16* __restrict__ outb) {
  int row = blockIdx.x, tid = threadIdx.x;
  float4 v = *(const float4*)&x[(size_t)row * D_ + tid * 4];
  float ss = v.x*v.x + v.y*v.y + v.z*v.z + v.w*v.w;
  #pragma unroll
  for (int m = 32; m >= 1; m >>= 1) ss += __shfl_xor(ss, m, 64);
  __shared__ float red[4];
  if ((tid & 63) == 0) red[tid >> 6] = ss;
  __syncthreads();
  ss = red[0] + red[1] + red[2] + red[3];
  float sc = 1.0f / sqrtf(ss * (1.0f / 1024.0f) + 1e-6f);
  float4 wv = *(const float4*)&w[tid * 4];
  float4 o; o.x = wv.x*v.x*sc; o.y = wv.y*v.y*sc; o.z = wv.z*v.z*sc; o.w = wv.w*v.w*sc;
  *(float4*)&outf[(size_t)row * D_ + tid * 4] = o;
  ushort4 ob; ob.x = f2b(o.x); ob.y = f2b(o.y); ob.z = f2b(o.z); ob.w = f2b(o.w);
  *(ushort4*)&outb[(size_t)row * D_ + tid * 4] = ob;
}

// ---------------- LayerNorm on latent (in-place, 512 cols) ----------------
__global__ __launch_bounds__(256) void k_ln(float* __restrict__ lat, const float* __restrict__ g,
                                            const float* __restrict__ bb) {
  int row = blockIdx.x, tid = threadIdx.x;
  float* r = lat + (size_t)row * KV_;
  float v0 = r[tid], v1 = r[tid + 256];
  float s = v0 + v1;
  #pragma unroll
  for (int m = 32; m >= 1; m >>= 1) s += __shfl_xor(s, m, 64);
  __shared__ float red[4];
  if ((tid & 63) == 0) red[tid >> 6] = s;
  __syncthreads();
  float mu = (red[0] + red[1] + red[2] + red[3]) * (1.0f / 512.0f);
  __syncthreads();
  float d0 = v0 - mu, d1 = v1 - mu;
  float ss = d0*d0 + d1*d1;
  #pragma unroll
  for (int m = 32; m >= 1; m >>= 1) ss += __shfl_xor(ss, m, 64);
  if ((tid & 63) == 0) red[tid >> 6] = ss;
  __syncthreads();
  float var = (red[0] + red[1] + red[2] + red[3]) * (1.0f / 512.0f);
  float sc = 1.0f / sqrtf(var + 1e-5f);
  r[tid]       = d0 * sc * g[tid]       + bb[tid];
  r[tid + 256] = d1 * sc * g[tid + 256] + bb[tid + 256];
}

// ---------------- fp32 GEMM: C[M,N] = A[M,K] @ Bw[N,K]^T (+ f32 residual) ----------------
__global__ __launch_bounds__(256) void k_gemm32(const float* __restrict__ A, const float* __restrict__ Bw,
                                                float* __restrict__ C, const float* __restrict__ resid,
                                                int N, int K) {
  __shared__ __align__(16) float As[16][68];
  __shared__ __align__(16) float Bs[16][68];
  int nb = blockIdx.x * 64, mb = blockIdx.y * 64;
  int tid = threadIdx.x, tx = tid & 15, ty = tid >> 4;
  int lr = tid >> 2, lk = (tid & 3) * 4;
  float acc[4][4] = {};
  for (int kb = 0; kb < K; kb += 16) {
    __syncthreads();
    float4 av = *(const float4*)&A[(size_t)(mb + lr) * K + kb + lk];
    float4 bv = *(const float4*)&Bw[(size_t)(nb + lr) * K + kb + lk];
    As[lk + 0][lr] = av.x; As[lk + 1][lr] = av.y; As[lk + 2][lr] = av.z; As[lk + 3][lr] = av.w;
    Bs[lk + 0][lr] = bv.x; Bs[lk + 1][lr] = bv.y; Bs[lk + 2][lr] = bv.z; Bs[lk + 3][lr] = bv.w;
    __syncthreads();
    #pragma unroll
    for (int kk = 0; kk < 16; ++kk) {
      float4 a = *(const float4*)&As[kk][ty * 4];
      float4 b = *(const float4*)&Bs[kk][tx * 4];
      FMA16(acc, a, b);
    }
  }
  #pragma unroll
  for (int i = 0; i < 4; ++i) {
    size_t base = (size_t)(mb + ty * 4 + i) * N + nb + tx * 4;
    float4 o; o.x = acc[i][0]; o.y = acc[i][1]; o.z = acc[i][2]; o.w = acc[i][3];
    if (resid) {
      float4 rv = *(const float4*)&resid[base];
      o.x += rv.x; o.y += rv.y; o.z += rv.z; o.w += rv.w;
    }
    *(float4*)&C[base] = o;
  }
}

// ---------------- RoPE (in-place on q and k, f32) ----------------
__global__ __launch_bounds__(256) void k_rope(float* __restrict__ q, float* __restrict__ k) {
  int g = blockIdx.x * 256 + threadIdx.x;
  int j = g & 31;
  int h = (g >> 5) & 15;
  int row = g >> 9;
  int t = row & (T_ - 1);
  float p = (float)pow(10000.0, (double)j * (1.0 / 32.0));
  float invf = 1.0f / p;
  float ang = (float)t * invf;
  float sn, cs; sincosf(ang, &sn, &cs);
  size_t base = (size_t)row * D_ + h * 64 + j;
  float x1 = q[base], x2 = q[base + 32];
  q[base] = x1 * cs - x2 * sn; q[base + 32] = x1 * sn + x2 * cs;
  x1 = k[base]; x2 = k[base + 32];
  k[base] = x1 * cs - x2 * sn; k[base + 32] = x1 * sn + x2 * cs;
}

// ---------------- Flash attention, fp32 register-tiled, 64-row q-tile per block ----------------
// Grid: (32 [qt x b], 16 heads). 256 threads = 16x16, each computes 4x4 of the 64x64 tiles.
// In-place: out overwrites qio. Online softmax (m, l, O) in registers.
__global__ __launch_bounds__(256) void k_fattn(float* __restrict__ qio, const float* __restrict__ kk_,
                                               const float* __restrict__ v) {
  int idx = blockIdx.x, h = blockIdx.y;
  int b = idx >> 4;
  int qt = idx & 15;
  if (b) qt = 15 - qt;  // complementary pairing: co-resident pair sums to 17 k-tiles
  __shared__ __align__(16) float Qs[64][68];  // [d][q], pre-scaled by 1/8
  __shared__ __align__(16) float Ks[64][68];  // [d][k]
  __shared__ __align__(16) float Vs[64][68];  // [k][vd]
  __shared__ __align__(16) float Ps[64][68];  // [k][q]  (P^T)
  int tid = threadIdx.x, tx = tid & 15, ty = tid >> 4;
  size_t rowbase = (size_t)b * T_;
  int colbase = h * HD_;
  int q0 = qt * 64;
  int lr = tid >> 2, ld = (tid & 3) * 16;
  {
    const float* qr = qio + (rowbase + q0 + lr) * D_ + colbase + ld;
    #pragma unroll
    for (int c = 0; c < 16; c += 4) {
      float4 t4 = *(const float4*)&qr[c];
      Qs[ld + c + 0][lr] = t4.x * 0.125f;
      Qs[ld + c + 1][lr] = t4.y * 0.125f;
      Qs[ld + c + 2][lr] = t4.z * 0.125f;
      Qs[ld + c + 3][lr] = t4.w * 0.125f;
    }
  }
  float m[4], l[4], O[4][4];
  #pragma unroll
  for (int i = 0; i < 4; ++i) {
    m[i] = NEGBIG; l[i] = 0.f;
    O[i][0] = O[i][1] = O[i][2] = O[i][3] = 0.f;
  }
  for (int kt = 0; kt <= qt; ++kt) {
    __syncthreads();  // prev PV done (Ks/Vs/Ps free), Q staged on first iter
    {
      const float* kr = kk_ + (rowbase + kt * 64 + lr) * D_ + colbase + ld;
      const float* vr = v   + (rowbase + kt * 64 + lr) * D_ + colbase + ld;
      #pragma unroll
      for (int c = 0; c < 16; c += 4) {
        float4 t4 = *(const float4*)&kr[c];
        Ks[ld + c + 0][lr] = t4.x; Ks[ld + c + 1][lr] = t4.y;
        Ks[ld + c + 2][lr] = t4.z; Ks[ld + c + 3][lr] = t4.w;
        float4 v4 = *(const float4*)&vr[c];
        *(float4*)&Vs[lr][ld + c] = v4;
      }
    }
    __syncthreads();
    float S[4][4] = {};
    #pragma unroll 8
    for (int d = 0; d < 64; ++d) {
      float4 a = *(const float4*)&Qs[d][ty * 4];
      float4 bb4 = *(const float4*)&Ks[d][tx * 4];
      FMA16(S, a, bb4);
    }
    if (kt == qt) {  // diagonal tile: q0 == kt*64 so mask is local-index compare
      #pragma unroll
      for (int i = 0; i < 4; ++i)
        #pragma unroll
        for (int j = 0; j < 4; ++j)
          if (tx * 4 + j > ty * 4 + i) S[i][j] = NEGBIG;
    }
    // online softmax update (per q-row i, reduce across the 16 tx lanes)
    #pragma unroll
    for (int i = 0; i < 4; ++i) {
      float tm = fmaxf(fmaxf(S[i][0], S[i][1]), fmaxf(S[i][2], S[i][3]));
      #pragma unroll
      for (int mk = 8; mk >= 1; mk >>= 1) tm = fmaxf(tm, __shfl_xor(tm, mk, 64));
      float mn = fmaxf(m[i], tm);
      float f = __expf(m[i] - mn);
      m[i] = mn;
      float rs = 0.f;
      #pragma unroll
      for (int j = 0; j < 4; ++j) {
        float p = __expf(S[i][j] - mn);
        S[i][j] = p; rs += p;
      }
      #pragma unroll
      for (int mk = 8; mk >= 1; mk >>= 1) rs += __shfl_xor(rs, mk, 64);
      l[i] = l[i] * f + rs;
      O[i][0] *= f; O[i][1] *= f; O[i][2] *= f; O[i][3] *= f;
      #pragma unroll
      for (int j = 0; j < 4; ++j) Ps[tx * 4 + j][ty * 4 + i] = S[i][j];  // P^T
    }
    __syncthreads();
    #pragma unroll 8
    for (int kkk = 0; kkk < 64; ++kkk) {
      float4 a = *(const float4*)&Ps[kkk][ty * 4];
      float4 bb4 = *(const float4*)&Vs[kkk][tx * 4];
      FMA16(O, a, bb4);
    }
  }
  #pragma unroll
  for (int i = 0; i < 4; ++i) {
    float inv = 1.0f / l[i];
    float4 o;
    o.x = O[i][0] * inv; o.y = O[i][1] * inv; o.z = O[i][2] * inv; o.w = O[i][3] * inv;
    *(float4*)&qio[(rowbase + q0 + ty * 4 + i) * D_ + colbase + tx * 4] = o;
  }
}

// ---------------- MoE gate ----------------
__global__ __launch_bounds__(256) void k_init(int* cnt) { if (threadIdx.x < 4) cnt[threadIdx.x] = 0; }

__global__ __launch_bounds__(256) void k_gate(const float* __restrict__ h2, const float* __restrict__ gw,
                                              const float* __restrict__ gb, int* __restrict__ expert,
                                              int* __restrict__ cnt) {
  int wid = threadIdx.x >> 6, lane = threadIdx.x & 63;
  int t = blockIdx.x * 4 + wid;
  const float* hr = h2 + (size_t)t * D_;
  float a0 = 0, a1 = 0, a2 = 0, a3 = 0;
  for (int c = lane; c < D_; c += 64) {
    float xv = hr[c];
    a0 += xv * gw[c];
    a1 += xv * gw[D_ + c];
    a2 += xv * gw[2 * D_ + c];
    a3 += xv * gw[3 * D_ + c];
  }
  #pragma unroll
  for (int m = 32; m >= 1; m >>= 1) {
    a0 += __shfl_xor(a0, m, 64); a1 += __shfl_xor(a1, m, 64);
    a2 += __shfl_xor(a2, m, 64); a3 += __shfl_xor(a3, m, 64);
  }
  if (lane == 0) {
    float l0 = a0 + gb[0], l1 = a1 + gb[1], l2 = a2 + gb[2], l3 = a3 + gb[3];
    int best = 0; float bv = l0;
    if (l1 > bv) { bv = l1; best = 1; }
    if (l2 > bv) { bv = l2; best = 2; }
    if (l3 > bv) { bv = l3; best = 3; }
    expert[t] = best;
    atomicAdd(&cnt[best], 1);
  }
}

__global__ __launch_bounds__(256) void k_scatter(const int* __restrict__ expert, const int* __restrict__ cnt,
                                                 int* __restrict__ off, int* __restrict__ sorted) {
  __shared__ int cur[4];
  if (threadIdx.x == 0) {
    int o0 = 0, o1 = cnt[0], o2 = o1 + cnt[1], o3 = o2 + cnt[2];
    off[0] = o0; off[1] = o1; off[2] = o2; off[3] = o3;
    cur[0] = o0; cur[1] = o1; cur[2] = o2; cur[3] = o3;
  }
  __syncthreads();
  for (int t = threadIdx.x; t < M_; t += 256) {
    int e = expert[t];
    int p = atomicAdd(&cur[e], 1);
    sorted[p] = t;
  }
}

// ---------------- MoE MFMA GEMM 1: hbuf = bf16(relu(h2b[gather] @ W1[e]^T + b1[e])) ----------------
__global__ __launch_bounds__(256) void k_moe1(const u16* __restrict__ A, const float* __restrict__ W1,
                                              const float* __restrict__ b1, const int* __restrict__ cnt,
                                              const int* __restrict__ off, const int* __restrict__ sorted,
                                              u16* __restrict__ hbuf) {
  int e = blockIdx.z, mt = blockIdx.y, nt = blockIdx.x;
  int rem = cnt[e] - mt * 64;
  if (rem <= 0) return;
  __shared__ __align__(16) u16 As[64][72];
  __shared__ __align__(16) u16 Bs[64][72];
  int tid = threadIdx.x, lane = tid & 63, wave = tid >> 6;
  int wm = (wave >> 1) * 32, wn = (wave & 1) * 32;
  int lr = tid >> 2, lc = (tid & 3) * 16;
  int rr = lr < rem ? lr : rem - 1;
  const u16* arow = A + (size_t)sorted[off[e] + mt * 64 + rr] * D_;
  const float* brow = W1 + (size_t)e * DH_ * D_ + (size_t)(nt * 64 + lr) * D_;
  floatx4 z = {0.f, 0.f, 0.f, 0.f};
  floatx4 acc00 = z, acc01 = z, acc10 = z, acc11 = z;
  int fm = lane & 15, fkq = (lane >> 4) * 8;
  for (int kb = 0; kb < D_; kb += 64) {
    __syncthreads();
    *(uint4*)&As[lr][lc]     = *(const uint4*)&arow[kb + lc];
    *(uint4*)&As[lr][lc + 8] = *(const uint4*)&arow[kb + lc + 8];
    #pragma unroll
    for (int c = 0; c < 16; c += 4) {
      float4 f = *(const float4*)&brow[kb + lc + c];
      ushort4 u; u.x = f2b(f.x); u.y = f2b(f.y); u.z = f2b(f.z); u.w = f2b(f.w);
      *(ushort4*)&Bs[lr][lc + c] = u;
    }
    __syncthreads();
    #pragma unroll
    for (int ks = 0; ks < 64; ks += 32) {
      shortx8 a0  = *(const shortx8*)&As[wm + fm][ks + fkq];
      shortx8 a1  = *(const shortx8*)&As[wm + 16 + fm][ks + fkq];
      shortx8 b0  = *(const shortx8*)&Bs[wn + fm][ks + fkq];
      shortx8 b1v = *(const shortx8*)&Bs[wn + 16 + fm][ks + fkq];
      acc00 = __builtin_amdgcn_mfma_f32_16x16x32_bf16(a0, b0,  acc00, 0, 0, 0);
      acc01 = __builtin_amdgcn_mfma_f32_16x16x32_bf16(a0, b1v, acc01, 0, 0, 0);
      acc10 = __builtin_amdgcn_mfma_f32_16x16x32_bf16(a1, b0,  acc10, 0, 0, 0);
      acc11 = __builtin_amdgcn_mfma_f32_16x16x32_bf16(a1, b1v, acc11, 0, 0, 0);
    }
  }
  int q4 = (lane >> 4) * 4, cix = lane & 15;
  #pragma unroll
  for (int im = 0; im < 2; ++im) {
    #pragma unroll
    for (int rg = 0; rg < 4; ++rg) {
      int ml = wm + im * 16 + q4 + rg;
      if (ml >= rem) continue;
      size_t grow = (size_t)(off[e] + mt * 64 + ml);
      #pragma unroll
      for (int in = 0; in < 2; ++in) {
        int gn = nt * 64 + wn + in * 16 + cix;
        float vv = (im == 0 ? (in == 0 ? acc00[rg] : acc01[rg]) : (in == 0 ? acc10[rg] : acc11[rg]));
        vv += b1[e * DH_ + gn];
        hbuf[grow * DH_ + gn] = f2b(fmaxf(vv, 0.f));
      }
    }
  }
}

// ---------------- MoE MFMA GEMM 2: out_f32 = x1 + hbuf @ W2[e]^T + b2[e] ----------------
__global__ __launch_bounds__(256) void k_moe2(const u16* __restrict__ hbuf, const float* __restrict__ W2,
                                              const float* __restrict__ b2w, const float* __restrict__ x1f,
                                              const int* __restrict__ cnt, const int* __restrict__ off,
                                              const int* __restrict__ sorted, float* __restrict__ out) {
  int e = blockIdx.z, mt = blockIdx.y, nt = blockIdx.x;
  int rem = cnt[e] - mt * 64;
  if (rem <= 0) return;
  __shared__ __align__(16) u16 As[64][72];
  __shared__ __align__(16) u16 Bs[64][72];
  int tid = threadIdx.x, lane = tid & 63, wave = tid >> 6;
  int wm = (wave >> 1) * 32, wn = (wave & 1) * 32;
  int lr = tid >> 2, lc = (tid & 3) * 16;
  int rr = lr < rem ? lr : rem - 1;
  const u16* arow = hbuf + (size_t)(off[e] + mt * 64 + rr) * DH_;
  const float* brow = W2 + (size_t)e * D_ * DH_ + (size_t)(nt * 64 + lr) * DH_;
  floatx4 z = {0.f, 0.f, 0.f, 0.f};
  floatx4 acc00 = z, acc01 = z, acc10 = z, acc11 = z;
  int fm = lane & 15, fkq = (lane >> 4) * 8;
  for (int kb = 0; kb < DH_; kb += 64) {
    __syncthreads();
    *(uint4*)&As[lr][lc]     = *(const uint4*)&arow[kb + lc];
    *(uint4*)&As[lr][lc + 8] = *(const uint4*)&arow[kb + lc + 8];
    #pragma unroll
    for (int c = 0; c < 16; c += 4) {
      float4 f = *(const float4*)&brow[kb + lc + c];
      ushort4 u; u.x = f2b(f.x); u.y = f2b(f.y); u.z = f2b(f.z); u.w = f2b(f.w);
      *(ushort4*)&Bs[lr][lc + c] = u;
    }
    __syncthreads();
    #pragma unroll
    for (int ks = 0; ks < 64; ks += 32) {
      shortx8 a0  = *(const shortx8*)&As[wm + fm][ks + fkq];
      shortx8 a1  = *(const shortx8*)&As[wm + 16 + fm][ks + fkq];
      shortx8 b0  = *(const shortx8*)&Bs[wn + fm][ks + fkq];
      shortx8 b1v = *(const shortx8*)&Bs[wn + 16 + fm][ks + fkq];
      acc00 = __builtin_amdgcn_mfma_f32_16x16x32_bf16(a0, b0,  acc00, 0, 0, 0);
      acc01 = __builtin_amdgcn_mfma_f32_16x16x32_bf16(a0, b1v, acc01, 0, 0, 0);
      acc10 = __builtin_amdgcn_mfma_f32_16x16x32_bf16(a1, b0,  acc10, 0, 0, 0);
      acc11 = __builtin_amdgcn_mfma_f32_16x16x32_bf16(a1, b1v, acc11, 0, 0, 0);
    }
  }
  int q4 = (lane >> 4) * 4, cix = lane & 15;
  #pragma unroll
  for (int im = 0; im < 2; ++im) {
    #pragma unroll
    for (int rg = 0; rg < 4; ++rg) {
      int ml = wm + im * 16 + q4 + rg;
      if (ml >= rem) continue;
      int tok = sorted[off[e] + mt * 64 + ml];
      #pragma unroll
      for (int in = 0; in < 2; ++in) {
        int gn = nt * 64 + wn + in * 16 + cix;
        float vv = (im == 0 ? (in == 0 ? acc00[rg] : acc01[rg]) : (in == 0 ? acc10[rg] : acc11[rg]));
        out[(size_t)tok * D_ + gn] = vv + b2w[e * D_ + gn] + x1f[(size_t)tok * D_ + gn];
      }
    }
  }
}

extern "C" void kernel_launch(void* const* d_in, const int* in_sizes, int n_in,
                              void* d_out, int out_size, void* d_ws, size_t ws_size,
                              hipStream_t stream) {
  int map[16];
  for (int i = 0; i < 16; ++i) map[i] = i;
  if (n_in == 16 && in_sizes[0] == 16777216) {
    const int mm[16] = {15, 13, 14, 4, 2, 5, 6, 3, 12, 11, 10, 9, 0, 7, 1, 8};
    for (int i = 0; i < 16; ++i) map[i] = mm[i];
  } else if (n_in == 16 && in_sizes[0] == 4096) {
    for (int i = 0; i < 16; ++i) map[i] = 15 - i;
  }
  const float* x    = (const float*)d_in[map[0]];
  const float* n1w  = (const float*)d_in[map[1]];
  const float* n2w  = (const float*)d_in[map[2]];
  const float* Wq   = (const float*)d_in[map[3]];
  const float* Wdkv = (const float*)d_in[map[4]];
  const float* Wuk  = (const float*)d_in[map[5]];
  const float* Wuv  = (const float*)d_in[map[6]];
  const float* Wo   = (const float*)d_in[map[7]];
  const float* lng  = (const float*)d_in[map[8]];
  const float* lnb  = (const float*)d_in[map[9]];
  const float* gw   = (const float*)d_in[map[10]];
  const float* gb   = (const float*)d_in[map[11]];
  const float* W1   = (const float*)d_in[map[12]];
  const float* b1   = (const float*)d_in[map[13]];
  const float* W2   = (const float*)d_in[map[14]];
  const float* b2w  = (const float*)d_in[map[15]];
  float* out = (float*)d_out;
  char* ws = (char*)d_ws;
  const size_t MB = 1ull << 20;
  // Overlay layout, peak 36MB + 20KB:
  //  A [0,8)  : h1f (rms1 -> Wq,Wdkv) -> kf (Wuk -> rope -> attn) -> hbuf.lo (moe1 -> moe2)
  //  B [8,16) : qf (Wq -> rope -> attn in-place -> Wo gemm)       -> hbuf.hi
  //  C [16,24): vf (Wuv -> attn)                                  -> h2f (rms2 -> gate)
  //  D [24,32): x1f (Wo out + resid x; residual for moe2, live to end)
  //  E [32,36): latf (Wdkv -> ln -> Wuk,Wuv)                      -> h2b bf16 (rms2 -> moe1)
  float* h1f  = (float*)(ws + 0);
  float* kf   = (float*)(ws + 0);
  u16*   hbuf = (u16*)(ws + 0);            // 16MB: [0,16)
  float* qf   = (float*)(ws + 8 * MB);
  float* vf   = (float*)(ws + 16 * MB);
  float* h2f  = (float*)(ws + 16 * MB);
  float* x1f  = (float*)(ws + 24 * MB);
  float* latf = (float*)(ws + 32 * MB);
  u16*   h2b  = (u16*)(ws + 32 * MB);
  int*   cnt    = (int*)(ws + 36 * MB);
  int*   off    = cnt + 8;
  int*   expert = cnt + 16;
  int*   sorted = expert + 2048;

  k_rms1<<<2048, 256, 0, stream>>>(x, n1w, h1f);
  k_gemm32<<<dim3(16, 32), 256, 0, stream>>>(h1f, Wq, qf, nullptr, 1024, 1024);
  k_gemm32<<<dim3(8, 32), 256, 0, stream>>>(h1f, Wdkv, latf, nullptr, 512, 1024);
  k_ln<<<2048, 256, 0, stream>>>(latf, lng, lnb);
  k_gemm32<<<dim3(16, 32), 256, 0, stream>>>(latf, Wuk, kf, nullptr, 1024, 512);
  k_gemm32<<<dim3(16, 32), 256, 0, stream>>>(latf, Wuv, vf, nullptr, 1024, 512);
  k_rope<<<4096, 256, 0, stream>>>(qf, kf);
  k_fattn<<<dim3(32, 16), 256, 0, stream>>>(qf, kf, vf);
  k_gemm32<<<dim3(16, 32), 256, 0, stream>>>(qf, Wo, x1f, x, 1024, 1024);
  k_rms2b<<<2048, 256, 0, stream>>>(x1f, n2w, h2f, h2b);
  k_init<<<1, 64, 0, stream>>>(cnt);
  k_gate<<<512, 256, 0, stream>>>(h2f, gw, gb, expert, cnt);
  k_scatter<<<1, 256, 0, stream>>>(expert, cnt, off, sorted);
  k_moe1<<<dim3(64, 32, 4), 256, 0, stream>>>(h2b, W1, b1, cnt, off, sorted, hbuf);
  k_moe2<<<dim3(16, 32, 4), 256, 0, stream>>>(hbuf, W2, b2w, x1f, cnt, off, sorted, out);
}

// Round 2
// 648.994 us; speedup vs baseline: 1.5737x; 1.3110x over previous
//
#include <hip/hip_runtime.h>
#include <hip/hip_bf16.h>
#include <math.h>

typedef unsigned short u16;
typedef __attribute__((ext_vector_type(4))) float floatx4;
typedef __attribute__((ext_vector_type(8))) short shortx8;

#define DEVI static __device__ __forceinline__

DEVI float b2f(u16 u) { union { unsigned int i; float f; } v; v.i = ((unsigned int)u) << 16; return v.f; }
DEVI u16 f2b(float f) {
  union { float f; unsigned int i; } v; v.f = f;
  unsigned int x = v.i;
  return (u16)((x + 0x7fffu + ((x >> 16) & 1u)) >> 16);
}

constexpr int T_ = 1024, D_ = 1024, HD_ = 64, KV_ = 512, DH_ = 4096, M_ = 2048;
#define NEGBIG (-1e30f)

#define FMA16(ACC, A, B) \
  ACC[0][0] += A.x*B.x; ACC[0][1] += A.x*B.y; ACC[0][2] += A.x*B.z; ACC[0][3] += A.x*B.w; \
  ACC[1][0] += A.y*B.x; ACC[1][1] += A.y*B.y; ACC[1][2] += A.y*B.z; ACC[1][3] += A.y*B.w; \
  ACC[2][0] += A.z*B.x; ACC[2][1] += A.z*B.y; ACC[2][2] += A.z*B.z; ACC[2][3] += A.z*B.w; \
  ACC[3][0] += A.w*B.x; ACC[3][1] += A.w*B.y; ACC[3][2] += A.w*B.z; ACC[3][3] += A.w*B.w;

// ---------------- RMSNorm (f32 in -> bf16 out) ----------------
__global__ __launch_bounds__(256) void k_rms1b(const float* __restrict__ x, const float* __restrict__ w,
                                               u16* __restrict__ outb) {
  int row = blockIdx.x, tid = threadIdx.x;
  float4 v = *(const float4*)&x[(size_t)row * D_ + tid * 4];
  float ss = v.x*v.x + v.y*v.y + v.z*v.z + v.w*v.w;
  #pragma unroll
  for (int m = 32; m >= 1; m >>= 1) ss += __shfl_xor(ss, m, 64);
  __shared__ float red[4];
  if ((tid & 63) == 0) red[tid >> 6] = ss;
  __syncthreads();
  ss = red[0] + red[1] + red[2] + red[3];
  float sc = 1.0f / sqrtf(ss * (1.0f / 1024.0f) + 1e-6f);
  float4 wv = *(const float4*)&w[tid * 4];
  ushort4 ob;
  ob.x = f2b(wv.x*v.x*sc); ob.y = f2b(wv.y*v.y*sc);
  ob.z = f2b(wv.z*v.z*sc); ob.w = f2b(wv.w*v.w*sc);
  *(ushort4*)&outb[(size_t)row * D_ + tid * 4] = ob;
}

// ---------------- RMSNorm (f32 in -> f32 out + bf16 out) ----------------
__global__ __launch_bounds__(256) void k_rms2b(const float* __restrict__ x, const float* __restrict__ w,
                                               float* __restrict__ outf, u16* __restrict__ outb) {
  int row = blockIdx.x, tid = threadIdx.x;
  float4 v = *(const float4*)&x[(size_t)row * D_ + tid * 4];
  float ss = v.x*v.x + v.y*v.y + v.z*v.z + v.w*v.w;
  #pragma unroll
  for (int m = 32; m >= 1; m >>= 1) ss += __shfl_xor(ss, m, 64);
  __shared__ float red[4];
  if ((tid & 63) == 0) red[tid >> 6] = ss;
  __syncthreads();
  ss = red[0] + red[1] + red[2] + red[3];
  float sc = 1.0f / sqrtf(ss * (1.0f / 1024.0f) + 1e-6f);
  float4 wv = *(const float4*)&w[tid * 4];
  float4 o; o.x = wv.x*v.x*sc; o.y = wv.y*v.y*sc; o.z = wv.z*v.z*sc; o.w = wv.w*v.w*sc;
  *(float4*)&outf[(size_t)row * D_ + tid * 4] = o;
  ushort4 ob; ob.x = f2b(o.x); ob.y = f2b(o.y); ob.z = f2b(o.z); ob.w = f2b(o.w);
  *(ushort4*)&outb[(size_t)row * D_ + tid * 4] = ob;
}

// ---------------- LayerNorm on latent (f32 in -> bf16 out, 512 cols) ----------------
__global__ __launch_bounds__(256) void k_lnb(const float* __restrict__ lat, const float* __restrict__ g,
                                             const float* __restrict__ bb, u16* __restrict__ ob) {
  int row = blockIdx.x, tid = threadIdx.x;
  const float* r = lat + (size_t)row * KV_;
  float v0 = r[tid], v1 = r[tid + 256];
  float s = v0 + v1;
  #pragma unroll
  for (int m = 32; m >= 1; m >>= 1) s += __shfl_xor(s, m, 64);
  __shared__ float red[4];
  if ((tid & 63) == 0) red[tid >> 6] = s;
  __syncthreads();
  float mu = (red[0] + red[1] + red[2] + red[3]) * (1.0f / 512.0f);
  __syncthreads();
  float d0 = v0 - mu, d1 = v1 - mu;
  float ss = d0*d0 + d1*d1;
  #pragma unroll
  for (int m = 32; m >= 1; m >>= 1) ss += __shfl_xor(ss, m, 64);
  if ((tid & 63) == 0) red[tid >> 6] = ss;
  __syncthreads();
  float var = (red[0] + red[1] + red[2] + red[3]) * (1.0f / 512.0f);
  float sc = 1.0f / sqrtf(var + 1e-5f);
  ob[(size_t)row * KV_ + tid]       = f2b(d0 * sc * g[tid]       + bb[tid]);
  ob[(size_t)row * KV_ + tid + 256] = f2b(d1 * sc * g[tid + 256] + bb[tid + 256]);
}

// ---------------- bf16 MFMA GEMM: C_f32[M,N] = A_bf16[M,K] @ Bw_f32[N,K]^T (+resid) ----------------
// Same proven structure as k_moe1 (64x64 tile, 4 waves in 2x2 quadrants of 32x32).
__global__ __launch_bounds__(256) void k_gemmbf(const u16* __restrict__ A, const float* __restrict__ Bw,
                                                const float* __restrict__ resid, float* __restrict__ C,
                                                int N, int K) {
  int nt = blockIdx.x, mt = blockIdx.y;
  __shared__ __align__(16) u16 As[64][72];
  __shared__ __align__(16) u16 Bs[64][72];
  int tid = threadIdx.x, lane = tid & 63, wave = tid >> 6;
  int wm = (wave >> 1) * 32, wn = (wave & 1) * 32;
  int lr = tid >> 2, lc = (tid & 3) * 16;
  const u16* arow = A + (size_t)(mt * 64 + lr) * K;
  const float* brow = Bw + (size_t)(nt * 64 + lr) * K;
  floatx4 z = {0.f, 0.f, 0.f, 0.f};
  floatx4 acc00 = z, acc01 = z, acc10 = z, acc11 = z;
  int fm = lane & 15, fkq = (lane >> 4) * 8;
  for (int kb = 0; kb < K; kb += 64) {
    __syncthreads();
    *(uint4*)&As[lr][lc]     = *(const uint4*)&arow[kb + lc];
    *(uint4*)&As[lr][lc + 8] = *(const uint4*)&arow[kb + lc + 8];
    #pragma unroll
    for (int c = 0; c < 16; c += 4) {
      float4 f = *(const float4*)&brow[kb + lc + c];
      ushort4 u; u.x = f2b(f.x); u.y = f2b(f.y); u.z = f2b(f.z); u.w = f2b(f.w);
      *(ushort4*)&Bs[lr][lc + c] = u;
    }
    __syncthreads();
    #pragma unroll
    for (int ks = 0; ks < 64; ks += 32) {
      shortx8 a0  = *(const shortx8*)&As[wm + fm][ks + fkq];
      shortx8 a1  = *(const shortx8*)&As[wm + 16 + fm][ks + fkq];
      shortx8 b0  = *(const shortx8*)&Bs[wn + fm][ks + fkq];
      shortx8 b1v = *(const shortx8*)&Bs[wn + 16 + fm][ks + fkq];
      acc00 = __builtin_amdgcn_mfma_f32_16x16x32_bf16(a0, b0,  acc00, 0, 0, 0);
      acc01 = __builtin_amdgcn_mfma_f32_16x16x32_bf16(a0, b1v, acc01, 0, 0, 0);
      acc10 = __builtin_amdgcn_mfma_f32_16x16x32_bf16(a1, b0,  acc10, 0, 0, 0);
      acc11 = __builtin_amdgcn_mfma_f32_16x16x32_bf16(a1, b1v, acc11, 0, 0, 0);
    }
  }
  int q4 = (lane >> 4) * 4, cix = lane & 15;
  #pragma unroll
  for (int im = 0; im < 2; ++im) {
    #pragma unroll
    for (int rg = 0; rg < 4; ++rg) {
      int row = mt * 64 + wm + im * 16 + q4 + rg;
      #pragma unroll
      for (int in = 0; in < 2; ++in) {
        int gn = nt * 64 + wn + in * 16 + cix;
        float vv = (im == 0 ? (in == 0 ? acc00[rg] : acc01[rg]) : (in == 0 ? acc10[rg] : acc11[rg]));
        size_t idx = (size_t)row * N + gn;
        if (resid) vv += resid[idx];
        C[idx] = vv;
      }
    }
  }
}

// ---------------- RoPE (in-place on q and k, f32) ----------------
__global__ __launch_bounds__(256) void k_rope(float* __restrict__ q, float* __restrict__ k) {
  int g = blockIdx.x * 256 + threadIdx.x;
  int j = g & 31;
  int h = (g >> 5) & 15;
  int row = g >> 9;
  int t = row & (T_ - 1);
  float p = (float)pow(10000.0, (double)j * (1.0 / 32.0));
  float invf = 1.0f / p;
  float ang = (float)t * invf;
  float sn, cs; sincosf(ang, &sn, &cs);
  size_t base = (size_t)row * D_ + h * 64 + j;
  float x1 = q[base], x2 = q[base + 32];
  q[base] = x1 * cs - x2 * sn; q[base + 32] = x1 * sn + x2 * cs;
  x1 = k[base]; x2 = k[base + 32];
  k[base] = x1 * cs - x2 * sn; k[base + 32] = x1 * sn + x2 * cs;
}

// ---------------- Flash attention, fp32 register-tiled, 64-row q-tile per block ----------------
// Grid: (32 [qt x b], 16 heads). 256 threads = 16x16, each computes 4x4 of the 64x64 tiles.
// Output written as bf16 (consumed only as A-operand of Wo GEMM).
__global__ __launch_bounds__(256) void k_fattn(const float* __restrict__ qin, const float* __restrict__ kk_,
                                               const float* __restrict__ v, u16* __restrict__ ob) {
  int idx = blockIdx.x, h = blockIdx.y;
  int b = idx >> 4;
  int qt = idx & 15;
  if (b) qt = 15 - qt;  // complementary pairing: co-resident pair sums to 17 k-tiles
  __shared__ __align__(16) float Qs[64][68];  // [d][q], pre-scaled by 1/8
  __shared__ __align__(16) float Ks[64][68];  // [d][k]
  __shared__ __align__(16) float Vs[64][68];  // [k][vd]
  __shared__ __align__(16) float Ps[64][68];  // [k][q]  (P^T)
  int tid = threadIdx.x, tx = tid & 15, ty = tid >> 4;
  size_t rowbase = (size_t)b * T_;
  int colbase = h * HD_;
  int q0 = qt * 64;
  int lr = tid >> 2, ld = (tid & 3) * 16;
  {
    const float* qr = qin + (rowbase + q0 + lr) * D_ + colbase + ld;
    #pragma unroll
    for (int c = 0; c < 16; c += 4) {
      float4 t4 = *(const float4*)&qr[c];
      Qs[ld + c + 0][lr] = t4.x * 0.125f;
      Qs[ld + c + 1][lr] = t4.y * 0.125f;
      Qs[ld + c + 2][lr] = t4.z * 0.125f;
      Qs[ld + c + 3][lr] = t4.w * 0.125f;
    }
  }
  float m[4], l[4], O[4][4];
  #pragma unroll
  for (int i = 0; i < 4; ++i) {
    m[i] = NEGBIG; l[i] = 0.f;
    O[i][0] = O[i][1] = O[i][2] = O[i][3] = 0.f;
  }
  for (int kt = 0; kt <= qt; ++kt) {
    __syncthreads();  // prev PV done (Ks/Vs/Ps free), Q staged on first iter
    {
      const float* kr = kk_ + (rowbase + kt * 64 + lr) * D_ + colbase + ld;
      const float* vr = v   + (rowbase + kt * 64 + lr) * D_ + colbase + ld;
      #pragma unroll
      for (int c = 0; c < 16; c += 4) {
        float4 t4 = *(const float4*)&kr[c];
        Ks[ld + c + 0][lr] = t4.x; Ks[ld + c + 1][lr] = t4.y;
        Ks[ld + c + 2][lr] = t4.z; Ks[ld + c + 3][lr] = t4.w;
        float4 v4 = *(const float4*)&vr[c];
        *(float4*)&Vs[lr][ld + c] = v4;
      }
    }
    __syncthreads();
    float S[4][4] = {};
    #pragma unroll 8
    for (int d = 0; d < 64; ++d) {
      float4 a = *(const float4*)&Qs[d][ty * 4];
      float4 bb4 = *(const float4*)&Ks[d][tx * 4];
      FMA16(S, a, bb4);
    }
    if (kt == qt) {  // diagonal tile: q0 == kt*64 so mask is local-index compare
      #pragma unroll
      for (int i = 0; i < 4; ++i)
        #pragma unroll
        for (int j = 0; j < 4; ++j)
          if (tx * 4 + j > ty * 4 + i) S[i][j] = NEGBIG;
    }
    // online softmax update (per q-row i, reduce across the 16 tx lanes)
    #pragma unroll
    for (int i = 0; i < 4; ++i) {
      float tm = fmaxf(fmaxf(S[i][0], S[i][1]), fmaxf(S[i][2], S[i][3]));
      #pragma unroll
      for (int mk = 8; mk >= 1; mk >>= 1) tm = fmaxf(tm, __shfl_xor(tm, mk, 64));
      float mn = fmaxf(m[i], tm);
      float f = __expf(m[i] - mn);
      m[i] = mn;
      float rs = 0.f;
      #pragma unroll
      for (int j = 0; j < 4; ++j) {
        float p = __expf(S[i][j] - mn);
        S[i][j] = p; rs += p;
      }
      #pragma unroll
      for (int mk = 8; mk >= 1; mk >>= 1) rs += __shfl_xor(rs, mk, 64);
      l[i] = l[i] * f + rs;
      O[i][0] *= f; O[i][1] *= f; O[i][2] *= f; O[i][3] *= f;
      #pragma unroll
      for (int j = 0; j < 4; ++j) Ps[tx * 4 + j][ty * 4 + i] = S[i][j];  // P^T
    }
    __syncthreads();
    #pragma unroll 8
    for (int kkk = 0; kkk < 64; ++kkk) {
      float4 a = *(const float4*)&Ps[kkk][ty * 4];
      float4 bb4 = *(const float4*)&Vs[kkk][tx * 4];
      FMA16(O, a, bb4);
    }
  }
  #pragma unroll
  for (int i = 0; i < 4; ++i) {
    float inv = 1.0f / l[i];
    ushort4 o;
    o.x = f2b(O[i][0] * inv); o.y = f2b(O[i][1] * inv);
    o.z = f2b(O[i][2] * inv); o.w = f2b(O[i][3] * inv);
    *(ushort4*)&ob[(rowbase + q0 + ty * 4 + i) * D_ + colbase + tx * 4] = o;
  }
}

// ---------------- MoE gate ----------------
__global__ __launch_bounds__(256) void k_init(int* cnt) { if (threadIdx.x < 4) cnt[threadIdx.x] = 0; }

__global__ __launch_bounds__(256) void k_gate(const float* __restrict__ h2, const float* __restrict__ gw,
                                              const float* __restrict__ gb, int* __restrict__ expert,
                                              int* __restrict__ cnt) {
  int wid = threadIdx.x >> 6, lane = threadIdx.x & 63;
  int t = blockIdx.x * 4 + wid;
  const float* hr = h2 + (size_t)t * D_;
  float a0 = 0, a1 = 0, a2 = 0, a3 = 0;
  for (int c = lane; c < D_; c += 64) {
    float xv = hr[c];
    a0 += xv * gw[c];
    a1 += xv * gw[D_ + c];
    a2 += xv * gw[2 * D_ + c];
    a3 += xv * gw[3 * D_ + c];
  }
  #pragma unroll
  for (int m = 32; m >= 1; m >>= 1) {
    a0 += __shfl_xor(a0, m, 64); a1 += __shfl_xor(a1, m, 64);
    a2 += __shfl_xor(a2, m, 64); a3 += __shfl_xor(a3, m, 64);
  }
  if (lane == 0) {
    float l0 = a0 + gb[0], l1 = a1 + gb[1], l2 = a2 + gb[2], l3 = a3 + gb[3];
    int best = 0; float bv = l0;
    if (l1 > bv) { bv = l1; best = 1; }
    if (l2 > bv) { bv = l2; best = 2; }
    if (l3 > bv) { bv = l3; best = 3; }
    expert[t] = best;
    atomicAdd(&cnt[best], 1);
  }
}

__global__ __launch_bounds__(256) void k_scatter(const int* __restrict__ expert, const int* __restrict__ cnt,
                                                 int* __restrict__ off, int* __restrict__ sorted) {
  __shared__ int cur[4];
  if (threadIdx.x == 0) {
    int o0 = 0, o1 = cnt[0], o2 = o1 + cnt[1], o3 = o2 + cnt[2];
    off[0] = o0; off[1] = o1; off[2] = o2; off[3] = o3;
    cur[0] = o0; cur[1] = o1; cur[2] = o2; cur[3] = o3;
  }
  __syncthreads();
  for (int t = threadIdx.x; t < M_; t += 256) {
    int e = expert[t];
    int p = atomicAdd(&cur[e], 1);
    sorted[p] = t;
  }
}

// ---------------- MoE MFMA GEMM 1: hbuf = bf16(relu(h2b[gather] @ W1[e]^T + b1[e])) ----------------
__global__ __launch_bounds__(256) void k_moe1(const u16* __restrict__ A, const float* __restrict__ W1,
                                              const float* __restrict__ b1, const int* __restrict__ cnt,
                                              const int* __restrict__ off, const int* __restrict__ sorted,
                                              u16* __restrict__ hbuf) {
  int e = blockIdx.z, mt = blockIdx.y, nt = blockIdx.x;
  int rem = cnt[e] - mt * 64;
  if (rem <= 0) return;
  __shared__ __align__(16) u16 As[64][72];
  __shared__ __align__(16) u16 Bs[64][72];
  int tid = threadIdx.x, lane = tid & 63, wave = tid >> 6;
  int wm = (wave >> 1) * 32, wn = (wave & 1) * 32;
  int lr = tid >> 2, lc = (tid & 3) * 16;
  int rr = lr < rem ? lr : rem - 1;
  const u16* arow = A + (size_t)sorted[off[e] + mt * 64 + rr] * D_;
  const float* brow = W1 + (size_t)e * DH_ * D_ + (size_t)(nt * 64 + lr) * D_;
  floatx4 z = {0.f, 0.f, 0.f, 0.f};
  floatx4 acc00 = z, acc01 = z, acc10 = z, acc11 = z;
  int fm = lane & 15, fkq = (lane >> 4) * 8;
  for (int kb = 0; kb < D_; kb += 64) {
    __syncthreads();
    *(uint4*)&As[lr][lc]     = *(const uint4*)&arow[kb + lc];
    *(uint4*)&As[lr][lc + 8] = *(const uint4*)&arow[kb + lc + 8];
    #pragma unroll
    for (int c = 0; c < 16; c += 4) {
      float4 f = *(const float4*)&brow[kb + lc + c];
      ushort4 u; u.x = f2b(f.x); u.y = f2b(f.y); u.z = f2b(f.z); u.w = f2b(f.w);
      *(ushort4*)&Bs[lr][lc + c] = u;
    }
    __syncthreads();
    #pragma unroll
    for (int ks = 0; ks < 64; ks += 32) {
      shortx8 a0  = *(const shortx8*)&As[wm + fm][ks + fkq];
      shortx8 a1  = *(const shortx8*)&As[wm + 16 + fm][ks + fkq];
      shortx8 b0  = *(const shortx8*)&Bs[wn + fm][ks + fkq];
      shortx8 b1v = *(const shortx8*)&Bs[wn + 16 + fm][ks + fkq];
      acc00 = __builtin_amdgcn_mfma_f32_16x16x32_bf16(a0, b0,  acc00, 0, 0, 0);
      acc01 = __builtin_amdgcn_mfma_f32_16x16x32_bf16(a0, b1v, acc01, 0, 0, 0);
      acc10 = __builtin_amdgcn_mfma_f32_16x16x32_bf16(a1, b0,  acc10, 0, 0, 0);
      acc11 = __builtin_amdgcn_mfma_f32_16x16x32_bf16(a1, b1v, acc11, 0, 0, 0);
    }
  }
  int q4 = (lane >> 4) * 4, cix = lane & 15;
  #pragma unroll
  for (int im = 0; im < 2; ++im) {
    #pragma unroll
    for (int rg = 0; rg < 4; ++rg) {
      int ml = wm + im * 16 + q4 + rg;
      if (ml >= rem) continue;
      size_t grow = (size_t)(off[e] + mt * 64 + ml);
      #pragma unroll
      for (int in = 0; in < 2; ++in) {
        int gn = nt * 64 + wn + in * 16 + cix;
        float vv = (im == 0 ? (in == 0 ? acc00[rg] : acc01[rg]) : (in == 0 ? acc10[rg] : acc11[rg]));
        vv += b1[e * DH_ + gn];
        hbuf[grow * DH_ + gn] = f2b(fmaxf(vv, 0.f));
      }
    }
  }
}

// ---------------- MoE MFMA GEMM 2: out_f32 = x1 + hbuf @ W2[e]^T + b2[e] ----------------
__global__ __launch_bounds__(256) void k_moe2(const u16* __restrict__ hbuf, const float* __restrict__ W2,
                                              const float* __restrict__ b2w, const float* __restrict__ x1f,
                                              const int* __restrict__ cnt, const int* __restrict__ off,
                                              const int* __restrict__ sorted, float* __restrict__ out) {
  int e = blockIdx.z, mt = blockIdx.y, nt = blockIdx.x;
  int rem = cnt[e] - mt * 64;
  if (rem <= 0) return;
  __shared__ __align__(16) u16 As[64][72];
  __shared__ __align__(16) u16 Bs[64][72];
  int tid = threadIdx.x, lane = tid & 63, wave = tid >> 6;
  int wm = (wave >> 1) * 32, wn = (wave & 1) * 32;
  int lr = tid >> 2, lc = (tid & 3) * 16;
  int rr = lr < rem ? lr : rem - 1;
  const u16* arow = hbuf + (size_t)(off[e] + mt * 64 + rr) * DH_;
  const float* brow = W2 + (size_t)e * D_ * DH_ + (size_t)(nt * 64 + lr) * DH_;
  floatx4 z = {0.f, 0.f, 0.f, 0.f};
  floatx4 acc00 = z, acc01 = z, acc10 = z, acc11 = z;
  int fm = lane & 15, fkq = (lane >> 4) * 8;
  for (int kb = 0; kb < DH_; kb += 64) {
    __syncthreads();
    *(uint4*)&As[lr][lc]     = *(const uint4*)&arow[kb + lc];
    *(uint4*)&As[lr][lc + 8] = *(const uint4*)&arow[kb + lc + 8];
    #pragma unroll
    for (int c = 0; c < 16; c += 4) {
      float4 f = *(const float4*)&brow[kb + lc + c];
      ushort4 u; u.x = f2b(f.x); u.y = f2b(f.y); u.z = f2b(f.z); u.w = f2b(f.w);
      *(ushort4*)&Bs[lr][lc + c] = u;
    }
    __syncthreads();
    #pragma unroll
    for (int ks = 0; ks < 64; ks += 32) {
      shortx8 a0  = *(const shortx8*)&As[wm + fm][ks + fkq];
      shortx8 a1  = *(const shortx8*)&As[wm + 16 + fm][ks + fkq];
      shortx8 b0  = *(const shortx8*)&Bs[wn + fm][ks + fkq];
      shortx8 b1v = *(const shortx8*)&Bs[wn + 16 + fm][ks + fkq];
      acc00 = __builtin_amdgcn_mfma_f32_16x16x32_bf16(a0, b0,  acc00, 0, 0, 0);
      acc01 = __builtin_amdgcn_mfma_f32_16x16x32_bf16(a0, b1v, acc01, 0, 0, 0);
      acc10 = __builtin_amdgcn_mfma_f32_16x16x32_bf16(a1, b0,  acc10, 0, 0, 0);
      acc11 = __builtin_amdgcn_mfma_f32_16x16x32_bf16(a1, b1v, acc11, 0, 0, 0);
    }
  }
  int q4 = (lane >> 4) * 4, cix = lane & 15;
  #pragma unroll
  for (int im = 0; im < 2; ++im) {
    #pragma unroll
    for (int rg = 0; rg < 4; ++rg) {
      int ml = wm + im * 16 + q4 + rg;
      if (ml >= rem) continue;
      int tok = sorted[off[e] + mt * 64 + ml];
      #pragma unroll
      for (int in = 0; in < 2; ++in) {
        int gn = nt * 64 + wn + in * 16 + cix;
        float vv = (im == 0 ? (in == 0 ? acc00[rg] : acc01[rg]) : (in == 0 ? acc10[rg] : acc11[rg]));
        out[(size_t)tok * D_ + gn] = vv + b2w[e * D_ + gn] + x1f[(size_t)tok * D_ + gn];
      }
    }
  }
}

extern "C" void kernel_launch(void* const* d_in, const int* in_sizes, int n_in,
                              void* d_out, int out_size, void* d_ws, size_t ws_size,
                              hipStream_t stream) {
  int map[16];
  for (int i = 0; i < 16; ++i) map[i] = i;
  if (n_in == 16 && in_sizes[0] == 16777216) {
    const int mm[16] = {15, 13, 14, 4, 2, 5, 6, 3, 12, 11, 10, 9, 0, 7, 1, 8};
    for (int i = 0; i < 16; ++i) map[i] = mm[i];
  } else if (n_in == 16 && in_sizes[0] == 4096) {
    for (int i = 0; i < 16; ++i) map[i] = 15 - i;
  }
  const float* x    = (const float*)d_in[map[0]];
  const float* n1w  = (const float*)d_in[map[1]];
  const float* n2w  = (const float*)d_in[map[2]];
  const float* Wq   = (const float*)d_in[map[3]];
  const float* Wdkv = (const float*)d_in[map[4]];
  const float* Wuk  = (const float*)d_in[map[5]];
  const float* Wuv  = (const float*)d_in[map[6]];
  const float* Wo   = (const float*)d_in[map[7]];
  const float* lng  = (const float*)d_in[map[8]];
  const float* lnb  = (const float*)d_in[map[9]];
  const float* gw   = (const float*)d_in[map[10]];
  const float* gb   = (const float*)d_in[map[11]];
  const float* W1   = (const float*)d_in[map[12]];
  const float* b1   = (const float*)d_in[map[13]];
  const float* W2   = (const float*)d_in[map[14]];
  const float* b2w  = (const float*)d_in[map[15]];
  float* out = (float*)d_out;
  char* ws = (char*)d_ws;
  const size_t MB = 1ull << 20;
  // Overlay layout, peak 36MB + 20KB:
  //  [0,8)  : qf f32 (Wq -> rope -> fattn)            -> hbuf.lo (moe1 -> moe2)
  //  [8,16) : kf f32 (Wuk -> rope -> fattn)           -> hbuf.hi
  //  [16,20): h1b bf16 (rms1 -> Wq,Wdkv; dead before Wuv writes vf)
  //  [16,24): vf f32 (Wuv -> fattn)                   -> h2f f32 (rms2 -> gate)
  //  [24,26): latb bf16 (ln -> Wuk,Wuv; dead before Wo writes x1f)
  //  [24,32): x1f f32 (Wo out + resid x; residual for moe2, live to end)
  //  [32,36): latf f32 (Wdkv -> ln) -> ab bf16 (fattn -> Wo) -> h2b bf16 (rms2 -> moe1)
  float* qf   = (float*)(ws + 0);
  u16*   hbuf = (u16*)(ws + 0);            // 16MB: [0,16)
  float* kf   = (float*)(ws + 8 * MB);
  u16*   h1b  = (u16*)(ws + 16 * MB);
  float* vf   = (float*)(ws + 16 * MB);
  float* h2f  = (float*)(ws + 16 * MB);
  u16*   latb = (u16*)(ws + 24 * MB);
  float* x1f  = (float*)(ws + 24 * MB);
  float* latf = (float*)(ws + 32 * MB);
  u16*   ab   = (u16*)(ws + 32 * MB);
  u16*   h2b  = (u16*)(ws + 32 * MB);
  int*   cnt    = (int*)(ws + 36 * MB);
  int*   off    = cnt + 8;
  int*   expert = cnt + 16;
  int*   sorted = expert + 2048;

  k_rms1b<<<2048, 256, 0, stream>>>(x, n1w, h1b);
  k_gemmbf<<<dim3(16, 32), 256, 0, stream>>>(h1b, Wq, nullptr, qf, 1024, 1024);
  k_gemmbf<<<dim3(8, 32), 256, 0, stream>>>(h1b, Wdkv, nullptr, latf, 512, 1024);
  k_lnb<<<2048, 256, 0, stream>>>(latf, lng, lnb, latb);
  k_gemmbf<<<dim3(16, 32), 256, 0, stream>>>(latb, Wuk, nullptr, kf, 1024, 512);
  k_gemmbf<<<dim3(16, 32), 256, 0, stream>>>(latb, Wuv, nullptr, vf, 1024, 512);
  k_rope<<<4096, 256, 0, stream>>>(qf, kf);
  k_fattn<<<dim3(32, 16), 256, 0, stream>>>(qf, kf, vf, ab);
  k_gemmbf<<<dim3(16, 32), 256, 0, stream>>>(ab, Wo, x, x1f, 1024, 1024);
  k_rms2b<<<2048, 256, 0, stream>>>(x1f, n2w, h2f, h2b);
  k_init<<<1, 64, 0, stream>>>(cnt);
  k_gate<<<512, 256, 0, stream>>>(h2f, gw, gb, expert, cnt);
  k_scatter<<<1, 256, 0, stream>>>(expert, cnt, off, sorted);
  k_moe1<<<dim3(64, 32, 4), 256, 0, stream>>>(h2b, W1, b1, cnt, off, sorted, hbuf);
  k_moe2<<<dim3(16, 32, 4), 256, 0, stream>>>(hbuf, W2, b2w, x1f, cnt, off, sorted, out);
}

// Round 3
// 567.556 us; speedup vs baseline: 1.7995x; 1.1435x over previous
//
#include <hip/hip_runtime.h>
#include <hip/hip_bf16.h>
#include <math.h>

typedef unsigned short u16;
typedef __attribute__((ext_vector_type(4))) float floatx4;
typedef __attribute__((ext_vector_type(8))) short shortx8;

#define DEVI static __device__ __forceinline__

DEVI u16 f2b(float f) {
  union { float f; unsigned int i; } v; v.f = f;
  unsigned int x = v.i;
  return (u16)((x + 0x7fffu + ((x >> 16) & 1u)) >> 16);
}

constexpr int T_ = 1024, D_ = 1024, HD_ = 64, KV_ = 512, DH_ = 4096, M_ = 2048;
#define NEGBIG (-1e30f)

// ---------------- RMSNorm (f32 in -> bf16 out) ----------------
__global__ __launch_bounds__(256) void k_rms1b(const float* __restrict__ x, const float* __restrict__ w,
                                               u16* __restrict__ outb) {
  int row = blockIdx.x, tid = threadIdx.x;
  float4 v = *(const float4*)&x[(size_t)row * D_ + tid * 4];
  float ss = v.x*v.x + v.y*v.y + v.z*v.z + v.w*v.w;
  #pragma unroll
  for (int m = 32; m >= 1; m >>= 1) ss += __shfl_xor(ss, m, 64);
  __shared__ float red[4];
  if ((tid & 63) == 0) red[tid >> 6] = ss;
  __syncthreads();
  ss = red[0] + red[1] + red[2] + red[3];
  float sc = 1.0f / sqrtf(ss * (1.0f / 1024.0f) + 1e-6f);
  float4 wv = *(const float4*)&w[tid * 4];
  ushort4 ob;
  ob.x = f2b(wv.x*v.x*sc); ob.y = f2b(wv.y*v.y*sc);
  ob.z = f2b(wv.z*v.z*sc); ob.w = f2b(wv.w*v.w*sc);
  *(ushort4*)&outb[(size_t)row * D_ + tid * 4] = ob;
}

// ---------------- RMSNorm (f32 in -> f32 out + bf16 out) ----------------
__global__ __launch_bounds__(256) void k_rms2b(const float* __restrict__ x, const float* __restrict__ w,
                                               float* __restrict__ outf, u16* __restrict__ outb) {
  int row = blockIdx.x, tid = threadIdx.x;
  float4 v = *(const float4*)&x[(size_t)row * D_ + tid * 4];
  float ss = v.x*v.x + v.y*v.y + v.z*v.z + v.w*v.w;
  #pragma unroll
  for (int m = 32; m >= 1; m >>= 1) ss += __shfl_xor(ss, m, 64);
  __shared__ float red[4];
  if ((tid & 63) == 0) red[tid >> 6] = ss;
  __syncthreads();
  ss = red[0] + red[1] + red[2] + red[3];
  float sc = 1.0f / sqrtf(ss * (1.0f / 1024.0f) + 1e-6f);
  float4 wv = *(const float4*)&w[tid * 4];
  float4 o; o.x = wv.x*v.x*sc; o.y = wv.y*v.y*sc; o.z = wv.z*v.z*sc; o.w = wv.w*v.w*sc;
  *(float4*)&outf[(size_t)row * D_ + tid * 4] = o;
  ushort4 ob; ob.x = f2b(o.x); ob.y = f2b(o.y); ob.z = f2b(o.z); ob.w = f2b(o.w);
  *(ushort4*)&outb[(size_t)row * D_ + tid * 4] = ob;
}

// ---------------- LayerNorm on latent (f32 in -> bf16 out, 512 cols) ----------------
__global__ __launch_bounds__(256) void k_lnb(const float* __restrict__ lat, const float* __restrict__ g,
                                             const float* __restrict__ bb, u16* __restrict__ ob) {
  int row = blockIdx.x, tid = threadIdx.x;
  const float* r = lat + (size_t)row * KV_;
  float v0 = r[tid], v1 = r[tid + 256];
  float s = v0 + v1;
  #pragma unroll
  for (int m = 32; m >= 1; m >>= 1) s += __shfl_xor(s, m, 64);
  __shared__ float red[4];
  if ((tid & 63) == 0) red[tid >> 6] = s;
  __syncthreads();
  float mu = (red[0] + red[1] + red[2] + red[3]) * (1.0f / 512.0f);
  __syncthreads();
  float d0 = v0 - mu, d1 = v1 - mu;
  float ss = d0*d0 + d1*d1;
  #pragma unroll
  for (int m = 32; m >= 1; m >>= 1) ss += __shfl_xor(ss, m, 64);
  if ((tid & 63) == 0) red[tid >> 6] = ss;
  __syncthreads();
  float var = (red[0] + red[1] + red[2] + red[3]) * (1.0f / 512.0f);
  float sc = 1.0f / sqrtf(var + 1e-5f);
  ob[(size_t)row * KV_ + tid]       = f2b(d0 * sc * g[tid]       + bb[tid]);
  ob[(size_t)row * KV_ + tid + 256] = f2b(d1 * sc * g[tid + 256] + bb[tid + 256]);
}

// ---------------- bf16 MFMA GEMM: C_f32[M,N] = A_bf16[M,K] @ Bw_f32[N,K]^T (+resid) ----------------
__global__ __launch_bounds__(256) void k_gemmbf(const u16* __restrict__ A, const float* __restrict__ Bw,
                                                const float* __restrict__ resid, float* __restrict__ C,
                                                int N, int K) {
  int nt = blockIdx.x, mt = blockIdx.y;
  __shared__ __align__(16) u16 As[64][72];
  __shared__ __align__(16) u16 Bs[64][72];
  int tid = threadIdx.x, lane = tid & 63, wave = tid >> 6;
  int wm = (wave >> 1) * 32, wn = (wave & 1) * 32;
  int lr = tid >> 2, lc = (tid & 3) * 16;
  const u16* arow = A + (size_t)(mt * 64 + lr) * K;
  const float* brow = Bw + (size_t)(nt * 64 + lr) * K;
  floatx4 z = {0.f, 0.f, 0.f, 0.f};
  floatx4 acc00 = z, acc01 = z, acc10 = z, acc11 = z;
  int fm = lane & 15, fkq = (lane >> 4) * 8;
  for (int kb = 0; kb < K; kb += 64) {
    __syncthreads();
    *(uint4*)&As[lr][lc]     = *(const uint4*)&arow[kb + lc];
    *(uint4*)&As[lr][lc + 8] = *(const uint4*)&arow[kb + lc + 8];
    #pragma unroll
    for (int c = 0; c < 16; c += 4) {
      float4 f = *(const float4*)&brow[kb + lc + c];
      ushort4 u; u.x = f2b(f.x); u.y = f2b(f.y); u.z = f2b(f.z); u.w = f2b(f.w);
      *(ushort4*)&Bs[lr][lc + c] = u;
    }
    __syncthreads();
    #pragma unroll
    for (int ks = 0; ks < 64; ks += 32) {
      shortx8 a0  = *(const shortx8*)&As[wm + fm][ks + fkq];
      shortx8 a1  = *(const shortx8*)&As[wm + 16 + fm][ks + fkq];
      shortx8 b0  = *(const shortx8*)&Bs[wn + fm][ks + fkq];
      shortx8 b1v = *(const shortx8*)&Bs[wn + 16 + fm][ks + fkq];
      acc00 = __builtin_amdgcn_mfma_f32_16x16x32_bf16(a0, b0,  acc00, 0, 0, 0);
      acc01 = __builtin_amdgcn_mfma_f32_16x16x32_bf16(a0, b1v, acc01, 0, 0, 0);
      acc10 = __builtin_amdgcn_mfma_f32_16x16x32_bf16(a1, b0,  acc10, 0, 0, 0);
      acc11 = __builtin_amdgcn_mfma_f32_16x16x32_bf16(a1, b1v, acc11, 0, 0, 0);
    }
  }
  int q4 = (lane >> 4) * 4, cix = lane & 15;
  #pragma unroll
  for (int im = 0; im < 2; ++im) {
    #pragma unroll
    for (int rg = 0; rg < 4; ++rg) {
      int row = mt * 64 + wm + im * 16 + q4 + rg;
      #pragma unroll
      for (int in = 0; in < 2; ++in) {
        int gn = nt * 64 + wn + in * 16 + cix;
        float vv = (im == 0 ? (in == 0 ? acc00[rg] : acc01[rg]) : (in == 0 ? acc10[rg] : acc11[rg]));
        size_t idx = (size_t)row * N + gn;
        if (resid) vv += resid[idx];
        C[idx] = vv;
      }
    }
  }
}

// ---------------- bf16 MFMA GEMM variant: bf16 out, no residual ----------------
__global__ __launch_bounds__(256) void k_gemmbf_b(const u16* __restrict__ A, const float* __restrict__ Bw,
                                                  u16* __restrict__ Cb, int N, int K) {
  int nt = blockIdx.x, mt = blockIdx.y;
  __shared__ __align__(16) u16 As[64][72];
  __shared__ __align__(16) u16 Bs[64][72];
  int tid = threadIdx.x, lane = tid & 63, wave = tid >> 6;
  int wm = (wave >> 1) * 32, wn = (wave & 1) * 32;
  int lr = tid >> 2, lc = (tid & 3) * 16;
  const u16* arow = A + (size_t)(mt * 64 + lr) * K;
  const float* brow = Bw + (size_t)(nt * 64 + lr) * K;
  floatx4 z = {0.f, 0.f, 0.f, 0.f};
  floatx4 acc00 = z, acc01 = z, acc10 = z, acc11 = z;
  int fm = lane & 15, fkq = (lane >> 4) * 8;
  for (int kb = 0; kb < K; kb += 64) {
    __syncthreads();
    *(uint4*)&As[lr][lc]     = *(const uint4*)&arow[kb + lc];
    *(uint4*)&As[lr][lc + 8] = *(const uint4*)&arow[kb + lc + 8];
    #pragma unroll
    for (int c = 0; c < 16; c += 4) {
      float4 f = *(const float4*)&brow[kb + lc + c];
      ushort4 u; u.x = f2b(f.x); u.y = f2b(f.y); u.z = f2b(f.z); u.w = f2b(f.w);
      *(ushort4*)&Bs[lr][lc + c] = u;
    }
    __syncthreads();
    #pragma unroll
    for (int ks = 0; ks < 64; ks += 32) {
      shortx8 a0  = *(const shortx8*)&As[wm + fm][ks + fkq];
      shortx8 a1  = *(const shortx8*)&As[wm + 16 + fm][ks + fkq];
      shortx8 b0  = *(const shortx8*)&Bs[wn + fm][ks + fkq];
      shortx8 b1v = *(const shortx8*)&Bs[wn + 16 + fm][ks + fkq];
      acc00 = __builtin_amdgcn_mfma_f32_16x16x32_bf16(a0, b0,  acc00, 0, 0, 0);
      acc01 = __builtin_amdgcn_mfma_f32_16x16x32_bf16(a0, b1v, acc01, 0, 0, 0);
      acc10 = __builtin_amdgcn_mfma_f32_16x16x32_bf16(a1, b0,  acc10, 0, 0, 0);
      acc11 = __builtin_amdgcn_mfma_f32_16x16x32_bf16(a1, b1v, acc11, 0, 0, 0);
    }
  }
  int q4 = (lane >> 4) * 4, cix = lane & 15;
  #pragma unroll
  for (int im = 0; im < 2; ++im) {
    #pragma unroll
    for (int rg = 0; rg < 4; ++rg) {
      int row = mt * 64 + wm + im * 16 + q4 + rg;
      #pragma unroll
      for (int in = 0; in < 2; ++in) {
        int gn = nt * 64 + wn + in * 16 + cix;
        float vv = (im == 0 ? (in == 0 ? acc00[rg] : acc01[rg]) : (in == 0 ? acc10[rg] : acc11[rg]));
        Cb[(size_t)row * N + gn] = f2b(vv);
      }
    }
  }
}

// ---------------- RoPE: f32 q,k in -> bf16 qb (pre-scaled 1/8), kb out ----------------
__global__ __launch_bounds__(256) void k_rope2b(const float* __restrict__ q, const float* __restrict__ k,
                                                u16* __restrict__ qb, u16* __restrict__ kb) {
  int g = blockIdx.x * 256 + threadIdx.x;
  int j = g & 31;
  int h = (g >> 5) & 15;
  int row = g >> 9;
  int t = row & (T_ - 1);
  float p = (float)pow(10000.0, (double)j * (1.0 / 32.0));
  float ang = (float)t / p;
  float sn, cs; sincosf(ang, &sn, &cs);
  size_t base = (size_t)row * D_ + h * 64 + j;
  float x1 = q[base], x2 = q[base + 32];
  qb[base]      = f2b((x1 * cs - x2 * sn) * 0.125f);
  qb[base + 32] = f2b((x1 * sn + x2 * cs) * 0.125f);
  x1 = k[base]; x2 = k[base + 32];
  kb[base]      = f2b(x1 * cs - x2 * sn);
  kb[base + 32] = f2b(x1 * sn + x2 * cs);
}

// ---------------- Flash attention, bf16 MFMA, 64-row q-tile per block ----------------
// Grid: (32 [qt x b], 16 heads), 256 threads = 4 waves in 2x2 quadrants of 32x32.
// S = QK^T via mfma (fp32 acc), online softmax in registers, PV via mfma.
__global__ __launch_bounds__(256) void k_fattn(const u16* __restrict__ qbp, const u16* __restrict__ kbp,
                                               const u16* __restrict__ vbp, u16* __restrict__ ob) {
  int idx = blockIdx.x, h = blockIdx.y;
  int b = idx >> 4;
  int qt = idx & 15;
  if (b) qt = 15 - qt;  // complementary pairing: co-resident pair sums to 17 k-tiles
  __shared__ __align__(16) u16 Qs[64][72];   // [q][d] bf16 (A-operand), pre-scaled 1/8
  __shared__ __align__(16) u16 Ks[64][72];   // [k][d] bf16 (B-operand)
  __shared__ __align__(16) u16 Vs[64][72];   // [d][k] bf16 transposed (B-operand for PV)
  __shared__ __align__(16) u16 Ps[64][72];   // [q][k] bf16 (A-operand for PV)
  __shared__ float red1[2][64];
  __shared__ float red2[2][64];
  int tid = threadIdx.x, lane = tid & 63, wave = tid >> 6;
  int wm = (wave >> 1) * 32, wn = (wave & 1) * 32, w1 = wave & 1;
  int fm = lane & 15, fkq = (lane >> 4) * 8;
  int q4 = (lane >> 4) * 4, cix = lane & 15;
  size_t rowbase = (size_t)b * T_;
  int colbase = h * HD_;
  int q0 = qt * 64;
  int lr = tid >> 2, ld = (tid & 3) * 16;
  {
    const u16* qr = qbp + (rowbase + q0 + lr) * D_ + colbase + ld;
    *(uint4*)&Qs[lr][ld]     = *(const uint4*)&qr[0];
    *(uint4*)&Qs[lr][ld + 8] = *(const uint4*)&qr[8];
  }
  floatx4 z = {0.f, 0.f, 0.f, 0.f};
  floatx4 s[2][2], o[2][2];
  o[0][0] = z; o[0][1] = z; o[1][0] = z; o[1][1] = z;
  float m[2][4], l[2][4], f_[2][4];
  #pragma unroll
  for (int im = 0; im < 2; ++im)
    #pragma unroll
    for (int rg = 0; rg < 4; ++rg) { m[im][rg] = NEGBIG; l[im][rg] = 0.f; }
  for (int kt = 0; kt <= qt; ++kt) {
    __syncthreads();  // prev PV done; staging buffers free (Q-stage covered on first iter)
    {
      const u16* kr = kbp + (rowbase + kt * 64 + lr) * D_ + colbase + ld;
      *(uint4*)&Ks[lr][ld]     = *(const uint4*)&kr[0];
      *(uint4*)&Ks[lr][ld + 8] = *(const uint4*)&kr[8];
      const u16* vr = vbp + (rowbase + kt * 64 + lr) * D_ + colbase + ld;
      #pragma unroll
      for (int c = 0; c < 16; ++c) Vs[ld + c][lr] = vr[c];
    }
    __syncthreads();
    s[0][0] = z; s[0][1] = z; s[1][0] = z; s[1][1] = z;
    #pragma unroll
    for (int ks = 0; ks < 64; ks += 32) {
      shortx8 a0  = *(const shortx8*)&Qs[wm + fm][ks + fkq];
      shortx8 a1  = *(const shortx8*)&Qs[wm + 16 + fm][ks + fkq];
      shortx8 b0  = *(const shortx8*)&Ks[wn + fm][ks + fkq];
      shortx8 b1v = *(const shortx8*)&Ks[wn + 16 + fm][ks + fkq];
      s[0][0] = __builtin_amdgcn_mfma_f32_16x16x32_bf16(a0, b0,  s[0][0], 0, 0, 0);
      s[0][1] = __builtin_amdgcn_mfma_f32_16x16x32_bf16(a0, b1v, s[0][1], 0, 0, 0);
      s[1][0] = __builtin_amdgcn_mfma_f32_16x16x32_bf16(a1, b0,  s[1][0], 0, 0, 0);
      s[1][1] = __builtin_amdgcn_mfma_f32_16x16x32_bf16(a1, b1v, s[1][1], 0, 0, 0);
    }
    if (kt == qt) {  // diagonal tile: local-index causal mask
      #pragma unroll
      for (int im = 0; im < 2; ++im)
        #pragma unroll
        for (int rg = 0; rg < 4; ++rg) {
          int r = wm + im * 16 + q4 + rg;
          #pragma unroll
          for (int in = 0; in < 2; ++in)
            if (wn + in * 16 + cix > r) s[im][in][rg] = NEGBIG;
        }
    }
    // row-max partial over this wave's 32 cols (shfl across the 16-lane col group)
    #pragma unroll
    for (int im = 0; im < 2; ++im)
      #pragma unroll
      for (int rg = 0; rg < 4; ++rg) {
        float pm = fmaxf(s[im][0][rg], s[im][1][rg]);
        #pragma unroll
        for (int mk = 8; mk >= 1; mk >>= 1) pm = fmaxf(pm, __shfl_xor(pm, mk, 64));
        if (cix == 0) red1[w1][wm + im * 16 + q4 + rg] = pm;
        f_[im][rg] = pm;  // stash partial max
      }
    __syncthreads();
    #pragma unroll
    for (int im = 0; im < 2; ++im)
      #pragma unroll
      for (int rg = 0; rg < 4; ++rg) {
        int r = wm + im * 16 + q4 + rg;
        float mx = fmaxf(f_[im][rg], red1[w1 ^ 1][r]);
        float mn = fmaxf(m[im][rg], mx);
        float f = __expf(m[im][rg] - mn);
        m[im][rg] = mn;
        float p0 = __expf(s[im][0][rg] - mn);
        float p1 = __expf(s[im][1][rg] - mn);
        float ss = p0 + p1;
        #pragma unroll
        for (int mk = 8; mk >= 1; mk >>= 1) ss += __shfl_xor(ss, mk, 64);
        if (cix == 0) red2[w1][r] = ss;
        Ps[r][wn + cix]      = f2b(p0);
        Ps[r][wn + 16 + cix] = f2b(p1);
        l[im][rg] *= f;
        o[im][0][rg] *= f;
        o[im][1][rg] *= f;
      }
    __syncthreads();  // Ps/red2 complete from all waves
    #pragma unroll
    for (int im = 0; im < 2; ++im)
      #pragma unroll
      for (int rg = 0; rg < 4; ++rg) {
        int r = wm + im * 16 + q4 + rg;
        l[im][rg] += red2[0][r] + red2[1][r];
      }
    #pragma unroll
    for (int ks = 0; ks < 64; ks += 32) {
      shortx8 a0  = *(const shortx8*)&Ps[wm + fm][ks + fkq];
      shortx8 a1  = *(const shortx8*)&Ps[wm + 16 + fm][ks + fkq];
      shortx8 b0  = *(const shortx8*)&Vs[wn + fm][ks + fkq];
      shortx8 b1v = *(const shortx8*)&Vs[wn + 16 + fm][ks + fkq];
      o[0][0] = __builtin_amdgcn_mfma_f32_16x16x32_bf16(a0, b0,  o[0][0], 0, 0, 0);
      o[0][1] = __builtin_amdgcn_mfma_f32_16x16x32_bf16(a0, b1v, o[0][1], 0, 0, 0);
      o[1][0] = __builtin_amdgcn_mfma_f32_16x16x32_bf16(a1, b0,  o[1][0], 0, 0, 0);
      o[1][1] = __builtin_amdgcn_mfma_f32_16x16x32_bf16(a1, b1v, o[1][1], 0, 0, 0);
    }
  }
  #pragma unroll
  for (int im = 0; im < 2; ++im)
    #pragma unroll
    for (int rg = 0; rg < 4; ++rg) {
      int r = wm + im * 16 + q4 + rg;
      float inv = 1.0f / l[im][rg];
      size_t base = (rowbase + q0 + r) * D_ + colbase;
      ob[base + wn + cix]      = f2b(o[im][0][rg] * inv);
      ob[base + wn + 16 + cix] = f2b(o[im][1][rg] * inv);
    }
}

// ---------------- MoE gate ----------------
__global__ __launch_bounds__(256) void k_init(int* cnt) { if (threadIdx.x < 4) cnt[threadIdx.x] = 0; }

__global__ __launch_bounds__(256) void k_gate(const float* __restrict__ h2, const float* __restrict__ gw,
                                              const float* __restrict__ gb, int* __restrict__ expert,
                                              int* __restrict__ cnt) {
  int wid = threadIdx.x >> 6, lane = threadIdx.x & 63;
  int t = blockIdx.x * 4 + wid;
  const float* hr = h2 + (size_t)t * D_;
  float a0 = 0, a1 = 0, a2 = 0, a3 = 0;
  for (int c = lane; c < D_; c += 64) {
    float xv = hr[c];
    a0 += xv * gw[c];
    a1 += xv * gw[D_ + c];
    a2 += xv * gw[2 * D_ + c];
    a3 += xv * gw[3 * D_ + c];
  }
  #pragma unroll
  for (int m = 32; m >= 1; m >>= 1) {
    a0 += __shfl_xor(a0, m, 64); a1 += __shfl_xor(a1, m, 64);
    a2 += __shfl_xor(a2, m, 64); a3 += __shfl_xor(a3, m, 64);
  }
  if (lane == 0) {
    float l0 = a0 + gb[0], l1 = a1 + gb[1], l2 = a2 + gb[2], l3 = a3 + gb[3];
    int best = 0; float bv = l0;
    if (l1 > bv) { bv = l1; best = 1; }
    if (l2 > bv) { bv = l2; best = 2; }
    if (l3 > bv) { bv = l3; best = 3; }
    expert[t] = best;
    atomicAdd(&cnt[best], 1);
  }
}

__global__ __launch_bounds__(256) void k_scatter(const int* __restrict__ expert, const int* __restrict__ cnt,
                                                 int* __restrict__ off, int* __restrict__ sorted) {
  __shared__ int cur[4];
  if (threadIdx.x == 0) {
    int o0 = 0, o1 = cnt[0], o2 = o1 + cnt[1], o3 = o2 + cnt[2];
    off[0] = o0; off[1] = o1; off[2] = o2; off[3] = o3;
    cur[0] = o0; cur[1] = o1; cur[2] = o2; cur[3] = o3;
  }
  __syncthreads();
  for (int t = threadIdx.x; t < M_; t += 256) {
    int e = expert[t];
    int p = atomicAdd(&cur[e], 1);
    sorted[p] = t;
  }
}

// ---------------- MoE MFMA GEMM 1: hbuf = bf16(relu(h2b[gather] @ W1[e]^T + b1[e])) ----------------
__global__ __launch_bounds__(256) void k_moe1(const u16* __restrict__ A, const float* __restrict__ W1,
                                              const float* __restrict__ b1, const int* __restrict__ cnt,
                                              const int* __restrict__ off, const int* __restrict__ sorted,
                                              u16* __restrict__ hbuf) {
  int e = blockIdx.z, mt = blockIdx.y, nt = blockIdx.x;
  int rem = cnt[e] - mt * 64;
  if (rem <= 0) return;
  __shared__ __align__(16) u16 As[64][72];
  __shared__ __align__(16) u16 Bs[64][72];
  int tid = threadIdx.x, lane = tid & 63, wave = tid >> 6;
  int wm = (wave >> 1) * 32, wn = (wave & 1) * 32;
  int lr = tid >> 2, lc = (tid & 3) * 16;
  int rr = lr < rem ? lr : rem - 1;
  const u16* arow = A + (size_t)sorted[off[e] + mt * 64 + rr] * D_;
  const float* brow = W1 + (size_t)e * DH_ * D_ + (size_t)(nt * 64 + lr) * D_;
  floatx4 z = {0.f, 0.f, 0.f, 0.f};
  floatx4 acc00 = z, acc01 = z, acc10 = z, acc11 = z;
  int fm = lane & 15, fkq = (lane >> 4) * 8;
  for (int kb = 0; kb < D_; kb += 64) {
    __syncthreads();
    *(uint4*)&As[lr][lc]     = *(const uint4*)&arow[kb + lc];
    *(uint4*)&As[lr][lc + 8] = *(const uint4*)&arow[kb + lc + 8];
    #pragma unroll
    for (int c = 0; c < 16; c += 4) {
      float4 f = *(const float4*)&brow[kb + lc + c];
      ushort4 u; u.x = f2b(f.x); u.y = f2b(f.y); u.z = f2b(f.z); u.w = f2b(f.w);
      *(ushort4*)&Bs[lr][lc + c] = u;
    }
    __syncthreads();
    #pragma unroll
    for (int ks = 0; ks < 64; ks += 32) {
      shortx8 a0  = *(const shortx8*)&As[wm + fm][ks + fkq];
      shortx8 a1  = *(const shortx8*)&As[wm + 16 + fm][ks + fkq];
      shortx8 b0  = *(const shortx8*)&Bs[wn + fm][ks + fkq];
      shortx8 b1v = *(const shortx8*)&Bs[wn + 16 + fm][ks + fkq];
      acc00 = __builtin_amdgcn_mfma_f32_16x16x32_bf16(a0, b0,  acc00, 0, 0, 0);
      acc01 = __builtin_amdgcn_mfma_f32_16x16x32_bf16(a0, b1v, acc01, 0, 0, 0);
      acc10 = __builtin_amdgcn_mfma_f32_16x16x32_bf16(a1, b0,  acc10, 0, 0, 0);
      acc11 = __builtin_amdgcn_mfma_f32_16x16x32_bf16(a1, b1v, acc11, 0, 0, 0);
    }
  }
  int q4 = (lane >> 4) * 4, cix = lane & 15;
  #pragma unroll
  for (int im = 0; im < 2; ++im) {
    #pragma unroll
    for (int rg = 0; rg < 4; ++rg) {
      int ml = wm + im * 16 + q4 + rg;
      if (ml >= rem) continue;
      size_t grow = (size_t)(off[e] + mt * 64 + ml);
      #pragma unroll
      for (int in = 0; in < 2; ++in) {
        int gn = nt * 64 + wn + in * 16 + cix;
        float vv = (im == 0 ? (in == 0 ? acc00[rg] : acc01[rg]) : (in == 0 ? acc10[rg] : acc11[rg]));
        vv += b1[e * DH_ + gn];
        hbuf[grow * DH_ + gn] = f2b(fmaxf(vv, 0.f));
      }
    }
  }
}

// ---------------- MoE MFMA GEMM 2: out_f32 = x1 + hbuf @ W2[e]^T + b2[e] ----------------
__global__ __launch_bounds__(256) void k_moe2(const u16* __restrict__ hbuf, const float* __restrict__ W2,
                                              const float* __restrict__ b2w, const float* __restrict__ x1f,
                                              const int* __restrict__ cnt, const int* __restrict__ off,
                                              const int* __restrict__ sorted, float* __restrict__ out) {
  int e = blockIdx.z, mt = blockIdx.y, nt = blockIdx.x;
  int rem = cnt[e] - mt * 64;
  if (rem <= 0) return;
  __shared__ __align__(16) u16 As[64][72];
  __shared__ __align__(16) u16 Bs[64][72];
  int tid = threadIdx.x, lane = tid & 63, wave = tid >> 6;
  int wm = (wave >> 1) * 32, wn = (wave & 1) * 32;
  int lr = tid >> 2, lc = (tid & 3) * 16;
  int rr = lr < rem ? lr : rem - 1;
  const u16* arow = hbuf + (size_t)(off[e] + mt * 64 + rr) * DH_;
  const float* brow = W2 + (size_t)e * D_ * DH_ + (size_t)(nt * 64 + lr) * DH_;
  floatx4 z = {0.f, 0.f, 0.f, 0.f};
  floatx4 acc00 = z, acc01 = z, acc10 = z, acc11 = z;
  int fm = lane & 15, fkq = (lane >> 4) * 8;
  for (int kb = 0; kb < DH_; kb += 64) {
    __syncthreads();
    *(uint4*)&As[lr][lc]     = *(const uint4*)&arow[kb + lc];
    *(uint4*)&As[lr][lc + 8] = *(const uint4*)&arow[kb + lc + 8];
    #pragma unroll
    for (int c = 0; c < 16; c += 4) {
      float4 f = *(const float4*)&brow[kb + lc + c];
      ushort4 u; u.x = f2b(f.x); u.y = f2b(f.y); u.z = f2b(f.z); u.w = f2b(f.w);
      *(ushort4*)&Bs[lr][lc + c] = u;
    }
    __syncthreads();
    #pragma unroll
    for (int ks = 0; ks < 64; ks += 32) {
      shortx8 a0  = *(const shortx8*)&As[wm + fm][ks + fkq];
      shortx8 a1  = *(const shortx8*)&As[wm + 16 + fm][ks + fkq];
      shortx8 b0  = *(const shortx8*)&Bs[wn + fm][ks + fkq];
      shortx8 b1v = *(const shortx8*)&Bs[wn + 16 + fm][ks + fkq];
      acc00 = __builtin_amdgcn_mfma_f32_16x16x32_bf16(a0, b0,  acc00, 0, 0, 0);
      acc01 = __builtin_amdgcn_mfma_f32_16x16x32_bf16(a0, b1v, acc01, 0, 0, 0);
      acc10 = __builtin_amdgcn_mfma_f32_16x16x32_bf16(a1, b0,  acc10, 0, 0, 0);
      acc11 = __builtin_amdgcn_mfma_f32_16x16x32_bf16(a1, b1v, acc11, 0, 0, 0);
    }
  }
  int q4 = (lane >> 4) * 4, cix = lane & 15;
  #pragma unroll
  for (int im = 0; im < 2; ++im) {
    #pragma unroll
    for (int rg = 0; rg < 4; ++rg) {
      int ml = wm + im * 16 + q4 + rg;
      if (ml >= rem) continue;
      int tok = sorted[off[e] + mt * 64 + ml];
      #pragma unroll
      for (int in = 0; in < 2; ++in) {
        int gn = nt * 64 + wn + in * 16 + cix;
        float vv = (im == 0 ? (in == 0 ? acc00[rg] : acc01[rg]) : (in == 0 ? acc10[rg] : acc11[rg]));
        out[(size_t)tok * D_ + gn] = vv + b2w[e * D_ + gn] + x1f[(size_t)tok * D_ + gn];
      }
    }
  }
}

extern "C" void kernel_launch(void* const* d_in, const int* in_sizes, int n_in,
                              void* d_out, int out_size, void* d_ws, size_t ws_size,
                              hipStream_t stream) {
  int map[16];
  for (int i = 0; i < 16; ++i) map[i] = i;
  if (n_in == 16 && in_sizes[0] == 16777216) {
    const int mm[16] = {15, 13, 14, 4, 2, 5, 6, 3, 12, 11, 10, 9, 0, 7, 1, 8};
    for (int i = 0; i < 16; ++i) map[i] = mm[i];
  } else if (n_in == 16 && in_sizes[0] == 4096) {
    for (int i = 0; i < 16; ++i) map[i] = 15 - i;
  }
  const float* x    = (const float*)d_in[map[0]];
  const float* n1w  = (const float*)d_in[map[1]];
  const float* n2w  = (const float*)d_in[map[2]];
  const float* Wq   = (const float*)d_in[map[3]];
  const float* Wdkv = (const float*)d_in[map[4]];
  const float* Wuk  = (const float*)d_in[map[5]];
  const float* Wuv  = (const float*)d_in[map[6]];
  const float* Wo   = (const float*)d_in[map[7]];
  const float* lng  = (const float*)d_in[map[8]];
  const float* lnb  = (const float*)d_in[map[9]];
  const float* gw   = (const float*)d_in[map[10]];
  const float* gb   = (const float*)d_in[map[11]];
  const float* W1   = (const float*)d_in[map[12]];
  const float* b1   = (const float*)d_in[map[13]];
  const float* W2   = (const float*)d_in[map[14]];
  const float* b2w  = (const float*)d_in[map[15]];
  float* out = (float*)d_out;
  char* ws = (char*)d_ws;
  const size_t MB = 1ull << 20;
  // Overlay layout, peak 36MB + 20KB:
  //  [0,8)  : qf f32 (Wq -> rope)                 -> x1f f32 (Wo out; residual for moe2)
  //  [8,16) : kf f32 (Wuk -> rope)                -> hbuf.lo bf16 (moe1 -> moe2)
  //  [16,20): latf f32 (Wdkv -> ln)               -> qb bf16 (rope -> fattn)      -> hbuf.mid
  //  [20,24): h1b bf16 (rms1 -> Wq,Wdkv)          -> kb bf16 (rope -> fattn)      -> hbuf.hi
  //  [24,26): latb bf16 (ln -> Wuk,Wuv)           \
  //  [26,30): vb bf16 (Wuv -> fattn)               } -> h2f f32 [24,32) (rms2 -> gate)
  //  [30,34): ab bf16 (fattn -> Wo)               /  (ab[32,34) -> h2b below)
  //  [32,36): h2b bf16 (rms2 -> moe1)
  float* qf   = (float*)(ws + 0);
  float* x1f  = (float*)(ws + 0);
  float* kf   = (float*)(ws + 8 * MB);
  u16*   hbuf = (u16*)(ws + 8 * MB);       // 16MB: [8,24)
  float* latf = (float*)(ws + 16 * MB);
  u16*   qb   = (u16*)(ws + 16 * MB);
  u16*   h1b  = (u16*)(ws + 20 * MB);
  u16*   kb   = (u16*)(ws + 20 * MB);
  u16*   latb = (u16*)(ws + 24 * MB);
  float* h2f  = (float*)(ws + 24 * MB);
  u16*   vb   = (u16*)(ws + 26 * MB);
  u16*   ab   = (u16*)(ws + 30 * MB);
  u16*   h2b  = (u16*)(ws + 32 * MB);
  int*   cnt    = (int*)(ws + 36 * MB);
  int*   off    = cnt + 8;
  int*   expert = cnt + 16;
  int*   sorted = expert + 2048;

  k_rms1b<<<2048, 256, 0, stream>>>(x, n1w, h1b);
  k_gemmbf<<<dim3(16, 32), 256, 0, stream>>>(h1b, Wq, nullptr, qf, 1024, 1024);
  k_gemmbf<<<dim3(8, 32), 256, 0, stream>>>(h1b, Wdkv, nullptr, latf, 512, 1024);
  k_lnb<<<2048, 256, 0, stream>>>(latf, lng, lnb, latb);
  k_gemmbf<<<dim3(16, 32), 256, 0, stream>>>(latb, Wuk, nullptr, kf, 1024, 512);
  k_gemmbf_b<<<dim3(16, 32), 256, 0, stream>>>(latb, Wuv, vb, 1024, 512);
  k_rope2b<<<4096, 256, 0, stream>>>(qf, kf, qb, kb);
  k_fattn<<<dim3(32, 16), 256, 0, stream>>>(qb, kb, vb, ab);
  k_gemmbf<<<dim3(16, 32), 256, 0, stream>>>(ab, Wo, x, x1f, 1024, 1024);
  k_rms2b<<<2048, 256, 0, stream>>>(x1f, n2w, h2f, h2b);
  k_init<<<1, 64, 0, stream>>>(cnt);
  k_gate<<<512, 256, 0, stream>>>(h2f, gw, gb, expert, cnt);
  k_scatter<<<1, 256, 0, stream>>>(expert, cnt, off, sorted);
  k_moe1<<<dim3(64, 32, 4), 256, 0, stream>>>(h2b, W1, b1, cnt, off, sorted, hbuf);
  k_moe2<<<dim3(16, 32, 4), 256, 0, stream>>>(hbuf, W2, b2w, x1f, cnt, off, sorted, out);
}

// Round 4
// 545.015 us; speedup vs baseline: 1.8739x; 1.0414x over previous
//
#include <hip/hip_runtime.h>
#include <hip/hip_bf16.h>
#include <math.h>

typedef unsigned short u16;
typedef __attribute__((ext_vector_type(4))) float floatx4;
typedef __attribute__((ext_vector_type(8))) short shortx8;

#define DEVI static __device__ __forceinline__

DEVI u16 f2b(float f) {
  union { float f; unsigned int i; } v; v.f = f;
  unsigned int x = v.i;
  return (u16)((x + 0x7fffu + ((x >> 16) & 1u)) >> 16);
}

constexpr int T_ = 1024, D_ = 1024, HD_ = 64, KV_ = 512, DH_ = 4096, M_ = 2048;
#define NEGBIG (-1e30f)

// ---------------- RMSNorm (f32 in -> bf16 out) ----------------
__global__ __launch_bounds__(256) void k_rms1b(const float* __restrict__ x, const float* __restrict__ w,
                                               u16* __restrict__ outb) {
  int row = blockIdx.x, tid = threadIdx.x;
  float4 v = *(const float4*)&x[(size_t)row * D_ + tid * 4];
  float ss = v.x*v.x + v.y*v.y + v.z*v.z + v.w*v.w;
  #pragma unroll
  for (int m = 32; m >= 1; m >>= 1) ss += __shfl_xor(ss, m, 64);
  __shared__ float red[4];
  if ((tid & 63) == 0) red[tid >> 6] = ss;
  __syncthreads();
  ss = red[0] + red[1] + red[2] + red[3];
  float sc = 1.0f / sqrtf(ss * (1.0f / 1024.0f) + 1e-6f);
  float4 wv = *(const float4*)&w[tid * 4];
  ushort4 ob;
  ob.x = f2b(wv.x*v.x*sc); ob.y = f2b(wv.y*v.y*sc);
  ob.z = f2b(wv.z*v.z*sc); ob.w = f2b(wv.w*v.w*sc);
  *(ushort4*)&outb[(size_t)row * D_ + tid * 4] = ob;
}

// ---------------- RMSNorm (f32 in -> f32 out + bf16 out) ----------------
__global__ __launch_bounds__(256) void k_rms2b(const float* __restrict__ x, const float* __restrict__ w,
                                               float* __restrict__ outf, u16* __restrict__ outb) {
  int row = blockIdx.x, tid = threadIdx.x;
  float4 v = *(const float4*)&x[(size_t)row * D_ + tid * 4];
  float ss = v.x*v.x + v.y*v.y + v.z*v.z + v.w*v.w;
  #pragma unroll
  for (int m = 32; m >= 1; m >>= 1) ss += __shfl_xor(ss, m, 64);
  __shared__ float red[4];
  if ((tid & 63) == 0) red[tid >> 6] = ss;
  __syncthreads();
  ss = red[0] + red[1] + red[2] + red[3];
  float sc = 1.0f / sqrtf(ss * (1.0f / 1024.0f) + 1e-6f);
  float4 wv = *(const float4*)&w[tid * 4];
  float4 o; o.x = wv.x*v.x*sc; o.y = wv.y*v.y*sc; o.z = wv.z*v.z*sc; o.w = wv.w*v.w*sc;
  *(float4*)&outf[(size_t)row * D_ + tid * 4] = o;
  ushort4 ob; ob.x = f2b(o.x); ob.y = f2b(o.y); ob.z = f2b(o.z); ob.w = f2b(o.w);
  *(ushort4*)&outb[(size_t)row * D_ + tid * 4] = ob;
}

// ---------------- LayerNorm on latent (f32 in -> bf16 out, 512 cols) ----------------
__global__ __launch_bounds__(256) void k_lnb(const float* __restrict__ lat, const float* __restrict__ g,
                                             const float* __restrict__ bb, u16* __restrict__ ob) {
  int row = blockIdx.x, tid = threadIdx.x;
  const float* r = lat + (size_t)row * KV_;
  float v0 = r[tid], v1 = r[tid + 256];
  float s = v0 + v1;
  #pragma unroll
  for (int m = 32; m >= 1; m >>= 1) s += __shfl_xor(s, m, 64);
  __shared__ float red[4];
  if ((tid & 63) == 0) red[tid >> 6] = s;
  __syncthreads();
  float mu = (red[0] + red[1] + red[2] + red[3]) * (1.0f / 512.0f);
  __syncthreads();
  float d0 = v0 - mu, d1 = v1 - mu;
  float ss = d0*d0 + d1*d1;
  #pragma unroll
  for (int m = 32; m >= 1; m >>= 1) ss += __shfl_xor(ss, m, 64);
  if ((tid & 63) == 0) red[tid >> 6] = ss;
  __syncthreads();
  float var = (red[0] + red[1] + red[2] + red[3]) * (1.0f / 512.0f);
  float sc = 1.0f / sqrtf(var + 1e-5f);
  ob[(size_t)row * KV_ + tid]       = f2b(d0 * sc * g[tid]       + bb[tid]);
  ob[(size_t)row * KV_ + tid + 256] = f2b(d1 * sc * g[tid + 256] + bb[tid + 256]);
}

// ---------------- bf16 MFMA GEMM: C_f32[M,N] = A_bf16[M,K] @ Bw_f32[N,K]^T (+resid) ----------------
// Register double-buffer: global loads for K-tile t+1 issued before MFMA of tile t.
__global__ __launch_bounds__(256) void k_gemmbf(const u16* __restrict__ A, const float* __restrict__ Bw,
                                                const float* __restrict__ resid, float* __restrict__ C,
                                                int N, int K) {
  int nt = blockIdx.x, mt = blockIdx.y;
  __shared__ __align__(16) u16 As[64][72];
  __shared__ __align__(16) u16 Bs[64][72];
  int tid = threadIdx.x, lane = tid & 63, wave = tid >> 6;
  int wm = (wave >> 1) * 32, wn = (wave & 1) * 32;
  int lr = tid >> 2, lc = (tid & 3) * 16;
  const u16* arow = A + (size_t)(mt * 64 + lr) * K + lc;
  const float* brow = Bw + (size_t)(nt * 64 + lr) * K + lc;
  floatx4 z = {0.f, 0.f, 0.f, 0.f};
  floatx4 acc00 = z, acc01 = z, acc10 = z, acc11 = z;
  int fm = lane & 15, fkq = (lane >> 4) * 8;
  uint4 ra0 = *(const uint4*)&arow[0];
  uint4 ra1 = *(const uint4*)&arow[8];
  float4 rb0 = *(const float4*)&brow[0],  rb1 = *(const float4*)&brow[4];
  float4 rb2 = *(const float4*)&brow[8],  rb3 = *(const float4*)&brow[12];
  for (int kb = 0; kb < K; kb += 64) {
    *(uint4*)&As[lr][lc]     = ra0;
    *(uint4*)&As[lr][lc + 8] = ra1;
    ushort4 u;
    u.x = f2b(rb0.x); u.y = f2b(rb0.y); u.z = f2b(rb0.z); u.w = f2b(rb0.w); *(ushort4*)&Bs[lr][lc]      = u;
    u.x = f2b(rb1.x); u.y = f2b(rb1.y); u.z = f2b(rb1.z); u.w = f2b(rb1.w); *(ushort4*)&Bs[lr][lc + 4]  = u;
    u.x = f2b(rb2.x); u.y = f2b(rb2.y); u.z = f2b(rb2.z); u.w = f2b(rb2.w); *(ushort4*)&Bs[lr][lc + 8]  = u;
    u.x = f2b(rb3.x); u.y = f2b(rb3.y); u.z = f2b(rb3.z); u.w = f2b(rb3.w); *(ushort4*)&Bs[lr][lc + 12] = u;
    __syncthreads();
    if (kb + 64 < K) {
      ra0 = *(const uint4*)&arow[kb + 64];
      ra1 = *(const uint4*)&arow[kb + 72];
      rb0 = *(const float4*)&brow[kb + 64];
      rb1 = *(const float4*)&brow[kb + 68];
      rb2 = *(const float4*)&brow[kb + 72];
      rb3 = *(const float4*)&brow[kb + 76];
    }
    #pragma unroll
    for (int ks = 0; ks < 64; ks += 32) {
      shortx8 a0  = *(const shortx8*)&As[wm + fm][ks + fkq];
      shortx8 a1  = *(const shortx8*)&As[wm + 16 + fm][ks + fkq];
      shortx8 b0  = *(const shortx8*)&Bs[wn + fm][ks + fkq];
      shortx8 b1v = *(const shortx8*)&Bs[wn + 16 + fm][ks + fkq];
      acc00 = __builtin_amdgcn_mfma_f32_16x16x32_bf16(a0, b0,  acc00, 0, 0, 0);
      acc01 = __builtin_amdgcn_mfma_f32_16x16x32_bf16(a0, b1v, acc01, 0, 0, 0);
      acc10 = __builtin_amdgcn_mfma_f32_16x16x32_bf16(a1, b0,  acc10, 0, 0, 0);
      acc11 = __builtin_amdgcn_mfma_f32_16x16x32_bf16(a1, b1v, acc11, 0, 0, 0);
    }
    __syncthreads();
  }
  int q4 = (lane >> 4) * 4, cix = lane & 15;
  #pragma unroll
  for (int im = 0; im < 2; ++im) {
    #pragma unroll
    for (int rg = 0; rg < 4; ++rg) {
      int row = mt * 64 + wm + im * 16 + q4 + rg;
      #pragma unroll
      for (int in = 0; in < 2; ++in) {
        int gn = nt * 64 + wn + in * 16 + cix;
        float vv = (im == 0 ? (in == 0 ? acc00[rg] : acc01[rg]) : (in == 0 ? acc10[rg] : acc11[rg]));
        size_t idx = (size_t)row * N + gn;
        if (resid) vv += resid[idx];
        C[idx] = vv;
      }
    }
  }
}

// ---------------- bf16 MFMA GEMM variant: bf16 out, no residual ----------------
__global__ __launch_bounds__(256) void k_gemmbf_b(const u16* __restrict__ A, const float* __restrict__ Bw,
                                                  u16* __restrict__ Cb, int N, int K) {
  int nt = blockIdx.x, mt = blockIdx.y;
  __shared__ __align__(16) u16 As[64][72];
  __shared__ __align__(16) u16 Bs[64][72];
  int tid = threadIdx.x, lane = tid & 63, wave = tid >> 6;
  int wm = (wave >> 1) * 32, wn = (wave & 1) * 32;
  int lr = tid >> 2, lc = (tid & 3) * 16;
  const u16* arow = A + (size_t)(mt * 64 + lr) * K + lc;
  const float* brow = Bw + (size_t)(nt * 64 + lr) * K + lc;
  floatx4 z = {0.f, 0.f, 0.f, 0.f};
  floatx4 acc00 = z, acc01 = z, acc10 = z, acc11 = z;
  int fm = lane & 15, fkq = (lane >> 4) * 8;
  uint4 ra0 = *(const uint4*)&arow[0];
  uint4 ra1 = *(const uint4*)&arow[8];
  float4 rb0 = *(const float4*)&brow[0],  rb1 = *(const float4*)&brow[4];
  float4 rb2 = *(const float4*)&brow[8],  rb3 = *(const float4*)&brow[12];
  for (int kb = 0; kb < K; kb += 64) {
    *(uint4*)&As[lr][lc]     = ra0;
    *(uint4*)&As[lr][lc + 8] = ra1;
    ushort4 u;
    u.x = f2b(rb0.x); u.y = f2b(rb0.y); u.z = f2b(rb0.z); u.w = f2b(rb0.w); *(ushort4*)&Bs[lr][lc]      = u;
    u.x = f2b(rb1.x); u.y = f2b(rb1.y); u.z = f2b(rb1.z); u.w = f2b(rb1.w); *(ushort4*)&Bs[lr][lc + 4]  = u;
    u.x = f2b(rb2.x); u.y = f2b(rb2.y); u.z = f2b(rb2.z); u.w = f2b(rb2.w); *(ushort4*)&Bs[lr][lc + 8]  = u;
    u.x = f2b(rb3.x); u.y = f2b(rb3.y); u.z = f2b(rb3.z); u.w = f2b(rb3.w); *(ushort4*)&Bs[lr][lc + 12] = u;
    __syncthreads();
    if (kb + 64 < K) {
      ra0 = *(const uint4*)&arow[kb + 64];
      ra1 = *(const uint4*)&arow[kb + 72];
      rb0 = *(const float4*)&brow[kb + 64];
      rb1 = *(const float4*)&brow[kb + 68];
      rb2 = *(const float4*)&brow[kb + 72];
      rb3 = *(const float4*)&brow[kb + 76];
    }
    #pragma unroll
    for (int ks = 0; ks < 64; ks += 32) {
      shortx8 a0  = *(const shortx8*)&As[wm + fm][ks + fkq];
      shortx8 a1  = *(const shortx8*)&As[wm + 16 + fm][ks + fkq];
      shortx8 b0  = *(const shortx8*)&Bs[wn + fm][ks + fkq];
      shortx8 b1v = *(const shortx8*)&Bs[wn + 16 + fm][ks + fkq];
      acc00 = __builtin_amdgcn_mfma_f32_16x16x32_bf16(a0, b0,  acc00, 0, 0, 0);
      acc01 = __builtin_amdgcn_mfma_f32_16x16x32_bf16(a0, b1v, acc01, 0, 0, 0);
      acc10 = __builtin_amdgcn_mfma_f32_16x16x32_bf16(a1, b0,  acc10, 0, 0, 0);
      acc11 = __builtin_amdgcn_mfma_f32_16x16x32_bf16(a1, b1v, acc11, 0, 0, 0);
    }
    __syncthreads();
  }
  int q4 = (lane >> 4) * 4, cix = lane & 15;
  #pragma unroll
  for (int im = 0; im < 2; ++im) {
    #pragma unroll
    for (int rg = 0; rg < 4; ++rg) {
      int row = mt * 64 + wm + im * 16 + q4 + rg;
      #pragma unroll
      for (int in = 0; in < 2; ++in) {
        int gn = nt * 64 + wn + in * 16 + cix;
        float vv = (im == 0 ? (in == 0 ? acc00[rg] : acc01[rg]) : (in == 0 ? acc10[rg] : acc11[rg]));
        Cb[(size_t)row * N + gn] = f2b(vv);
      }
    }
  }
}

// ---------------- RoPE: f32 q,k in -> bf16 qb (pre-scaled 1/8), kb out ----------------
__global__ __launch_bounds__(256) void k_rope2b(const float* __restrict__ q, const float* __restrict__ k,
                                                u16* __restrict__ qb, u16* __restrict__ kb) {
  int g = blockIdx.x * 256 + threadIdx.x;
  int j = g & 31;
  int h = (g >> 5) & 15;
  int row = g >> 9;
  int t = row & (T_ - 1);
  float p = (float)pow(10000.0, (double)j * (1.0 / 32.0));
  float ang = (float)t / p;
  float sn, cs; sincosf(ang, &sn, &cs);
  size_t base = (size_t)row * D_ + h * 64 + j;
  float x1 = q[base], x2 = q[base + 32];
  qb[base]      = f2b((x1 * cs - x2 * sn) * 0.125f);
  qb[base + 32] = f2b((x1 * sn + x2 * cs) * 0.125f);
  x1 = k[base]; x2 = k[base + 32];
  kb[base]      = f2b(x1 * cs - x2 * sn);
  kb[base + 32] = f2b(x1 * sn + x2 * cs);
}

// ---------------- Flash attention, bf16 MFMA, 64-row q-tile per block ----------------
__global__ __launch_bounds__(256) void k_fattn(const u16* __restrict__ qbp, const u16* __restrict__ kbp,
                                               const u16* __restrict__ vbp, u16* __restrict__ ob) {
  int idx = blockIdx.x, h = blockIdx.y;
  int b = idx >> 4;
  int qt = idx & 15;
  if (b) qt = 15 - qt;  // complementary pairing: co-resident pair sums to 17 k-tiles
  __shared__ __align__(16) u16 Qs[64][72];   // [q][d] bf16 (A-operand), pre-scaled 1/8
  __shared__ __align__(16) u16 Ks[64][72];   // [k][d] bf16 (B-operand)
  __shared__ __align__(16) u16 Vs[64][72];   // [d][k] bf16 transposed (B-operand for PV)
  __shared__ __align__(16) u16 Ps[64][72];   // [q][k] bf16 (A-operand for PV)
  __shared__ float red1[2][64];
  __shared__ float red2[2][64];
  int tid = threadIdx.x, lane = tid & 63, wave = tid >> 6;
  int wm = (wave >> 1) * 32, wn = (wave & 1) * 32, w1 = wave & 1;
  int fm = lane & 15, fkq = (lane >> 4) * 8;
  int q4 = (lane >> 4) * 4, cix = lane & 15;
  size_t rowbase = (size_t)b * T_;
  int colbase = h * HD_;
  int q0 = qt * 64;
  int lr = tid >> 2, ld = (tid & 3) * 16;
  {
    const u16* qr = qbp + (rowbase + q0 + lr) * D_ + colbase + ld;
    *(uint4*)&Qs[lr][ld]     = *(const uint4*)&qr[0];
    *(uint4*)&Qs[lr][ld + 8] = *(const uint4*)&qr[8];
  }
  floatx4 z = {0.f, 0.f, 0.f, 0.f};
  floatx4 s[2][2], o[2][2];
  o[0][0] = z; o[0][1] = z; o[1][0] = z; o[1][1] = z;
  float m[2][4], l[2][4], f_[2][4];
  #pragma unroll
  for (int im = 0; im < 2; ++im)
    #pragma unroll
    for (int rg = 0; rg < 4; ++rg) { m[im][rg] = NEGBIG; l[im][rg] = 0.f; }
  for (int kt = 0; kt <= qt; ++kt) {
    __syncthreads();  // prev PV done; staging buffers free (Q-stage covered on first iter)
    {
      const u16* kr = kbp + (rowbase + kt * 64 + lr) * D_ + colbase + ld;
      *(uint4*)&Ks[lr][ld]     = *(const uint4*)&kr[0];
      *(uint4*)&Ks[lr][ld + 8] = *(const uint4*)&kr[8];
      const u16* vr = vbp + (rowbase + kt * 64 + lr) * D_ + colbase + ld;
      #pragma unroll
      for (int c = 0; c < 16; ++c) Vs[ld + c][lr] = vr[c];
    }
    __syncthreads();
    s[0][0] = z; s[0][1] = z; s[1][0] = z; s[1][1] = z;
    #pragma unroll
    for (int ks = 0; ks < 64; ks += 32) {
      shortx8 a0  = *(const shortx8*)&Qs[wm + fm][ks + fkq];
      shortx8 a1  = *(const shortx8*)&Qs[wm + 16 + fm][ks + fkq];
      shortx8 b0  = *(const shortx8*)&Ks[wn + fm][ks + fkq];
      shortx8 b1v = *(const shortx8*)&Ks[wn + 16 + fm][ks + fkq];
      s[0][0] = __builtin_amdgcn_mfma_f32_16x16x32_bf16(a0, b0,  s[0][0], 0, 0, 0);
      s[0][1] = __builtin_amdgcn_mfma_f32_16x16x32_bf16(a0, b1v, s[0][1], 0, 0, 0);
      s[1][0] = __builtin_amdgcn_mfma_f32_16x16x32_bf16(a1, b0,  s[1][0], 0, 0, 0);
      s[1][1] = __builtin_amdgcn_mfma_f32_16x16x32_bf16(a1, b1v, s[1][1], 0, 0, 0);
    }
    if (kt == qt) {  // diagonal tile: local-index causal mask
      #pragma unroll
      for (int im = 0; im < 2; ++im)
        #pragma unroll
        for (int rg = 0; rg < 4; ++rg) {
          int r = wm + im * 16 + q4 + rg;
          #pragma unroll
          for (int in = 0; in < 2; ++in)
            if (wn + in * 16 + cix > r) s[im][in][rg] = NEGBIG;
        }
    }
    // row-max partial over this wave's 32 cols (shfl across the 16-lane col group)
    #pragma unroll
    for (int im = 0; im < 2; ++im)
      #pragma unroll
      for (int rg = 0; rg < 4; ++rg) {
        float pm = fmaxf(s[im][0][rg], s[im][1][rg]);
        #pragma unroll
        for (int mk = 8; mk >= 1; mk >>= 1) pm = fmaxf(pm, __shfl_xor(pm, mk, 64));
        if (cix == 0) red1[w1][wm + im * 16 + q4 + rg] = pm;
        f_[im][rg] = pm;  // stash partial max
      }
    __syncthreads();
    #pragma unroll
    for (int im = 0; im < 2; ++im)
      #pragma unroll
      for (int rg = 0; rg < 4; ++rg) {
        int r = wm + im * 16 + q4 + rg;
        float mx = fmaxf(f_[im][rg], red1[w1 ^ 1][r]);
        float mn = fmaxf(m[im][rg], mx);
        float f = __expf(m[im][rg] - mn);
        m[im][rg] = mn;
        float p0 = __expf(s[im][0][rg] - mn);
        float p1 = __expf(s[im][1][rg] - mn);
        float ss = p0 + p1;
        #pragma unroll
        for (int mk = 8; mk >= 1; mk >>= 1) ss += __shfl_xor(ss, mk, 64);
        if (cix == 0) red2[w1][r] = ss;
        Ps[r][wn + cix]      = f2b(p0);
        Ps[r][wn + 16 + cix] = f2b(p1);
        l[im][rg] *= f;
        o[im][0][rg] *= f;
        o[im][1][rg] *= f;
      }
    __syncthreads();  // Ps/red2 complete from all waves
    #pragma unroll
    for (int im = 0; im < 2; ++im)
      #pragma unroll
      for (int rg = 0; rg < 4; ++rg) {
        int r = wm + im * 16 + q4 + rg;
        l[im][rg] += red2[0][r] + red2[1][r];
      }
    #pragma unroll
    for (int ks = 0; ks < 64; ks += 32) {
      shortx8 a0  = *(const shortx8*)&Ps[wm + fm][ks + fkq];
      shortx8 a1  = *(const shortx8*)&Ps[wm + 16 + fm][ks + fkq];
      shortx8 b0  = *(const shortx8*)&Vs[wn + fm][ks + fkq];
      shortx8 b1v = *(const shortx8*)&Vs[wn + 16 + fm][ks + fkq];
      o[0][0] = __builtin_amdgcn_mfma_f32_16x16x32_bf16(a0, b0,  o[0][0], 0, 0, 0);
      o[0][1] = __builtin_amdgcn_mfma_f32_16x16x32_bf16(a0, b1v, o[0][1], 0, 0, 0);
      o[1][0] = __builtin_amdgcn_mfma_f32_16x16x32_bf16(a1, b0,  o[1][0], 0, 0, 0);
      o[1][1] = __builtin_amdgcn_mfma_f32_16x16x32_bf16(a1, b1v, o[1][1], 0, 0, 0);
    }
  }
  #pragma unroll
  for (int im = 0; im < 2; ++im)
    #pragma unroll
    for (int rg = 0; rg < 4; ++rg) {
      int r = wm + im * 16 + q4 + rg;
      float inv = 1.0f / l[im][rg];
      size_t base = (rowbase + q0 + r) * D_ + colbase;
      ob[base + wn + cix]      = f2b(o[im][0][rg] * inv);
      ob[base + wn + 16 + cix] = f2b(o[im][1][rg] * inv);
    }
}

// ---------------- MoE gate ----------------
__global__ __launch_bounds__(256) void k_init(int* cnt) { if (threadIdx.x < 4) cnt[threadIdx.x] = 0; }

__global__ __launch_bounds__(256) void k_gate(const float* __restrict__ h2, const float* __restrict__ gw,
                                              const float* __restrict__ gb, int* __restrict__ expert,
                                              int* __restrict__ cnt) {
  int wid = threadIdx.x >> 6, lane = threadIdx.x & 63;
  int t = blockIdx.x * 4 + wid;
  const float* hr = h2 + (size_t)t * D_;
  float a0 = 0, a1 = 0, a2 = 0, a3 = 0;
  for (int c = lane; c < D_; c += 64) {
    float xv = hr[c];
    a0 += xv * gw[c];
    a1 += xv * gw[D_ + c];
    a2 += xv * gw[2 * D_ + c];
    a3 += xv * gw[3 * D_ + c];
  }
  #pragma unroll
  for (int m = 32; m >= 1; m >>= 1) {
    a0 += __shfl_xor(a0, m, 64); a1 += __shfl_xor(a1, m, 64);
    a2 += __shfl_xor(a2, m, 64); a3 += __shfl_xor(a3, m, 64);
  }
  if (lane == 0) {
    float l0 = a0 + gb[0], l1 = a1 + gb[1], l2 = a2 + gb[2], l3 = a3 + gb[3];
    int best = 0; float bv = l0;
    if (l1 > bv) { bv = l1; best = 1; }
    if (l2 > bv) { bv = l2; best = 2; }
    if (l3 > bv) { bv = l3; best = 3; }
    expert[t] = best;
    atomicAdd(&cnt[best], 1);
  }
}

__global__ __launch_bounds__(256) void k_scatter(const int* __restrict__ expert, const int* __restrict__ cnt,
                                                 int* __restrict__ off, int* __restrict__ sorted) {
  __shared__ int cur[4];
  if (threadIdx.x == 0) {
    int o0 = 0, o1 = cnt[0], o2 = o1 + cnt[1], o3 = o2 + cnt[2];
    off[0] = o0; off[1] = o1; off[2] = o2; off[3] = o3;
    cur[0] = o0; cur[1] = o1; cur[2] = o2; cur[3] = o3;
  }
  __syncthreads();
  for (int t = threadIdx.x; t < M_; t += 256) {
    int e = expert[t];
    int p = atomicAdd(&cur[e], 1);
    sorted[p] = t;
  }
}

// ---------------- MoE MFMA GEMM 1: hbuf = bf16(relu(h2b[gather] @ W1[e]^T + b1[e])) ----------------
__global__ __launch_bounds__(256) void k_moe1(const u16* __restrict__ A, const float* __restrict__ W1,
                                              const float* __restrict__ b1, const int* __restrict__ cnt,
                                              const int* __restrict__ off, const int* __restrict__ sorted,
                                              u16* __restrict__ hbuf) {
  int e = blockIdx.z, mt = blockIdx.y, nt = blockIdx.x;
  int rem = cnt[e] - mt * 64;
  if (rem <= 0) return;
  __shared__ __align__(16) u16 As[64][72];
  __shared__ __align__(16) u16 Bs[64][72];
  int tid = threadIdx.x, lane = tid & 63, wave = tid >> 6;
  int wm = (wave >> 1) * 32, wn = (wave & 1) * 32;
  int lr = tid >> 2, lc = (tid & 3) * 16;
  int rr = lr < rem ? lr : rem - 1;
  const u16* arow = A + (size_t)sorted[off[e] + mt * 64 + rr] * D_ + lc;
  const float* brow = W1 + (size_t)e * DH_ * D_ + (size_t)(nt * 64 + lr) * D_ + lc;
  floatx4 z = {0.f, 0.f, 0.f, 0.f};
  floatx4 acc00 = z, acc01 = z, acc10 = z, acc11 = z;
  int fm = lane & 15, fkq = (lane >> 4) * 8;
  uint4 ra0 = *(const uint4*)&arow[0];
  uint4 ra1 = *(const uint4*)&arow[8];
  float4 rb0 = *(const float4*)&brow[0],  rb1 = *(const float4*)&brow[4];
  float4 rb2 = *(const float4*)&brow[8],  rb3 = *(const float4*)&brow[12];
  for (int kb = 0; kb < D_; kb += 64) {
    *(uint4*)&As[lr][lc]     = ra0;
    *(uint4*)&As[lr][lc + 8] = ra1;
    ushort4 u;
    u.x = f2b(rb0.x); u.y = f2b(rb0.y); u.z = f2b(rb0.z); u.w = f2b(rb0.w); *(ushort4*)&Bs[lr][lc]      = u;
    u.x = f2b(rb1.x); u.y = f2b(rb1.y); u.z = f2b(rb1.z); u.w = f2b(rb1.w); *(ushort4*)&Bs[lr][lc + 4]  = u;
    u.x = f2b(rb2.x); u.y = f2b(rb2.y); u.z = f2b(rb2.z); u.w = f2b(rb2.w); *(ushort4*)&Bs[lr][lc + 8]  = u;
    u.x = f2b(rb3.x); u.y = f2b(rb3.y); u.z = f2b(rb3.z); u.w = f2b(rb3.w); *(ushort4*)&Bs[lr][lc + 12] = u;
    __syncthreads();
    if (kb + 64 < D_) {
      ra0 = *(const uint4*)&arow[kb + 64];
      ra1 = *(const uint4*)&arow[kb + 72];
      rb0 = *(const float4*)&brow[kb + 64];
      rb1 = *(const float4*)&brow[kb + 68];
      rb2 = *(const float4*)&brow[kb + 72];
      rb3 = *(const float4*)&brow[kb + 76];
    }
    #pragma unroll
    for (int ks = 0; ks < 64; ks += 32) {
      shortx8 a0  = *(const shortx8*)&As[wm + fm][ks + fkq];
      shortx8 a1  = *(const shortx8*)&As[wm + 16 + fm][ks + fkq];
      shortx8 b0  = *(const shortx8*)&Bs[wn + fm][ks + fkq];
      shortx8 b1v = *(const shortx8*)&Bs[wn + 16 + fm][ks + fkq];
      acc00 = __builtin_amdgcn_mfma_f32_16x16x32_bf16(a0, b0,  acc00, 0, 0, 0);
      acc01 = __builtin_amdgcn_mfma_f32_16x16x32_bf16(a0, b1v, acc01, 0, 0, 0);
      acc10 = __builtin_amdgcn_mfma_f32_16x16x32_bf16(a1, b0,  acc10, 0, 0, 0);
      acc11 = __builtin_amdgcn_mfma_f32_16x16x32_bf16(a1, b1v, acc11, 0, 0, 0);
    }
    __syncthreads();
  }
  int q4 = (lane >> 4) * 4, cix = lane & 15;
  #pragma unroll
  for (int im = 0; im < 2; ++im) {
    #pragma unroll
    for (int rg = 0; rg < 4; ++rg) {
      int ml = wm + im * 16 + q4 + rg;
      if (ml >= rem) continue;
      size_t grow = (size_t)(off[e] + mt * 64 + ml);
      #pragma unroll
      for (int in = 0; in < 2; ++in) {
        int gn = nt * 64 + wn + in * 16 + cix;
        float vv = (im == 0 ? (in == 0 ? acc00[rg] : acc01[rg]) : (in == 0 ? acc10[rg] : acc11[rg]));
        vv += b1[e * DH_ + gn];
        hbuf[grow * DH_ + gn] = f2b(fmaxf(vv, 0.f));
      }
    }
  }
}

// ---------------- MoE MFMA GEMM 2: out_f32 = x1 + hbuf @ W2[e]^T + b2[e] ----------------
__global__ __launch_bounds__(256) void k_moe2(const u16* __restrict__ hbuf, const float* __restrict__ W2,
                                              const float* __restrict__ b2w, const float* __restrict__ x1f,
                                              const int* __restrict__ cnt, const int* __restrict__ off,
                                              const int* __restrict__ sorted, float* __restrict__ out) {
  int e = blockIdx.z, mt = blockIdx.y, nt = blockIdx.x;
  int rem = cnt[e] - mt * 64;
  if (rem <= 0) return;
  __shared__ __align__(16) u16 As[64][72];
  __shared__ __align__(16) u16 Bs[64][72];
  int tid = threadIdx.x, lane = tid & 63, wave = tid >> 6;
  int wm = (wave >> 1) * 32, wn = (wave & 1) * 32;
  int lr = tid >> 2, lc = (tid & 3) * 16;
  int rr = lr < rem ? lr : rem - 1;
  const u16* arow = hbuf + (size_t)(off[e] + mt * 64 + rr) * DH_ + lc;
  const float* brow = W2 + (size_t)e * D_ * DH_ + (size_t)(nt * 64 + lr) * DH_ + lc;
  floatx4 z = {0.f, 0.f, 0.f, 0.f};
  floatx4 acc00 = z, acc01 = z, acc10 = z, acc11 = z;
  int fm = lane & 15, fkq = (lane >> 4) * 8;
  uint4 ra0 = *(const uint4*)&arow[0];
  uint4 ra1 = *(const uint4*)&arow[8];
  float4 rb0 = *(const float4*)&brow[0],  rb1 = *(const float4*)&brow[4];
  float4 rb2 = *(const float4*)&brow[8],  rb3 = *(const float4*)&brow[12];
  for (int kb = 0; kb < DH_; kb += 64) {
    *(uint4*)&As[lr][lc]     = ra0;
    *(uint4*)&As[lr][lc + 8] = ra1;
    ushort4 u;
    u.x = f2b(rb0.x); u.y = f2b(rb0.y); u.z = f2b(rb0.z); u.w = f2b(rb0.w); *(ushort4*)&Bs[lr][lc]      = u;
    u.x = f2b(rb1.x); u.y = f2b(rb1.y); u.z = f2b(rb1.z); u.w = f2b(rb1.w); *(ushort4*)&Bs[lr][lc + 4]  = u;
    u.x = f2b(rb2.x); u.y = f2b(rb2.y); u.z = f2b(rb2.z); u.w = f2b(rb2.w); *(ushort4*)&Bs[lr][lc + 8]  = u;
    u.x = f2b(rb3.x); u.y = f2b(rb3.y); u.z = f2b(rb3.z); u.w = f2b(rb3.w); *(ushort4*)&Bs[lr][lc + 12] = u;
    __syncthreads();
    if (kb + 64 < DH_) {
      ra0 = *(const uint4*)&arow[kb + 64];
      ra1 = *(const uint4*)&arow[kb + 72];
      rb0 = *(const float4*)&brow[kb + 64];
      rb1 = *(const float4*)&brow[kb + 68];
      rb2 = *(const float4*)&brow[kb + 72];
      rb3 = *(const float4*)&brow[kb + 76];
    }
    #pragma unroll
    for (int ks = 0; ks < 64; ks += 32) {
      shortx8 a0  = *(const shortx8*)&As[wm + fm][ks + fkq];
      shortx8 a1  = *(const shortx8*)&As[wm + 16 + fm][ks + fkq];
      shortx8 b0  = *(const shortx8*)&Bs[wn + fm][ks + fkq];
      shortx8 b1v = *(const shortx8*)&Bs[wn + 16 + fm][ks + fkq];
      acc00 = __builtin_amdgcn_mfma_f32_16x16x32_bf16(a0, b0,  acc00, 0, 0, 0);
      acc01 = __builtin_amdgcn_mfma_f32_16x16x32_bf16(a0, b1v, acc01, 0, 0, 0);
      acc10 = __builtin_amdgcn_mfma_f32_16x16x32_bf16(a1, b0,  acc10, 0, 0, 0);
      acc11 = __builtin_amdgcn_mfma_f32_16x16x32_bf16(a1, b1v, acc11, 0, 0, 0);
    }
    __syncthreads();
  }
  int q4 = (lane >> 4) * 4, cix = lane & 15;
  #pragma unroll
  for (int im = 0; im < 2; ++im) {
    #pragma unroll
    for (int rg = 0; rg < 4; ++rg) {
      int ml = wm + im * 16 + q4 + rg;
      if (ml >= rem) continue;
      int tok = sorted[off[e] + mt * 64 + ml];
      #pragma unroll
      for (int in = 0; in < 2; ++in) {
        int gn = nt * 64 + wn + in * 16 + cix;
        float vv = (im == 0 ? (in == 0 ? acc00[rg] : acc01[rg]) : (in == 0 ? acc10[rg] : acc11[rg]));
        out[(size_t)tok * D_ + gn] = vv + b2w[e * D_ + gn] + x1f[(size_t)tok * D_ + gn];
      }
    }
  }
}

extern "C" void kernel_launch(void* const* d_in, const int* in_sizes, int n_in,
                              void* d_out, int out_size, void* d_ws, size_t ws_size,
                              hipStream_t stream) {
  int map[16];
  for (int i = 0; i < 16; ++i) map[i] = i;
  if (n_in == 16 && in_sizes[0] == 16777216) {
    const int mm[16] = {15, 13, 14, 4, 2, 5, 6, 3, 12, 11, 10, 9, 0, 7, 1, 8};
    for (int i = 0; i < 16; ++i) map[i] = mm[i];
  } else if (n_in == 16 && in_sizes[0] == 4096) {
    for (int i = 0; i < 16; ++i) map[i] = 15 - i;
  }
  const float* x    = (const float*)d_in[map[0]];
  const float* n1w  = (const float*)d_in[map[1]];
  const float* n2w  = (const float*)d_in[map[2]];
  const float* Wq   = (const float*)d_in[map[3]];
  const float* Wdkv = (const float*)d_in[map[4]];
  const float* Wuk  = (const float*)d_in[map[5]];
  const float* Wuv  = (const float*)d_in[map[6]];
  const float* Wo   = (const float*)d_in[map[7]];
  const float* lng  = (const float*)d_in[map[8]];
  const float* lnb  = (const float*)d_in[map[9]];
  const float* gw   = (const float*)d_in[map[10]];
  const float* gb   = (const float*)d_in[map[11]];
  const float* W1   = (const float*)d_in[map[12]];
  const float* b1   = (const float*)d_in[map[13]];
  const float* W2   = (const float*)d_in[map[14]];
  const float* b2w  = (const float*)d_in[map[15]];
  float* out = (float*)d_out;
  char* ws = (char*)d_ws;
  const size_t MB = 1ull << 20;
  // Overlay layout, peak 36MB + 20KB:
  //  [0,8)  : qf f32 (Wq -> rope)                 -> x1f f32 (Wo out; residual for moe2)
  //  [8,16) : kf f32 (Wuk -> rope)                -> hbuf.lo bf16 (moe1 -> moe2)
  //  [16,20): latf f32 (Wdkv -> ln)               -> qb bf16 (rope -> fattn)      -> hbuf.mid
  //  [20,24): h1b bf16 (rms1 -> Wq,Wdkv)          -> kb bf16 (rope -> fattn)      -> hbuf.hi
  //  [24,26): latb bf16 (ln -> Wuk,Wuv)           \
  //  [26,30): vb bf16 (Wuv -> fattn)               } -> h2f f32 [24,32) (rms2 -> gate)
  //  [30,34): ab bf16 (fattn -> Wo)               /  (ab[32,34) -> h2b below)
  //  [32,36): h2b bf16 (rms2 -> moe1)
  float* qf   = (float*)(ws + 0);
  float* x1f  = (float*)(ws + 0);
  float* kf   = (float*)(ws + 8 * MB);
  u16*   hbuf = (u16*)(ws + 8 * MB);       // 16MB: [8,24)
  float* latf = (float*)(ws + 16 * MB);
  u16*   qb   = (u16*)(ws + 16 * MB);
  u16*   h1b  = (u16*)(ws + 20 * MB);
  u16*   kb   = (u16*)(ws + 20 * MB);
  u16*   latb = (u16*)(ws + 24 * MB);
  float* h2f  = (float*)(ws + 24 * MB);
  u16*   vb   = (u16*)(ws + 26 * MB);
  u16*   ab   = (u16*)(ws + 30 * MB);
  u16*   h2b  = (u16*)(ws + 32 * MB);
  int*   cnt    = (int*)(ws + 36 * MB);
  int*   off    = cnt + 8;
  int*   expert = cnt + 16;
  int*   sorted = expert + 2048;

  k_rms1b<<<2048, 256, 0, stream>>>(x, n1w, h1b);
  k_gemmbf<<<dim3(16, 32), 256, 0, stream>>>(h1b, Wq, nullptr, qf, 1024, 1024);
  k_gemmbf<<<dim3(8, 32), 256, 0, stream>>>(h1b, Wdkv, nullptr, latf, 512, 1024);
  k_lnb<<<2048, 256, 0, stream>>>(latf, lng, lnb, latb);
  k_gemmbf<<<dim3(16, 32), 256, 0, stream>>>(latb, Wuk, nullptr, kf, 1024, 512);
  k_gemmbf_b<<<dim3(16, 32), 256, 0, stream>>>(latb, Wuv, vb, 1024, 512);
  k_rope2b<<<4096, 256, 0, stream>>>(qf, kf, qb, kb);
  k_fattn<<<dim3(32, 16), 256, 0, stream>>>(qb, kb, vb, ab);
  k_gemmbf<<<dim3(16, 32), 256, 0, stream>>>(ab, Wo, x, x1f, 1024, 1024);
  k_rms2b<<<2048, 256, 0, stream>>>(x1f, n2w, h2f, h2b);
  k_init<<<1, 64, 0, stream>>>(cnt);
  k_gate<<<512, 256, 0, stream>>>(h2f, gw, gb, expert, cnt);
  k_scatter<<<1, 256, 0, stream>>>(expert, cnt, off, sorted);
  k_moe1<<<dim3(64, 32, 4), 256, 0, stream>>>(h2b, W1, b1, cnt, off, sorted, hbuf);
  k_moe2<<<dim3(16, 32, 4), 256, 0, stream>>>(hbuf, W2, b2w, x1f, cnt, off, sorted, out);
}

// Round 5
// 501.105 us; speedup vs baseline: 2.0381x; 1.0876x over previous
//
#include <hip/hip_runtime.h>
#include <hip/hip_bf16.h>
#include <math.h>

typedef unsigned short u16;
typedef __attribute__((ext_vector_type(4))) float floatx4;
typedef __attribute__((ext_vector_type(8))) short shortx8;

#define DEVI static __device__ __forceinline__

DEVI u16 f2b(float f) {
  union { float f; unsigned int i; } v; v.f = f;
  unsigned int x = v.i;
  return (u16)((x + 0x7fffu + ((x >> 16) & 1u)) >> 16);
}

constexpr int T_ = 1024, D_ = 1024, HD_ = 64, KV_ = 512, DH_ = 4096, M_ = 2048;
#define NEGBIG (-1e30f)

// ---------------- RMSNorm (f32 in -> bf16 out) ----------------
__global__ __launch_bounds__(256) void k_rms1b(const float* __restrict__ x, const float* __restrict__ w,
                                               u16* __restrict__ outb) {
  int row = blockIdx.x, tid = threadIdx.x;
  float4 v = *(const float4*)&x[(size_t)row * D_ + tid * 4];
  float ss = v.x*v.x + v.y*v.y + v.z*v.z + v.w*v.w;
  #pragma unroll
  for (int m = 32; m >= 1; m >>= 1) ss += __shfl_xor(ss, m, 64);
  __shared__ float red[4];
  if ((tid & 63) == 0) red[tid >> 6] = ss;
  __syncthreads();
  ss = red[0] + red[1] + red[2] + red[3];
  float sc = 1.0f / sqrtf(ss * (1.0f / 1024.0f) + 1e-6f);
  float4 wv = *(const float4*)&w[tid * 4];
  ushort4 ob;
  ob.x = f2b(wv.x*v.x*sc); ob.y = f2b(wv.y*v.y*sc);
  ob.z = f2b(wv.z*v.z*sc); ob.w = f2b(wv.w*v.w*sc);
  *(ushort4*)&outb[(size_t)row * D_ + tid * 4] = ob;
}

// ---------------- RMSNorm (f32 in -> f32 out + bf16 out) ----------------
__global__ __launch_bounds__(256) void k_rms2b(const float* __restrict__ x, const float* __restrict__ w,
                                               float* __restrict__ outf, u16* __restrict__ outb) {
  int row = blockIdx.x, tid = threadIdx.x;
  float4 v = *(const float4*)&x[(size_t)row * D_ + tid * 4];
  float ss = v.x*v.x + v.y*v.y + v.z*v.z + v.w*v.w;
  #pragma unroll
  for (int m = 32; m >= 1; m >>= 1) ss += __shfl_xor(ss, m, 64);
  __shared__ float red[4];
  if ((tid & 63) == 0) red[tid >> 6] = ss;
  __syncthreads();
  ss = red[0] + red[1] + red[2] + red[3];
  float sc = 1.0f / sqrtf(ss * (1.0f / 1024.0f) + 1e-6f);
  float4 wv = *(const float4*)&w[tid * 4];
  float4 o; o.x = wv.x*v.x*sc; o.y = wv.y*v.y*sc; o.z = wv.z*v.z*sc; o.w = wv.w*v.w*sc;
  *(float4*)&outf[(size_t)row * D_ + tid * 4] = o;
  ushort4 ob; ob.x = f2b(o.x); ob.y = f2b(o.y); ob.z = f2b(o.z); ob.w = f2b(o.w);
  *(ushort4*)&outb[(size_t)row * D_ + tid * 4] = ob;
}

// ---------------- LayerNorm on latent (f32 in -> bf16 out, 512 cols) ----------------
__global__ __launch_bounds__(256) void k_lnb(const float* __restrict__ lat, const float* __restrict__ g,
                                             const float* __restrict__ bb, u16* __restrict__ ob) {
  int row = blockIdx.x, tid = threadIdx.x;
  const float* r = lat + (size_t)row * KV_;
  float v0 = r[tid], v1 = r[tid + 256];
  float s = v0 + v1;
  #pragma unroll
  for (int m = 32; m >= 1; m >>= 1) s += __shfl_xor(s, m, 64);
  __shared__ float red[4];
  if ((tid & 63) == 0) red[tid >> 6] = s;
  __syncthreads();
  float mu = (red[0] + red[1] + red[2] + red[3]) * (1.0f / 512.0f);
  __syncthreads();
  float d0 = v0 - mu, d1 = v1 - mu;
  float ss = d0*d0 + d1*d1;
  #pragma unroll
  for (int m = 32; m >= 1; m >>= 1) ss += __shfl_xor(ss, m, 64);
  if ((tid & 63) == 0) red[tid >> 6] = ss;
  __syncthreads();
  float var = (red[0] + red[1] + red[2] + red[3]) * (1.0f / 512.0f);
  float sc = 1.0f / sqrtf(var + 1e-5f);
  ob[(size_t)row * KV_ + tid]       = f2b(d0 * sc * g[tid]       + bb[tid]);
  ob[(size_t)row * KV_ + tid + 256] = f2b(d1 * sc * g[tid + 256] + bb[tid + 256]);
}

// ---------------- One-shot weight conversion f32 -> bf16 (concatenated dst) ----------------
// float4-unit boundaries: W1[0,4194304) W2[..8388608) Wq[..8650752) Wdkv[..8781824)
// Wuk[..8912896) Wuv[..9043968) Wo[..9306112)
__global__ __launch_bounds__(256) void k_cvtall(const float* __restrict__ W1, const float* __restrict__ W2,
                                                const float* __restrict__ Wq, const float* __restrict__ Wdkv,
                                                const float* __restrict__ Wuk, const float* __restrict__ Wuv,
                                                const float* __restrict__ Wo, u16* __restrict__ dst) {
  for (size_t i = (size_t)blockIdx.x * 256 + threadIdx.x; i < 9306112ull; i += (size_t)gridDim.x * 256) {
    const float* s;
    if      (i < 4194304ull) s = W1   + i * 4;
    else if (i < 8388608ull) s = W2   + (i - 4194304ull) * 4;
    else if (i < 8650752ull) s = Wq   + (i - 8388608ull) * 4;
    else if (i < 8781824ull) s = Wdkv + (i - 8650752ull) * 4;
    else if (i < 8912896ull) s = Wuk  + (i - 8781824ull) * 4;
    else if (i < 9043968ull) s = Wuv  + (i - 8912896ull) * 4;
    else                     s = Wo   + (i - 9043968ull) * 4;
    float4 f = *(const float4*)s;
    ushort4 u; u.x = f2b(f.x); u.y = f2b(f.y); u.z = f2b(f.z); u.w = f2b(f.w);
    *(ushort4*)(dst + i * 4) = u;
  }
}

// ---------------- bf16 MFMA GEMM (templated on B dtype): C[M,N] = A_bf16 @ B[N,K]^T ----------------
// 1D XCD-swizzled grid (grid = NT*32, all mt of an nt-panel land on one XCD -> B panel stays in L2).
// Epilogue: Cb != null -> bf16 store; else f32 store (+resid).
template<int BF16B>
__global__ __launch_bounds__(256) void k_gemm_t(const u16* __restrict__ A, const void* __restrict__ Bp,
                                                const float* __restrict__ resid, float* __restrict__ Cf,
                                                u16* __restrict__ Cb, int N, int K) {
  int bid = blockIdx.x;
  int xcd = bid & 7, jj = bid >> 3;
  int mt = jj & 31, nt = (jj >> 5) * 8 + xcd;
  __shared__ __align__(16) u16 As[64][72];
  __shared__ __align__(16) u16 Bs[64][72];
  int tid = threadIdx.x, lane = tid & 63, wave = tid >> 6;
  int wm = (wave >> 1) * 32, wn = (wave & 1) * 32;
  int lr = tid >> 2, lc = (tid & 3) * 16;
  const u16* arow = A + (size_t)(mt * 64 + lr) * K + lc;
  const u16* browb = (const u16*)Bp + (size_t)(nt * 64 + lr) * K + lc;
  const float* browf = (const float*)Bp + (size_t)(nt * 64 + lr) * K + lc;
  floatx4 z = {0.f, 0.f, 0.f, 0.f};
  floatx4 acc00 = z, acc01 = z, acc10 = z, acc11 = z;
  int fm = lane & 15, fkq = (lane >> 4) * 8;
  uint4 ra0 = *(const uint4*)&arow[0];
  uint4 ra1 = *(const uint4*)&arow[8];
  uint4 rbA, rbB; float4 rb0, rb1, rb2, rb3;
  if constexpr (BF16B) {
    rbA = *(const uint4*)&browb[0]; rbB = *(const uint4*)&browb[8];
  } else {
    rb0 = *(const float4*)&browf[0];  rb1 = *(const float4*)&browf[4];
    rb2 = *(const float4*)&browf[8];  rb3 = *(const float4*)&browf[12];
  }
  for (int kb = 0; kb < K; kb += 64) {
    *(uint4*)&As[lr][lc]     = ra0;
    *(uint4*)&As[lr][lc + 8] = ra1;
    if constexpr (BF16B) {
      *(uint4*)&Bs[lr][lc]     = rbA;
      *(uint4*)&Bs[lr][lc + 8] = rbB;
    } else {
      ushort4 u;
      u.x = f2b(rb0.x); u.y = f2b(rb0.y); u.z = f2b(rb0.z); u.w = f2b(rb0.w); *(ushort4*)&Bs[lr][lc]      = u;
      u.x = f2b(rb1.x); u.y = f2b(rb1.y); u.z = f2b(rb1.z); u.w = f2b(rb1.w); *(ushort4*)&Bs[lr][lc + 4]  = u;
      u.x = f2b(rb2.x); u.y = f2b(rb2.y); u.z = f2b(rb2.z); u.w = f2b(rb2.w); *(ushort4*)&Bs[lr][lc + 8]  = u;
      u.x = f2b(rb3.x); u.y = f2b(rb3.y); u.z = f2b(rb3.z); u.w = f2b(rb3.w); *(ushort4*)&Bs[lr][lc + 12] = u;
    }
    __syncthreads();
    if (kb + 64 < K) {
      ra0 = *(const uint4*)&arow[kb + 64];
      ra1 = *(const uint4*)&arow[kb + 72];
      if constexpr (BF16B) {
        rbA = *(const uint4*)&browb[kb + 64]; rbB = *(const uint4*)&browb[kb + 72];
      } else {
        rb0 = *(const float4*)&browf[kb + 64]; rb1 = *(const float4*)&browf[kb + 68];
        rb2 = *(const float4*)&browf[kb + 72]; rb3 = *(const float4*)&browf[kb + 76];
      }
    }
    #pragma unroll
    for (int ks = 0; ks < 64; ks += 32) {
      shortx8 a0  = *(const shortx8*)&As[wm + fm][ks + fkq];
      shortx8 a1  = *(const shortx8*)&As[wm + 16 + fm][ks + fkq];
      shortx8 b0  = *(const shortx8*)&Bs[wn + fm][ks + fkq];
      shortx8 b1v = *(const shortx8*)&Bs[wn + 16 + fm][ks + fkq];
      acc00 = __builtin_amdgcn_mfma_f32_16x16x32_bf16(a0, b0,  acc00, 0, 0, 0);
      acc01 = __builtin_amdgcn_mfma_f32_16x16x32_bf16(a0, b1v, acc01, 0, 0, 0);
      acc10 = __builtin_amdgcn_mfma_f32_16x16x32_bf16(a1, b0,  acc10, 0, 0, 0);
      acc11 = __builtin_amdgcn_mfma_f32_16x16x32_bf16(a1, b1v, acc11, 0, 0, 0);
    }
    __syncthreads();
  }
  int q4 = (lane >> 4) * 4, cix = lane & 15;
  #pragma unroll
  for (int im = 0; im < 2; ++im) {
    #pragma unroll
    for (int rg = 0; rg < 4; ++rg) {
      int row = mt * 64 + wm + im * 16 + q4 + rg;
      #pragma unroll
      for (int in = 0; in < 2; ++in) {
        int gn = nt * 64 + wn + in * 16 + cix;
        float vv = (im == 0 ? (in == 0 ? acc00[rg] : acc01[rg]) : (in == 0 ? acc10[rg] : acc11[rg]));
        size_t idx = (size_t)row * N + gn;
        if (Cb) {
          Cb[idx] = f2b(vv);
        } else {
          if (resid) vv += resid[idx];
          Cf[idx] = vv;
        }
      }
    }
  }
}

// ---------------- RoPE: f32 q,k in -> bf16 qb (pre-scaled 1/8), kb out ----------------
__global__ __launch_bounds__(256) void k_rope2b(const float* __restrict__ q, const float* __restrict__ k,
                                                u16* __restrict__ qb, u16* __restrict__ kb) {
  int g = blockIdx.x * 256 + threadIdx.x;
  int j = g & 31;
  int h = (g >> 5) & 15;
  int row = g >> 9;
  int t = row & (T_ - 1);
  float p = (float)pow(10000.0, (double)j * (1.0 / 32.0));
  float ang = (float)t / p;
  float sn, cs; sincosf(ang, &sn, &cs);
  size_t base = (size_t)row * D_ + h * 64 + j;
  float x1 = q[base], x2 = q[base + 32];
  qb[base]      = f2b((x1 * cs - x2 * sn) * 0.125f);
  qb[base + 32] = f2b((x1 * sn + x2 * cs) * 0.125f);
  x1 = k[base]; x2 = k[base + 32];
  kb[base]      = f2b(x1 * cs - x2 * sn);
  kb[base + 32] = f2b(x1 * sn + x2 * cs);
}

// ---------------- Flash attention, bf16 MFMA, 64-row q-tile per block ----------------
__global__ __launch_bounds__(256) void k_fattn(const u16* __restrict__ qbp, const u16* __restrict__ kbp,
                                               const u16* __restrict__ vbp, u16* __restrict__ ob) {
  int idx = blockIdx.x, h = blockIdx.y;
  int b = idx >> 4;
  int qt = idx & 15;
  if (b) qt = 15 - qt;  // complementary pairing: co-resident pair sums to 17 k-tiles
  __shared__ __align__(16) u16 Qs[64][72];   // [q][d] bf16 (A-operand), pre-scaled 1/8
  __shared__ __align__(16) u16 Ks[64][72];   // [k][d] bf16 (B-operand)
  __shared__ __align__(16) u16 Vs[64][72];   // [d][k] bf16 transposed (B-operand for PV)
  __shared__ __align__(16) u16 Ps[64][72];   // [q][k] bf16 (A-operand for PV)
  __shared__ float red1[2][64];
  __shared__ float red2[2][64];
  int tid = threadIdx.x, lane = tid & 63, wave = tid >> 6;
  int wm = (wave >> 1) * 32, wn = (wave & 1) * 32, w1 = wave & 1;
  int fm = lane & 15, fkq = (lane >> 4) * 8;
  int q4 = (lane >> 4) * 4, cix = lane & 15;
  size_t rowbase = (size_t)b * T_;
  int colbase = h * HD_;
  int q0 = qt * 64;
  int lr = tid >> 2, ld = (tid & 3) * 16;
  {
    const u16* qr = qbp + (rowbase + q0 + lr) * D_ + colbase + ld;
    *(uint4*)&Qs[lr][ld]     = *(const uint4*)&qr[0];
    *(uint4*)&Qs[lr][ld + 8] = *(const uint4*)&qr[8];
  }
  floatx4 z = {0.f, 0.f, 0.f, 0.f};
  floatx4 s[2][2], o[2][2];
  o[0][0] = z; o[0][1] = z; o[1][0] = z; o[1][1] = z;
  float m[2][4], l[2][4], f_[2][4];
  #pragma unroll
  for (int im = 0; im < 2; ++im)
    #pragma unroll
    for (int rg = 0; rg < 4; ++rg) { m[im][rg] = NEGBIG; l[im][rg] = 0.f; }
  for (int kt = 0; kt <= qt; ++kt) {
    __syncthreads();  // prev PV done; staging buffers free (Q-stage covered on first iter)
    {
      const u16* kr = kbp + (rowbase + kt * 64 + lr) * D_ + colbase + ld;
      *(uint4*)&Ks[lr][ld]     = *(const uint4*)&kr[0];
      *(uint4*)&Ks[lr][ld + 8] = *(const uint4*)&kr[8];
      const u16* vr = vbp + (rowbase + kt * 64 + lr) * D_ + colbase + ld;
      #pragma unroll
      for (int c = 0; c < 16; ++c) Vs[ld + c][lr] = vr[c];
    }
    __syncthreads();
    s[0][0] = z; s[0][1] = z; s[1][0] = z; s[1][1] = z;
    #pragma unroll
    for (int ks = 0; ks < 64; ks += 32) {
      shortx8 a0  = *(const shortx8*)&Qs[wm + fm][ks + fkq];
      shortx8 a1  = *(const shortx8*)&Qs[wm + 16 + fm][ks + fkq];
      shortx8 b0  = *(const shortx8*)&Ks[wn + fm][ks + fkq];
      shortx8 b1v = *(const shortx8*)&Ks[wn + 16 + fm][ks + fkq];
      s[0][0] = __builtin_amdgcn_mfma_f32_16x16x32_bf16(a0, b0,  s[0][0], 0, 0, 0);
      s[0][1] = __builtin_amdgcn_mfma_f32_16x16x32_bf16(a0, b1v, s[0][1], 0, 0, 0);
      s[1][0] = __builtin_amdgcn_mfma_f32_16x16x32_bf16(a1, b0,  s[1][0], 0, 0, 0);
      s[1][1] = __builtin_amdgcn_mfma_f32_16x16x32_bf16(a1, b1v, s[1][1], 0, 0, 0);
    }
    if (kt == qt) {  // diagonal tile: local-index causal mask
      #pragma unroll
      for (int im = 0; im < 2; ++im)
        #pragma unroll
        for (int rg = 0; rg < 4; ++rg) {
          int r = wm + im * 16 + q4 + rg;
          #pragma unroll
          for (int in = 0; in < 2; ++in)
            if (wn + in * 16 + cix > r) s[im][in][rg] = NEGBIG;
        }
    }
    // row-max partial over this wave's 32 cols (shfl across the 16-lane col group)
    #pragma unroll
    for (int im = 0; im < 2; ++im)
      #pragma unroll
      for (int rg = 0; rg < 4; ++rg) {
        float pm = fmaxf(s[im][0][rg], s[im][1][rg]);
        #pragma unroll
        for (int mk = 8; mk >= 1; mk >>= 1) pm = fmaxf(pm, __shfl_xor(pm, mk, 64));
        if (cix == 0) red1[w1][wm + im * 16 + q4 + rg] = pm;
        f_[im][rg] = pm;  // stash partial max
      }
    __syncthreads();
    #pragma unroll
    for (int im = 0; im < 2; ++im)
      #pragma unroll
      for (int rg = 0; rg < 4; ++rg) {
        int r = wm + im * 16 + q4 + rg;
        float mx = fmaxf(f_[im][rg], red1[w1 ^ 1][r]);
        float mn = fmaxf(m[im][rg], mx);
        float f = __expf(m[im][rg] - mn);
        m[im][rg] = mn;
        float p0 = __expf(s[im][0][rg] - mn);
        float p1 = __expf(s[im][1][rg] - mn);
        float ss = p0 + p1;
        #pragma unroll
        for (int mk = 8; mk >= 1; mk >>= 1) ss += __shfl_xor(ss, mk, 64);
        if (cix == 0) red2[w1][r] = ss;
        Ps[r][wn + cix]      = f2b(p0);
        Ps[r][wn + 16 + cix] = f2b(p1);
        l[im][rg] *= f;
        o[im][0][rg] *= f;
        o[im][1][rg] *= f;
      }
    __syncthreads();  // Ps/red2 complete from all waves
    #pragma unroll
    for (int im = 0; im < 2; ++im)
      #pragma unroll
      for (int rg = 0; rg < 4; ++rg) {
        int r = wm + im * 16 + q4 + rg;
        l[im][rg] += red2[0][r] + red2[1][r];
      }
    #pragma unroll
    for (int ks = 0; ks < 64; ks += 32) {
      shortx8 a0  = *(const shortx8*)&Ps[wm + fm][ks + fkq];
      shortx8 a1  = *(const shortx8*)&Ps[wm + 16 + fm][ks + fkq];
      shortx8 b0  = *(const shortx8*)&Vs[wn + fm][ks + fkq];
      shortx8 b1v = *(const shortx8*)&Vs[wn + 16 + fm][ks + fkq];
      o[0][0] = __builtin_amdgcn_mfma_f32_16x16x32_bf16(a0, b0,  o[0][0], 0, 0, 0);
      o[0][1] = __builtin_amdgcn_mfma_f32_16x16x32_bf16(a0, b1v, o[0][1], 0, 0, 0);
      o[1][0] = __builtin_amdgcn_mfma_f32_16x16x32_bf16(a1, b0,  o[1][0], 0, 0, 0);
      o[1][1] = __builtin_amdgcn_mfma_f32_16x16x32_bf16(a1, b1v, o[1][1], 0, 0, 0);
    }
  }
  #pragma unroll
  for (int im = 0; im < 2; ++im)
    #pragma unroll
    for (int rg = 0; rg < 4; ++rg) {
      int r = wm + im * 16 + q4 + rg;
      float inv = 1.0f / l[im][rg];
      size_t base = (rowbase + q0 + r) * D_ + colbase;
      ob[base + wn + cix]      = f2b(o[im][0][rg] * inv);
      ob[base + wn + 16 + cix] = f2b(o[im][1][rg] * inv);
    }
}

// ---------------- MoE gate ----------------
__global__ __launch_bounds__(256) void k_init(int* cnt) { if (threadIdx.x < 4) cnt[threadIdx.x] = 0; }

__global__ __launch_bounds__(256) void k_gate(const float* __restrict__ h2, const float* __restrict__ gw,
                                              const float* __restrict__ gb, int* __restrict__ expert,
                                              int* __restrict__ cnt) {
  int wid = threadIdx.x >> 6, lane = threadIdx.x & 63;
  int t = blockIdx.x * 4 + wid;
  const float* hr = h2 + (size_t)t * D_;
  float a0 = 0, a1 = 0, a2 = 0, a3 = 0;
  for (int c = lane; c < D_; c += 64) {
    float xv = hr[c];
    a0 += xv * gw[c];
    a1 += xv * gw[D_ + c];
    a2 += xv * gw[2 * D_ + c];
    a3 += xv * gw[3 * D_ + c];
  }
  #pragma unroll
  for (int m = 32; m >= 1; m >>= 1) {
    a0 += __shfl_xor(a0, m, 64); a1 += __shfl_xor(a1, m, 64);
    a2 += __shfl_xor(a2, m, 64); a3 += __shfl_xor(a3, m, 64);
  }
  if (lane == 0) {
    float l0 = a0 + gb[0], l1 = a1 + gb[1], l2 = a2 + gb[2], l3 = a3 + gb[3];
    int best = 0; float bv = l0;
    if (l1 > bv) { bv = l1; best = 1; }
    if (l2 > bv) { bv = l2; best = 2; }
    if (l3 > bv) { bv = l3; best = 3; }
    expert[t] = best;
    atomicAdd(&cnt[best], 1);
  }
}

__global__ __launch_bounds__(256) void k_scatter(const int* __restrict__ expert, const int* __restrict__ cnt,
                                                 int* __restrict__ off, int* __restrict__ sorted) {
  __shared__ int cur[4];
  if (threadIdx.x == 0) {
    int o0 = 0, o1 = cnt[0], o2 = o1 + cnt[1], o3 = o2 + cnt[2];
    off[0] = o0; off[1] = o1; off[2] = o2; off[3] = o3;
    cur[0] = o0; cur[1] = o1; cur[2] = o2; cur[3] = o3;
  }
  __syncthreads();
  for (int t = threadIdx.x; t < M_; t += 256) {
    int e = expert[t];
    int p = atomicAdd(&cur[e], 1);
    sorted[p] = t;
  }
}

// ---------------- MoE MFMA GEMM 1 (templated B): hbuf = bf16(relu(A[gather] @ W1[e]^T + b1[e])) ----------------
// 1D XCD-swizzled grid (8192): all mt of (e,nt) on one XCD -> W1 panel L2-resident.
template<int BF16B>
__global__ __launch_bounds__(256) void k_moe1_t(const u16* __restrict__ A, const void* __restrict__ W1p,
                                                const float* __restrict__ b1, const int* __restrict__ cnt,
                                                const int* __restrict__ off, const int* __restrict__ sorted,
                                                u16* __restrict__ hbuf) {
  int bid = blockIdx.x;
  int xcd = bid & 7, jj = bid >> 3;
  int mt = jj & 31, combo = (jj >> 5) * 8 + xcd;   // combo in [0,256)
  int e = combo >> 6, nt = combo & 63;
  int rem = cnt[e] - mt * 64;
  if (rem <= 0) return;
  __shared__ __align__(16) u16 As[64][72];
  __shared__ __align__(16) u16 Bs[64][72];
  int tid = threadIdx.x, lane = tid & 63, wave = tid >> 6;
  int wm = (wave >> 1) * 32, wn = (wave & 1) * 32;
  int lr = tid >> 2, lc = (tid & 3) * 16;
  int rr = lr < rem ? lr : rem - 1;
  const u16* arow = A + (size_t)sorted[off[e] + mt * 64 + rr] * D_ + lc;
  const u16* browb = (const u16*)W1p + (size_t)e * DH_ * D_ + (size_t)(nt * 64 + lr) * D_ + lc;
  const float* browf = (const float*)W1p + (size_t)e * DH_ * D_ + (size_t)(nt * 64 + lr) * D_ + lc;
  floatx4 z = {0.f, 0.f, 0.f, 0.f};
  floatx4 acc00 = z, acc01 = z, acc10 = z, acc11 = z;
  int fm = lane & 15, fkq = (lane >> 4) * 8;
  uint4 ra0 = *(const uint4*)&arow[0];
  uint4 ra1 = *(const uint4*)&arow[8];
  uint4 rbA, rbB; float4 rb0, rb1, rb2, rb3;
  if constexpr (BF16B) {
    rbA = *(const uint4*)&browb[0]; rbB = *(const uint4*)&browb[8];
  } else {
    rb0 = *(const float4*)&browf[0];  rb1 = *(const float4*)&browf[4];
    rb2 = *(const float4*)&browf[8];  rb3 = *(const float4*)&browf[12];
  }
  for (int kb = 0; kb < D_; kb += 64) {
    *(uint4*)&As[lr][lc]     = ra0;
    *(uint4*)&As[lr][lc + 8] = ra1;
    if constexpr (BF16B) {
      *(uint4*)&Bs[lr][lc]     = rbA;
      *(uint4*)&Bs[lr][lc + 8] = rbB;
    } else {
      ushort4 u;
      u.x = f2b(rb0.x); u.y = f2b(rb0.y); u.z = f2b(rb0.z); u.w = f2b(rb0.w); *(ushort4*)&Bs[lr][lc]      = u;
      u.x = f2b(rb1.x); u.y = f2b(rb1.y); u.z = f2b(rb1.z); u.w = f2b(rb1.w); *(ushort4*)&Bs[lr][lc + 4]  = u;
      u.x = f2b(rb2.x); u.y = f2b(rb2.y); u.z = f2b(rb2.z); u.w = f2b(rb2.w); *(ushort4*)&Bs[lr][lc + 8]  = u;
      u.x = f2b(rb3.x); u.y = f2b(rb3.y); u.z = f2b(rb3.z); u.w = f2b(rb3.w); *(ushort4*)&Bs[lr][lc + 12] = u;
    }
    __syncthreads();
    if (kb + 64 < D_) {
      ra0 = *(const uint4*)&arow[kb + 64];
      ra1 = *(const uint4*)&arow[kb + 72];
      if constexpr (BF16B) {
        rbA = *(const uint4*)&browb[kb + 64]; rbB = *(const uint4*)&browb[kb + 72];
      } else {
        rb0 = *(const float4*)&browf[kb + 64]; rb1 = *(const float4*)&browf[kb + 68];
        rb2 = *(const float4*)&browf[kb + 72]; rb3 = *(const float4*)&browf[kb + 76];
      }
    }
    #pragma unroll
    for (int ks = 0; ks < 64; ks += 32) {
      shortx8 a0  = *(const shortx8*)&As[wm + fm][ks + fkq];
      shortx8 a1  = *(const shortx8*)&As[wm + 16 + fm][ks + fkq];
      shortx8 b0  = *(const shortx8*)&Bs[wn + fm][ks + fkq];
      shortx8 b1v = *(const shortx8*)&Bs[wn + 16 + fm][ks + fkq];
      acc00 = __builtin_amdgcn_mfma_f32_16x16x32_bf16(a0, b0,  acc00, 0, 0, 0);
      acc01 = __builtin_amdgcn_mfma_f32_16x16x32_bf16(a0, b1v, acc01, 0, 0, 0);
      acc10 = __builtin_amdgcn_mfma_f32_16x16x32_bf16(a1, b0,  acc10, 0, 0, 0);
      acc11 = __builtin_amdgcn_mfma_f32_16x16x32_bf16(a1, b1v, acc11, 0, 0, 0);
    }
    __syncthreads();
  }
  int q4 = (lane >> 4) * 4, cix = lane & 15;
  #pragma unroll
  for (int im = 0; im < 2; ++im) {
    #pragma unroll
    for (int rg = 0; rg < 4; ++rg) {
      int ml = wm + im * 16 + q4 + rg;
      if (ml >= rem) continue;
      size_t grow = (size_t)(off[e] + mt * 64 + ml);
      #pragma unroll
      for (int in = 0; in < 2; ++in) {
        int gn = nt * 64 + wn + in * 16 + cix;
        float vv = (im == 0 ? (in == 0 ? acc00[rg] : acc01[rg]) : (in == 0 ? acc10[rg] : acc11[rg]));
        vv += b1[e * DH_ + gn];
        hbuf[grow * DH_ + gn] = f2b(fmaxf(vv, 0.f));
      }
    }
  }
}

// ---------------- MoE MFMA GEMM 2 (templated B): out_f32 = x1 + hbuf @ W2[e]^T + b2[e] ----------------
// 1D XCD-swizzled grid (2048).
template<int BF16B>
__global__ __launch_bounds__(256) void k_moe2_t(const u16* __restrict__ hbuf, const void* __restrict__ W2p,
                                                const float* __restrict__ b2w, const float* __restrict__ x1f,
                                                const int* __restrict__ cnt, const int* __restrict__ off,
                                                const int* __restrict__ sorted, float* __restrict__ out) {
  int bid = blockIdx.x;
  int xcd = bid & 7, jj = bid >> 3;
  int mt = jj & 31, combo = (jj >> 5) * 8 + xcd;   // combo in [0,64)
  int e = combo >> 4, nt = combo & 15;
  int rem = cnt[e] - mt * 64;
  if (rem <= 0) return;
  __shared__ __align__(16) u16 As[64][72];
  __shared__ __align__(16) u16 Bs[64][72];
  int tid = threadIdx.x, lane = tid & 63, wave = tid >> 6;
  int wm = (wave >> 1) * 32, wn = (wave & 1) * 32;
  int lr = tid >> 2, lc = (tid & 3) * 16;
  int rr = lr < rem ? lr : rem - 1;
  const u16* arow = hbuf + (size_t)(off[e] + mt * 64 + rr) * DH_ + lc;
  const u16* browb = (const u16*)W2p + (size_t)e * D_ * DH_ + (size_t)(nt * 64 + lr) * DH_ + lc;
  const float* browf = (const float*)W2p + (size_t)e * D_ * DH_ + (size_t)(nt * 64 + lr) * DH_ + lc;
  floatx4 z = {0.f, 0.f, 0.f, 0.f};
  floatx4 acc00 = z, acc01 = z, acc10 = z, acc11 = z;
  int fm = lane & 15, fkq = (lane >> 4) * 8;
  uint4 ra0 = *(const uint4*)&arow[0];
  uint4 ra1 = *(const uint4*)&arow[8];
  uint4 rbA, rbB; float4 rb0, rb1, rb2, rb3;
  if constexpr (BF16B) {
    rbA = *(const uint4*)&browb[0]; rbB = *(const uint4*)&browb[8];
  } else {
    rb0 = *(const float4*)&browf[0];  rb1 = *(const float4*)&browf[4];
    rb2 = *(const float4*)&browf[8];  rb3 = *(const float4*)&browf[12];
  }
  for (int kb = 0; kb < DH_; kb += 64) {
    *(uint4*)&As[lr][lc]     = ra0;
    *(uint4*)&As[lr][lc + 8] = ra1;
    if constexpr (BF16B) {
      *(uint4*)&Bs[lr][lc]     = rbA;
      *(uint4*)&Bs[lr][lc + 8] = rbB;
    } else {
      ushort4 u;
      u.x = f2b(rb0.x); u.y = f2b(rb0.y); u.z = f2b(rb0.z); u.w = f2b(rb0.w); *(ushort4*)&Bs[lr][lc]      = u;
      u.x = f2b(rb1.x); u.y = f2b(rb1.y); u.z = f2b(rb1.z); u.w = f2b(rb1.w); *(ushort4*)&Bs[lr][lc + 4]  = u;
      u.x = f2b(rb2.x); u.y = f2b(rb2.y); u.z = f2b(rb2.z); u.w = f2b(rb2.w); *(ushort4*)&Bs[lr][lc + 8]  = u;
      u.x = f2b(rb3.x); u.y = f2b(rb3.y); u.z = f2b(rb3.z); u.w = f2b(rb3.w); *(ushort4*)&Bs[lr][lc + 12] = u;
    }
    __syncthreads();
    if (kb + 64 < DH_) {
      ra0 = *(const uint4*)&arow[kb + 64];
      ra1 = *(const uint4*)&arow[kb + 72];
      if constexpr (BF16B) {
        rbA = *(const uint4*)&browb[kb + 64]; rbB = *(const uint4*)&browb[kb + 72];
      } else {
        rb0 = *(const float4*)&browf[kb + 64]; rb1 = *(const float4*)&browf[kb + 68];
        rb2 = *(const float4*)&browf[kb + 72]; rb3 = *(const float4*)&browf[kb + 76];
      }
    }
    #pragma unroll
    for (int ks = 0; ks < 64; ks += 32) {
      shortx8 a0  = *(const shortx8*)&As[wm + fm][ks + fkq];
      shortx8 a1  = *(const shortx8*)&As[wm + 16 + fm][ks + fkq];
      shortx8 b0  = *(const shortx8*)&Bs[wn + fm][ks + fkq];
      shortx8 b1v = *(const shortx8*)&Bs[wn + 16 + fm][ks + fkq];
      acc00 = __builtin_amdgcn_mfma_f32_16x16x32_bf16(a0, b0,  acc00, 0, 0, 0);
      acc01 = __builtin_amdgcn_mfma_f32_16x16x32_bf16(a0, b1v, acc01, 0, 0, 0);
      acc10 = __builtin_amdgcn_mfma_f32_16x16x32_bf16(a1, b0,  acc10, 0, 0, 0);
      acc11 = __builtin_amdgcn_mfma_f32_16x16x32_bf16(a1, b1v, acc11, 0, 0, 0);
    }
    __syncthreads();
  }
  int q4 = (lane >> 4) * 4, cix = lane & 15;
  #pragma unroll
  for (int im = 0; im < 2; ++im) {
    #pragma unroll
    for (int rg = 0; rg < 4; ++rg) {
      int ml = wm + im * 16 + q4 + rg;
      if (ml >= rem) continue;
      int tok = sorted[off[e] + mt * 64 + ml];
      #pragma unroll
      for (int in = 0; in < 2; ++in) {
        int gn = nt * 64 + wn + in * 16 + cix;
        float vv = (im == 0 ? (in == 0 ? acc00[rg] : acc01[rg]) : (in == 0 ? acc10[rg] : acc11[rg]));
        out[(size_t)tok * D_ + gn] = vv + b2w[e * D_ + gn] + x1f[(size_t)tok * D_ + gn];
      }
    }
  }
}

extern "C" void kernel_launch(void* const* d_in, const int* in_sizes, int n_in,
                              void* d_out, int out_size, void* d_ws, size_t ws_size,
                              hipStream_t stream) {
  int map[16];
  for (int i = 0; i < 16; ++i) map[i] = i;
  if (n_in == 16 && in_sizes[0] == 16777216) {
    const int mm[16] = {15, 13, 14, 4, 2, 5, 6, 3, 12, 11, 10, 9, 0, 7, 1, 8};
    for (int i = 0; i < 16; ++i) map[i] = mm[i];
  } else if (n_in == 16 && in_sizes[0] == 4096) {
    for (int i = 0; i < 16; ++i) map[i] = 15 - i;
  }
  const float* x    = (const float*)d_in[map[0]];
  const float* n1w  = (const float*)d_in[map[1]];
  const float* n2w  = (const float*)d_in[map[2]];
  const float* Wq   = (const float*)d_in[map[3]];
  const float* Wdkv = (const float*)d_in[map[4]];
  const float* Wuk  = (const float*)d_in[map[5]];
  const float* Wuv  = (const float*)d_in[map[6]];
  const float* Wo   = (const float*)d_in[map[7]];
  const float* lng  = (const float*)d_in[map[8]];
  const float* lnb  = (const float*)d_in[map[9]];
  const float* gw   = (const float*)d_in[map[10]];
  const float* gb   = (const float*)d_in[map[11]];
  const float* W1   = (const float*)d_in[map[12]];
  const float* b1   = (const float*)d_in[map[13]];
  const float* W2   = (const float*)d_in[map[14]];
  const float* b2w  = (const float*)d_in[map[15]];
  float* out = (float*)d_out;
  char* ws = (char*)d_ws;
  const size_t MB = 1ull << 20;
  // Activation overlay [0,36) MB (unchanged from round 4):
  //  [0,8)  : qf f32 (Wq -> rope)                 -> x1f f32 (Wo out; residual for moe2)
  //  [8,16) : kf f32 (Wuk -> rope)                -> hbuf.lo bf16 (moe1 -> moe2)
  //  [16,20): latf f32 (Wdkv -> ln)               -> qb bf16 (rope -> fattn)      -> hbuf.mid
  //  [20,24): h1b bf16 (rms1 -> Wq,Wdkv)          -> kb bf16 (rope -> fattn)      -> hbuf.hi
  //  [24,26): latb bf16 (ln -> Wuk,Wuv)           \
  //  [26,30): vb bf16 (Wuv -> fattn)               } -> h2f f32 [24,32) (rms2 -> gate)
  //  [30,34): ab bf16 (fattn -> Wo)               /
  //  [32,36): h2b bf16 (rms2 -> moe1)
  // Big-ws path adds bf16 weights at [36,107) MB; control block at 107 MB (else 36 MB).
  float* qf   = (float*)(ws + 0);
  float* x1f  = (float*)(ws + 0);
  float* kf   = (float*)(ws + 8 * MB);
  u16*   hbuf = (u16*)(ws + 8 * MB);       // 16MB: [8,24)
  float* latf = (float*)(ws + 16 * MB);
  u16*   qb   = (u16*)(ws + 16 * MB);
  u16*   h1b  = (u16*)(ws + 20 * MB);
  u16*   kb   = (u16*)(ws + 20 * MB);
  u16*   latb = (u16*)(ws + 24 * MB);
  float* h2f  = (float*)(ws + 24 * MB);
  u16*   vb   = (u16*)(ws + 26 * MB);
  u16*   ab   = (u16*)(ws + 30 * MB);
  u16*   h2b  = (u16*)(ws + 32 * MB);

  bool big = ws_size >= (107ull * MB + (64ull << 10));
  u16* wb = (u16*)(ws + 36 * MB);
  u16* W1b   = wb;
  u16* W2b   = wb + 16777216;
  u16* Wqb   = wb + 33554432;
  u16* Wdkvb = wb + 34603008;
  u16* Wukb  = wb + 35127296;
  u16* Wuvb  = wb + 35651584;
  u16* Wob   = wb + 36175872;
  int* cnt    = (int*)(ws + (big ? 107 * MB : 36 * MB));
  int* off    = cnt + 8;
  int* expert = cnt + 16;
  int* sorted = expert + 2048;

  if (big) {
    k_cvtall<<<2048, 256, 0, stream>>>(W1, W2, Wq, Wdkv, Wuk, Wuv, Wo, wb);
    k_rms1b<<<2048, 256, 0, stream>>>(x, n1w, h1b);
    k_gemm_t<1><<<512, 256, 0, stream>>>(h1b, Wqb, nullptr, qf, nullptr, 1024, 1024);
    k_gemm_t<1><<<256, 256, 0, stream>>>(h1b, Wdkvb, nullptr, latf, nullptr, 512, 1024);
    k_lnb<<<2048, 256, 0, stream>>>(latf, lng, lnb, latb);
    k_gemm_t<1><<<512, 256, 0, stream>>>(latb, Wukb, nullptr, kf, nullptr, 1024, 512);
    k_gemm_t<1><<<512, 256, 0, stream>>>(latb, Wuvb, nullptr, nullptr, vb, 1024, 512);
    k_rope2b<<<4096, 256, 0, stream>>>(qf, kf, qb, kb);
    k_fattn<<<dim3(32, 16), 256, 0, stream>>>(qb, kb, vb, ab);
    k_gemm_t<1><<<512, 256, 0, stream>>>(ab, Wob, x, x1f, nullptr, 1024, 1024);
    k_rms2b<<<2048, 256, 0, stream>>>(x1f, n2w, h2f, h2b);
    k_init<<<1, 64, 0, stream>>>(cnt);
    k_gate<<<512, 256, 0, stream>>>(h2f, gw, gb, expert, cnt);
    k_scatter<<<1, 256, 0, stream>>>(expert, cnt, off, sorted);
    k_moe1_t<1><<<8192, 256, 0, stream>>>(h2b, W1b, b1, cnt, off, sorted, hbuf);
    k_moe2_t<1><<<2048, 256, 0, stream>>>(hbuf, W2b, b2w, x1f, cnt, off, sorted, out);
  } else {
    k_rms1b<<<2048, 256, 0, stream>>>(x, n1w, h1b);
    k_gemm_t<0><<<512, 256, 0, stream>>>(h1b, Wq, nullptr, qf, nullptr, 1024, 1024);
    k_gemm_t<0><<<256, 256, 0, stream>>>(h1b, Wdkv, nullptr, latf, nullptr, 512, 1024);
    k_lnb<<<2048, 256, 0, stream>>>(latf, lng, lnb, latb);
    k_gemm_t<0><<<512, 256, 0, stream>>>(latb, Wuk, nullptr, kf, nullptr, 1024, 512);
    k_gemm_t<0><<<512, 256, 0, stream>>>(latb, Wuv, nullptr, nullptr, vb, 1024, 512);
    k_rope2b<<<4096, 256, 0, stream>>>(qf, kf, qb, kb);
    k_fattn<<<dim3(32, 16), 256, 0, stream>>>(qb, kb, vb, ab);
    k_gemm_t<0><<<512, 256, 0, stream>>>(ab, Wo, x, x1f, nullptr, 1024, 1024);
    k_rms2b<<<2048, 256, 0, stream>>>(x1f, n2w, h2f, h2b);
    k_init<<<1, 64, 0, stream>>>(cnt);
    k_gate<<<512, 256, 0, stream>>>(h2f, gw, gb, expert, cnt);
    k_scatter<<<1, 256, 0, stream>>>(expert, cnt, off, sorted);
    k_moe1_t<0><<<8192, 256, 0, stream>>>(h2b, W1, b1, cnt, off, sorted, hbuf);
    k_moe2_t<0><<<2048, 256, 0, stream>>>(hbuf, W2, b2w, x1f, cnt, off, sorted, out);
  }
}

// Round 6
// 468.747 us; speedup vs baseline: 2.1788x; 1.0690x over previous
//
#include <hip/hip_runtime.h>
#include <hip/hip_bf16.h>
#include <math.h>

typedef unsigned short u16;
typedef __attribute__((ext_vector_type(4))) float floatx4;
typedef __attribute__((ext_vector_type(8))) short shortx8;

#define DEVI static __device__ __forceinline__

DEVI u16 f2b(float f) {
  union { float f; unsigned int i; } v; v.f = f;
  unsigned int x = v.i;
  return (u16)((x + 0x7fffu + ((x >> 16) & 1u)) >> 16);
}

constexpr int T_ = 1024, D_ = 1024, HD_ = 64, KV_ = 512, DH_ = 4096, M_ = 2048;
#define NEGBIG (-1e30f)

// ---------------- RMSNorm (f32 in -> bf16 out) ----------------
__global__ __launch_bounds__(256) void k_rms1b(const float* __restrict__ x, const float* __restrict__ w,
                                               u16* __restrict__ outb) {
  int row = blockIdx.x, tid = threadIdx.x;
  float4 v = *(const float4*)&x[(size_t)row * D_ + tid * 4];
  float ss = v.x*v.x + v.y*v.y + v.z*v.z + v.w*v.w;
  #pragma unroll
  for (int m = 32; m >= 1; m >>= 1) ss += __shfl_xor(ss, m, 64);
  __shared__ float red[4];
  if ((tid & 63) == 0) red[tid >> 6] = ss;
  __syncthreads();
  ss = red[0] + red[1] + red[2] + red[3];
  float sc = 1.0f / sqrtf(ss * (1.0f / 1024.0f) + 1e-6f);
  float4 wv = *(const float4*)&w[tid * 4];
  ushort4 ob;
  ob.x = f2b(wv.x*v.x*sc); ob.y = f2b(wv.y*v.y*sc);
  ob.z = f2b(wv.z*v.z*sc); ob.w = f2b(wv.w*v.w*sc);
  *(ushort4*)&outb[(size_t)row * D_ + tid * 4] = ob;
}

// ---------------- RMSNorm (f32 in -> f32 out + bf16 out) ----------------
__global__ __launch_bounds__(256) void k_rms2b(const float* __restrict__ x, const float* __restrict__ w,
                                               float* __restrict__ outf, u16* __restrict__ outb) {
  int row = blockIdx.x, tid = threadIdx.x;
  float4 v = *(const float4*)&x[(size_t)row * D_ + tid * 4];
  float ss = v.x*v.x + v.y*v.y + v.z*v.z + v.w*v.w;
  #pragma unroll
  for (int m = 32; m >= 1; m >>= 1) ss += __shfl_xor(ss, m, 64);
  __shared__ float red[4];
  if ((tid & 63) == 0) red[tid >> 6] = ss;
  __syncthreads();
  ss = red[0] + red[1] + red[2] + red[3];
  float sc = 1.0f / sqrtf(ss * (1.0f / 1024.0f) + 1e-6f);
  float4 wv = *(const float4*)&w[tid * 4];
  float4 o; o.x = wv.x*v.x*sc; o.y = wv.y*v.y*sc; o.z = wv.z*v.z*sc; o.w = wv.w*v.w*sc;
  *(float4*)&outf[(size_t)row * D_ + tid * 4] = o;
  ushort4 ob; ob.x = f2b(o.x); ob.y = f2b(o.y); ob.z = f2b(o.z); ob.w = f2b(o.w);
  *(ushort4*)&outb[(size_t)row * D_ + tid * 4] = ob;
}

// ---------------- LayerNorm on latent (f32 in -> bf16 out, 512 cols) ----------------
__global__ __launch_bounds__(256) void k_lnb(const float* __restrict__ lat, const float* __restrict__ g,
                                             const float* __restrict__ bb, u16* __restrict__ ob) {
  int row = blockIdx.x, tid = threadIdx.x;
  const float* r = lat + (size_t)row * KV_;
  float v0 = r[tid], v1 = r[tid + 256];
  float s = v0 + v1;
  #pragma unroll
  for (int m = 32; m >= 1; m >>= 1) s += __shfl_xor(s, m, 64);
  __shared__ float red[4];
  if ((tid & 63) == 0) red[tid >> 6] = s;
  __syncthreads();
  float mu = (red[0] + red[1] + red[2] + red[3]) * (1.0f / 512.0f);
  __syncthreads();
  float d0 = v0 - mu, d1 = v1 - mu;
  float ss = d0*d0 + d1*d1;
  #pragma unroll
  for (int m = 32; m >= 1; m >>= 1) ss += __shfl_xor(ss, m, 64);
  if ((tid & 63) == 0) red[tid >> 6] = ss;
  __syncthreads();
  float var = (red[0] + red[1] + red[2] + red[3]) * (1.0f / 512.0f);
  float sc = 1.0f / sqrtf(var + 1e-5f);
  ob[(size_t)row * KV_ + tid]       = f2b(d0 * sc * g[tid]       + bb[tid]);
  ob[(size_t)row * KV_ + tid + 256] = f2b(d1 * sc * g[tid + 256] + bb[tid + 256]);
}

// ---------------- One-shot weight conversion f32 -> bf16 (concatenated dst) ----------------
__global__ __launch_bounds__(256) void k_cvtall(const float* __restrict__ W1, const float* __restrict__ W2,
                                                const float* __restrict__ Wq, const float* __restrict__ Wdkv,
                                                const float* __restrict__ Wuk, const float* __restrict__ Wuv,
                                                const float* __restrict__ Wo, u16* __restrict__ dst) {
  for (size_t i = (size_t)blockIdx.x * 256 + threadIdx.x; i < 9306112ull; i += (size_t)gridDim.x * 256) {
    const float* s;
    if      (i < 4194304ull) s = W1   + i * 4;
    else if (i < 8388608ull) s = W2   + (i - 4194304ull) * 4;
    else if (i < 8650752ull) s = Wq   + (i - 8388608ull) * 4;
    else if (i < 8781824ull) s = Wdkv + (i - 8650752ull) * 4;
    else if (i < 8912896ull) s = Wuk  + (i - 8781824ull) * 4;
    else if (i < 9043968ull) s = Wuv  + (i - 8912896ull) * 4;
    else                     s = Wo   + (i - 9043968ull) * 4;
    float4 f = *(const float4*)s;
    ushort4 u; u.x = f2b(f.x); u.y = f2b(f.y); u.z = f2b(f.z); u.w = f2b(f.w);
    *(ushort4*)(dst + i * 4) = u;
  }
}

// ---------------- bf16 MFMA GEMM (templated on B dtype): C[M,N] = A_bf16 @ B[N,K]^T ----------------
template<int BF16B>
__global__ __launch_bounds__(256) void k_gemm_t(const u16* __restrict__ A, const void* __restrict__ Bp,
                                                const float* __restrict__ resid, float* __restrict__ Cf,
                                                u16* __restrict__ Cb, int N, int K) {
  int bid = blockIdx.x;
  int xcd = bid & 7, jj = bid >> 3;
  int mt = jj & 31, nt = (jj >> 5) * 8 + xcd;
  __shared__ __align__(16) u16 As[64][72];
  __shared__ __align__(16) u16 Bs[64][72];
  int tid = threadIdx.x, lane = tid & 63, wave = tid >> 6;
  int wm = (wave >> 1) * 32, wn = (wave & 1) * 32;
  int lr = tid >> 2, lc = (tid & 3) * 16;
  const u16* arow = A + (size_t)(mt * 64 + lr) * K + lc;
  const u16* browb = (const u16*)Bp + (size_t)(nt * 64 + lr) * K + lc;
  const float* browf = (const float*)Bp + (size_t)(nt * 64 + lr) * K + lc;
  floatx4 z = {0.f, 0.f, 0.f, 0.f};
  floatx4 acc00 = z, acc01 = z, acc10 = z, acc11 = z;
  int fm = lane & 15, fkq = (lane >> 4) * 8;
  uint4 ra0 = *(const uint4*)&arow[0];
  uint4 ra1 = *(const uint4*)&arow[8];
  uint4 rbA, rbB; float4 rb0, rb1, rb2, rb3;
  if constexpr (BF16B) {
    rbA = *(const uint4*)&browb[0]; rbB = *(const uint4*)&browb[8];
  } else {
    rb0 = *(const float4*)&browf[0];  rb1 = *(const float4*)&browf[4];
    rb2 = *(const float4*)&browf[8];  rb3 = *(const float4*)&browf[12];
  }
  for (int kb = 0; kb < K; kb += 64) {
    *(uint4*)&As[lr][lc]     = ra0;
    *(uint4*)&As[lr][lc + 8] = ra1;
    if constexpr (BF16B) {
      *(uint4*)&Bs[lr][lc]     = rbA;
      *(uint4*)&Bs[lr][lc + 8] = rbB;
    } else {
      ushort4 u;
      u.x = f2b(rb0.x); u.y = f2b(rb0.y); u.z = f2b(rb0.z); u.w = f2b(rb0.w); *(ushort4*)&Bs[lr][lc]      = u;
      u.x = f2b(rb1.x); u.y = f2b(rb1.y); u.z = f2b(rb1.z); u.w = f2b(rb1.w); *(ushort4*)&Bs[lr][lc + 4]  = u;
      u.x = f2b(rb2.x); u.y = f2b(rb2.y); u.z = f2b(rb2.z); u.w = f2b(rb2.w); *(ushort4*)&Bs[lr][lc + 8]  = u;
      u.x = f2b(rb3.x); u.y = f2b(rb3.y); u.z = f2b(rb3.z); u.w = f2b(rb3.w); *(ushort4*)&Bs[lr][lc + 12] = u;
    }
    __syncthreads();
    if (kb + 64 < K) {
      ra0 = *(const uint4*)&arow[kb + 64];
      ra1 = *(const uint4*)&arow[kb + 72];
      if constexpr (BF16B) {
        rbA = *(const uint4*)&browb[kb + 64]; rbB = *(const uint4*)&browb[kb + 72];
      } else {
        rb0 = *(const float4*)&browf[kb + 64]; rb1 = *(const float4*)&browf[kb + 68];
        rb2 = *(const float4*)&browf[kb + 72]; rb3 = *(const float4*)&browf[kb + 76];
      }
    }
    #pragma unroll
    for (int ks = 0; ks < 64; ks += 32) {
      shortx8 a0  = *(const shortx8*)&As[wm + fm][ks + fkq];
      shortx8 a1  = *(const shortx8*)&As[wm + 16 + fm][ks + fkq];
      shortx8 b0  = *(const shortx8*)&Bs[wn + fm][ks + fkq];
      shortx8 b1v = *(const shortx8*)&Bs[wn + 16 + fm][ks + fkq];
      acc00 = __builtin_amdgcn_mfma_f32_16x16x32_bf16(a0, b0,  acc00, 0, 0, 0);
      acc01 = __builtin_amdgcn_mfma_f32_16x16x32_bf16(a0, b1v, acc01, 0, 0, 0);
      acc10 = __builtin_amdgcn_mfma_f32_16x16x32_bf16(a1, b0,  acc10, 0, 0, 0);
      acc11 = __builtin_amdgcn_mfma_f32_16x16x32_bf16(a1, b1v, acc11, 0, 0, 0);
    }
    __syncthreads();
  }
  int q4 = (lane >> 4) * 4, cix = lane & 15;
  #pragma unroll
  for (int im = 0; im < 2; ++im) {
    #pragma unroll
    for (int rg = 0; rg < 4; ++rg) {
      int row = mt * 64 + wm + im * 16 + q4 + rg;
      #pragma unroll
      for (int in = 0; in < 2; ++in) {
        int gn = nt * 64 + wn + in * 16 + cix;
        float vv = (im == 0 ? (in == 0 ? acc00[rg] : acc01[rg]) : (in == 0 ? acc10[rg] : acc11[rg]));
        size_t idx = (size_t)row * N + gn;
        if (Cb) {
          Cb[idx] = f2b(vv);
        } else {
          if (resid) vv += resid[idx];
          Cf[idx] = vv;
        }
      }
    }
  }
}

// ---------------- RoPE: f32 q,k in -> bf16 qb (pre-scaled 1/8), kb out ----------------
__global__ __launch_bounds__(256) void k_rope2b(const float* __restrict__ q, const float* __restrict__ k,
                                                u16* __restrict__ qb, u16* __restrict__ kb) {
  int g = blockIdx.x * 256 + threadIdx.x;
  int j = g & 31;
  int h = (g >> 5) & 15;
  int row = g >> 9;
  int t = row & (T_ - 1);
  float p = (float)pow(10000.0, (double)j * (1.0 / 32.0));
  float ang = (float)t / p;
  float sn, cs; sincosf(ang, &sn, &cs);
  size_t base = (size_t)row * D_ + h * 64 + j;
  float x1 = q[base], x2 = q[base + 32];
  qb[base]      = f2b((x1 * cs - x2 * sn) * 0.125f);
  qb[base + 32] = f2b((x1 * sn + x2 * cs) * 0.125f);
  x1 = k[base]; x2 = k[base + 32];
  kb[base]      = f2b(x1 * cs - x2 * sn);
  kb[base + 32] = f2b(x1 * sn + x2 * cs);
}

// ---------------- Flash attention, bf16 MFMA, 64-row q-tile per block ----------------
__global__ __launch_bounds__(256) void k_fattn(const u16* __restrict__ qbp, const u16* __restrict__ kbp,
                                               const u16* __restrict__ vbp, u16* __restrict__ ob) {
  int idx = blockIdx.x, h = blockIdx.y;
  int b = idx >> 4;
  int qt = idx & 15;
  if (b) qt = 15 - qt;  // complementary pairing: co-resident pair sums to 17 k-tiles
  __shared__ __align__(16) u16 Qs[64][72];   // [q][d] bf16 (A-operand), pre-scaled 1/8
  __shared__ __align__(16) u16 Ks[64][72];   // [k][d] bf16 (B-operand)
  __shared__ __align__(16) u16 Vs[64][72];   // [d][k] bf16 transposed (B-operand for PV)
  __shared__ __align__(16) u16 Ps[64][72];   // [q][k] bf16 (A-operand for PV)
  __shared__ float red1[2][64];
  __shared__ float red2[2][64];
  int tid = threadIdx.x, lane = tid & 63, wave = tid >> 6;
  int wm = (wave >> 1) * 32, wn = (wave & 1) * 32, w1 = wave & 1;
  int fm = lane & 15, fkq = (lane >> 4) * 8;
  int q4 = (lane >> 4) * 4, cix = lane & 15;
  size_t rowbase = (size_t)b * T_;
  int colbase = h * HD_;
  int q0 = qt * 64;
  int lr = tid >> 2, ld = (tid & 3) * 16;
  {
    const u16* qr = qbp + (rowbase + q0 + lr) * D_ + colbase + ld;
    *(uint4*)&Qs[lr][ld]     = *(const uint4*)&qr[0];
    *(uint4*)&Qs[lr][ld + 8] = *(const uint4*)&qr[8];
  }
  floatx4 z = {0.f, 0.f, 0.f, 0.f};
  floatx4 s[2][2], o[2][2];
  o[0][0] = z; o[0][1] = z; o[1][0] = z; o[1][1] = z;
  float m[2][4], l[2][4], f_[2][4];
  #pragma unroll
  for (int im = 0; im < 2; ++im)
    #pragma unroll
    for (int rg = 0; rg < 4; ++rg) { m[im][rg] = NEGBIG; l[im][rg] = 0.f; }
  for (int kt = 0; kt <= qt; ++kt) {
    __syncthreads();
    {
      const u16* kr = kbp + (rowbase + kt * 64 + lr) * D_ + colbase + ld;
      *(uint4*)&Ks[lr][ld]     = *(const uint4*)&kr[0];
      *(uint4*)&Ks[lr][ld + 8] = *(const uint4*)&kr[8];
      const u16* vr = vbp + (rowbase + kt * 64 + lr) * D_ + colbase + ld;
      #pragma unroll
      for (int c = 0; c < 16; ++c) Vs[ld + c][lr] = vr[c];
    }
    __syncthreads();
    s[0][0] = z; s[0][1] = z; s[1][0] = z; s[1][1] = z;
    #pragma unroll
    for (int ks = 0; ks < 64; ks += 32) {
      shortx8 a0  = *(const shortx8*)&Qs[wm + fm][ks + fkq];
      shortx8 a1  = *(const shortx8*)&Qs[wm + 16 + fm][ks + fkq];
      shortx8 b0  = *(const shortx8*)&Ks[wn + fm][ks + fkq];
      shortx8 b1v = *(const shortx8*)&Ks[wn + 16 + fm][ks + fkq];
      s[0][0] = __builtin_amdgcn_mfma_f32_16x16x32_bf16(a0, b0,  s[0][0], 0, 0, 0);
      s[0][1] = __builtin_amdgcn_mfma_f32_16x16x32_bf16(a0, b1v, s[0][1], 0, 0, 0);
      s[1][0] = __builtin_amdgcn_mfma_f32_16x16x32_bf16(a1, b0,  s[1][0], 0, 0, 0);
      s[1][1] = __builtin_amdgcn_mfma_f32_16x16x32_bf16(a1, b1v, s[1][1], 0, 0, 0);
    }
    if (kt == qt) {
      #pragma unroll
      for (int im = 0; im < 2; ++im)
        #pragma unroll
        for (int rg = 0; rg < 4; ++rg) {
          int r = wm + im * 16 + q4 + rg;
          #pragma unroll
          for (int in = 0; in < 2; ++in)
            if (wn + in * 16 + cix > r) s[im][in][rg] = NEGBIG;
        }
    }
    #pragma unroll
    for (int im = 0; im < 2; ++im)
      #pragma unroll
      for (int rg = 0; rg < 4; ++rg) {
        float pm = fmaxf(s[im][0][rg], s[im][1][rg]);
        #pragma unroll
        for (int mk = 8; mk >= 1; mk >>= 1) pm = fmaxf(pm, __shfl_xor(pm, mk, 64));
        if (cix == 0) red1[w1][wm + im * 16 + q4 + rg] = pm;
        f_[im][rg] = pm;
      }
    __syncthreads();
    #pragma unroll
    for (int im = 0; im < 2; ++im)
      #pragma unroll
      for (int rg = 0; rg < 4; ++rg) {
        int r = wm + im * 16 + q4 + rg;
        float mx = fmaxf(f_[im][rg], red1[w1 ^ 1][r]);
        float mn = fmaxf(m[im][rg], mx);
        float f = __expf(m[im][rg] - mn);
        m[im][rg] = mn;
        float p0 = __expf(s[im][0][rg] - mn);
        float p1 = __expf(s[im][1][rg] - mn);
        float ss = p0 + p1;
        #pragma unroll
        for (int mk = 8; mk >= 1; mk >>= 1) ss += __shfl_xor(ss, mk, 64);
        if (cix == 0) red2[w1][r] = ss;
        Ps[r][wn + cix]      = f2b(p0);
        Ps[r][wn + 16 + cix] = f2b(p1);
        l[im][rg] *= f;
        o[im][0][rg] *= f;
        o[im][1][rg] *= f;
      }
    __syncthreads();
    #pragma unroll
    for (int im = 0; im < 2; ++im)
      #pragma unroll
      for (int rg = 0; rg < 4; ++rg) {
        int r = wm + im * 16 + q4 + rg;
        l[im][rg] += red2[0][r] + red2[1][r];
      }
    #pragma unroll
    for (int ks = 0; ks < 64; ks += 32) {
      shortx8 a0  = *(const shortx8*)&Ps[wm + fm][ks + fkq];
      shortx8 a1  = *(const shortx8*)&Ps[wm + 16 + fm][ks + fkq];
      shortx8 b0  = *(const shortx8*)&Vs[wn + fm][ks + fkq];
      shortx8 b1v = *(const shortx8*)&Vs[wn + 16 + fm][ks + fkq];
      o[0][0] = __builtin_amdgcn_mfma_f32_16x16x32_bf16(a0, b0,  o[0][0], 0, 0, 0);
      o[0][1] = __builtin_amdgcn_mfma_f32_16x16x32_bf16(a0, b1v, o[0][1], 0, 0, 0);
      o[1][0] = __builtin_amdgcn_mfma_f32_16x16x32_bf16(a1, b0,  o[1][0], 0, 0, 0);
      o[1][1] = __builtin_amdgcn_mfma_f32_16x16x32_bf16(a1, b1v, o[1][1], 0, 0, 0);
    }
  }
  #pragma unroll
  for (int im = 0; im < 2; ++im)
    #pragma unroll
    for (int rg = 0; rg < 4; ++rg) {
      int r = wm + im * 16 + q4 + rg;
      float inv = 1.0f / l[im][rg];
      size_t base = (rowbase + q0 + r) * D_ + colbase;
      ob[base + wn + cix]      = f2b(o[im][0][rg] * inv);
      ob[base + wn + 16 + cix] = f2b(o[im][1][rg] * inv);
    }
}

// ---------------- MoE gate ----------------
__global__ __launch_bounds__(256) void k_init(int* cnt) { if (threadIdx.x < 4) cnt[threadIdx.x] = 0; }

__global__ __launch_bounds__(256) void k_gate(const float* __restrict__ h2, const float* __restrict__ gw,
                                              const float* __restrict__ gb, int* __restrict__ expert,
                                              int* __restrict__ cnt) {
  int wid = threadIdx.x >> 6, lane = threadIdx.x & 63;
  int t = blockIdx.x * 4 + wid;
  const float* hr = h2 + (size_t)t * D_;
  float a0 = 0, a1 = 0, a2 = 0, a3 = 0;
  for (int c = lane; c < D_; c += 64) {
    float xv = hr[c];
    a0 += xv * gw[c];
    a1 += xv * gw[D_ + c];
    a2 += xv * gw[2 * D_ + c];
    a3 += xv * gw[3 * D_ + c];
  }
  #pragma unroll
  for (int m = 32; m >= 1; m >>= 1) {
    a0 += __shfl_xor(a0, m, 64); a1 += __shfl_xor(a1, m, 64);
    a2 += __shfl_xor(a2, m, 64); a3 += __shfl_xor(a3, m, 64);
  }
  if (lane == 0) {
    float l0 = a0 + gb[0], l1 = a1 + gb[1], l2 = a2 + gb[2], l3 = a3 + gb[3];
    int best = 0; float bv = l0;
    if (l1 > bv) { bv = l1; best = 1; }
    if (l2 > bv) { bv = l2; best = 2; }
    if (l3 > bv) { bv = l3; best = 3; }
    expert[t] = best;
    atomicAdd(&cnt[best], 1);
  }
}

__global__ __launch_bounds__(256) void k_scatter(const int* __restrict__ expert, const int* __restrict__ cnt,
                                                 int* __restrict__ off, int* __restrict__ sorted) {
  __shared__ int cur[4];
  if (threadIdx.x == 0) {
    int o0 = 0, o1 = cnt[0], o2 = o1 + cnt[1], o3 = o2 + cnt[2];
    off[0] = o0; off[1] = o1; off[2] = o2; off[3] = o3;
    cur[0] = o0; cur[1] = o1; cur[2] = o2; cur[3] = o3;
  }
  __syncthreads();
  for (int t = threadIdx.x; t < M_; t += 256) {
    int e = expert[t];
    int p = atomicAdd(&cur[e], 1);
    sorted[p] = t;
  }
}

// ---------------- MoE MFMA GEMM 1 (templated B): hbuf = bf16(relu(A[gather] @ W1[e]^T + b1[e])) ----------------
template<int BF16B>
__global__ __launch_bounds__(256) void k_moe1_t(const u16* __restrict__ A, const void* __restrict__ W1p,
                                                const float* __restrict__ b1, const int* __restrict__ cnt,
                                                const int* __restrict__ off, const int* __restrict__ sorted,
                                                u16* __restrict__ hbuf) {
  int bid = blockIdx.x;
  int xcd = bid & 7, jj = bid >> 3;
  int mt = jj & 31, combo = (jj >> 5) * 8 + xcd;   // combo in [0,256)
  int e = combo >> 6, nt = combo & 63;
  int rem = cnt[e] - mt * 64;
  if (rem <= 0) return;
  __shared__ __align__(16) u16 As[64][72];
  __shared__ __align__(16) u16 Bs[64][72];
  int tid = threadIdx.x, lane = tid & 63, wave = tid >> 6;
  int wm = (wave >> 1) * 32, wn = (wave & 1) * 32;
  int lr = tid >> 2, lc = (tid & 3) * 16;
  int rr = lr < rem ? lr : rem - 1;
  const u16* arow = A + (size_t)sorted[off[e] + mt * 64 + rr] * D_ + lc;
  const u16* browb = (const u16*)W1p + (size_t)e * DH_ * D_ + (size_t)(nt * 64 + lr) * D_ + lc;
  const float* browf = (const float*)W1p + (size_t)e * DH_ * D_ + (size_t)(nt * 64 + lr) * D_ + lc;
  floatx4 z = {0.f, 0.f, 0.f, 0.f};
  floatx4 acc00 = z, acc01 = z, acc10 = z, acc11 = z;
  int fm = lane & 15, fkq = (lane >> 4) * 8;
  uint4 ra0 = *(const uint4*)&arow[0];
  uint4 ra1 = *(const uint4*)&arow[8];
  uint4 rbA, rbB; float4 rb0, rb1, rb2, rb3;
  if constexpr (BF16B) {
    rbA = *(const uint4*)&browb[0]; rbB = *(const uint4*)&browb[8];
  } else {
    rb0 = *(const float4*)&browf[0];  rb1 = *(const float4*)&browf[4];
    rb2 = *(const float4*)&browf[8];  rb3 = *(const float4*)&browf[12];
  }
  for (int kb = 0; kb < D_; kb += 64) {
    *(uint4*)&As[lr][lc]     = ra0;
    *(uint4*)&As[lr][lc + 8] = ra1;
    if constexpr (BF16B) {
      *(uint4*)&Bs[lr][lc]     = rbA;
      *(uint4*)&Bs[lr][lc + 8] = rbB;
    } else {
      ushort4 u;
      u.x = f2b(rb0.x); u.y = f2b(rb0.y); u.z = f2b(rb0.z); u.w = f2b(rb0.w); *(ushort4*)&Bs[lr][lc]      = u;
      u.x = f2b(rb1.x); u.y = f2b(rb1.y); u.z = f2b(rb1.z); u.w = f2b(rb1.w); *(ushort4*)&Bs[lr][lc + 4]  = u;
      u.x = f2b(rb2.x); u.y = f2b(rb2.y); u.z = f2b(rb2.z); u.w = f2b(rb2.w); *(ushort4*)&Bs[lr][lc + 8]  = u;
      u.x = f2b(rb3.x); u.y = f2b(rb3.y); u.z = f2b(rb3.z); u.w = f2b(rb3.w); *(ushort4*)&Bs[lr][lc + 12] = u;
    }
    __syncthreads();
    if (kb + 64 < D_) {
      ra0 = *(const uint4*)&arow[kb + 64];
      ra1 = *(const uint4*)&arow[kb + 72];
      if constexpr (BF16B) {
        rbA = *(const uint4*)&browb[kb + 64]; rbB = *(const uint4*)&browb[kb + 72];
      } else {
        rb0 = *(const float4*)&browf[kb + 64]; rb1 = *(const float4*)&browf[kb + 68];
        rb2 = *(const float4*)&browf[kb + 72]; rb3 = *(const float4*)&browf[kb + 76];
      }
    }
    #pragma unroll
    for (int ks = 0; ks < 64; ks += 32) {
      shortx8 a0  = *(const shortx8*)&As[wm + fm][ks + fkq];
      shortx8 a1  = *(const shortx8*)&As[wm + 16 + fm][ks + fkq];
      shortx8 b0  = *(const shortx8*)&Bs[wn + fm][ks + fkq];
      shortx8 b1v = *(const shortx8*)&Bs[wn + 16 + fm][ks + fkq];
      acc00 = __builtin_amdgcn_mfma_f32_16x16x32_bf16(a0, b0,  acc00, 0, 0, 0);
      acc01 = __builtin_amdgcn_mfma_f32_16x16x32_bf16(a0, b1v, acc01, 0, 0, 0);
      acc10 = __builtin_amdgcn_mfma_f32_16x16x32_bf16(a1, b0,  acc10, 0, 0, 0);
      acc11 = __builtin_amdgcn_mfma_f32_16x16x32_bf16(a1, b1v, acc11, 0, 0, 0);
    }
    __syncthreads();
  }
  int q4 = (lane >> 4) * 4, cix = lane & 15;
  #pragma unroll
  for (int im = 0; im < 2; ++im) {
    #pragma unroll
    for (int rg = 0; rg < 4; ++rg) {
      int ml = wm + im * 16 + q4 + rg;
      if (ml >= rem) continue;
      size_t grow = (size_t)(off[e] + mt * 64 + ml);
      #pragma unroll
      for (int in = 0; in < 2; ++in) {
        int gn = nt * 64 + wn + in * 16 + cix;
        float vv = (im == 0 ? (in == 0 ? acc00[rg] : acc01[rg]) : (in == 0 ? acc10[rg] : acc11[rg]));
        vv += b1[e * DH_ + gn];
        hbuf[grow * DH_ + gn] = f2b(fmaxf(vv, 0.f));
      }
    }
  }
}

// ---------------- MoE MFMA GEMM 2 (unsplit, small-ws fallback) ----------------
template<int BF16B>
__global__ __launch_bounds__(256) void k_moe2_t(const u16* __restrict__ hbuf, const void* __restrict__ W2p,
                                                const float* __restrict__ b2w, const float* __restrict__ x1f,
                                                const int* __restrict__ cnt, const int* __restrict__ off,
                                                const int* __restrict__ sorted, float* __restrict__ out) {
  int bid = blockIdx.x;
  int xcd = bid & 7, jj = bid >> 3;
  int mt = jj & 31, combo = (jj >> 5) * 8 + xcd;   // combo in [0,64)
  int e = combo >> 4, nt = combo & 15;
  int rem = cnt[e] - mt * 64;
  if (rem <= 0) return;
  __shared__ __align__(16) u16 As[64][72];
  __shared__ __align__(16) u16 Bs[64][72];
  int tid = threadIdx.x, lane = tid & 63, wave = tid >> 6;
  int wm = (wave >> 1) * 32, wn = (wave & 1) * 32;
  int lr = tid >> 2, lc = (tid & 3) * 16;
  int rr = lr < rem ? lr : rem - 1;
  const u16* arow = hbuf + (size_t)(off[e] + mt * 64 + rr) * DH_ + lc;
  const u16* browb = (const u16*)W2p + (size_t)e * D_ * DH_ + (size_t)(nt * 64 + lr) * DH_ + lc;
  const float* browf = (const float*)W2p + (size_t)e * D_ * DH_ + (size_t)(nt * 64 + lr) * DH_ + lc;
  floatx4 z = {0.f, 0.f, 0.f, 0.f};
  floatx4 acc00 = z, acc01 = z, acc10 = z, acc11 = z;
  int fm = lane & 15, fkq = (lane >> 4) * 8;
  uint4 ra0 = *(const uint4*)&arow[0];
  uint4 ra1 = *(const uint4*)&arow[8];
  uint4 rbA, rbB; float4 rb0, rb1, rb2, rb3;
  if constexpr (BF16B) {
    rbA = *(const uint4*)&browb[0]; rbB = *(const uint4*)&browb[8];
  } else {
    rb0 = *(const float4*)&browf[0];  rb1 = *(const float4*)&browf[4];
    rb2 = *(const float4*)&browf[8];  rb3 = *(const float4*)&browf[12];
  }
  for (int kb = 0; kb < DH_; kb += 64) {
    *(uint4*)&As[lr][lc]     = ra0;
    *(uint4*)&As[lr][lc + 8] = ra1;
    if constexpr (BF16B) {
      *(uint4*)&Bs[lr][lc]     = rbA;
      *(uint4*)&Bs[lr][lc + 8] = rbB;
    } else {
      ushort4 u;
      u.x = f2b(rb0.x); u.y = f2b(rb0.y); u.z = f2b(rb0.z); u.w = f2b(rb0.w); *(ushort4*)&Bs[lr][lc]      = u;
      u.x = f2b(rb1.x); u.y = f2b(rb1.y); u.z = f2b(rb1.z); u.w = f2b(rb1.w); *(ushort4*)&Bs[lr][lc + 4]  = u;
      u.x = f2b(rb2.x); u.y = f2b(rb2.y); u.z = f2b(rb2.z); u.w = f2b(rb2.w); *(ushort4*)&Bs[lr][lc + 8]  = u;
      u.x = f2b(rb3.x); u.y = f2b(rb3.y); u.z = f2b(rb3.z); u.w = f2b(rb3.w); *(ushort4*)&Bs[lr][lc + 12] = u;
    }
    __syncthreads();
    if (kb + 64 < DH_) {
      ra0 = *(const uint4*)&arow[kb + 64];
      ra1 = *(const uint4*)&arow[kb + 72];
      if constexpr (BF16B) {
        rbA = *(const uint4*)&browb[kb + 64]; rbB = *(const uint4*)&browb[kb + 72];
      } else {
        rb0 = *(const float4*)&browf[kb + 64]; rb1 = *(const float4*)&browf[kb + 68];
        rb2 = *(const float4*)&browf[kb + 72]; rb3 = *(const float4*)&browf[kb + 76];
      }
    }
    #pragma unroll
    for (int ks = 0; ks < 64; ks += 32) {
      shortx8 a0  = *(const shortx8*)&As[wm + fm][ks + fkq];
      shortx8 a1  = *(const shortx8*)&As[wm + 16 + fm][ks + fkq];
      shortx8 b0  = *(const shortx8*)&Bs[wn + fm][ks + fkq];
      shortx8 b1v = *(const shortx8*)&Bs[wn + 16 + fm][ks + fkq];
      acc00 = __builtin_amdgcn_mfma_f32_16x16x32_bf16(a0, b0,  acc00, 0, 0, 0);
      acc01 = __builtin_amdgcn_mfma_f32_16x16x32_bf16(a0, b1v, acc01, 0, 0, 0);
      acc10 = __builtin_amdgcn_mfma_f32_16x16x32_bf16(a1, b0,  acc10, 0, 0, 0);
      acc11 = __builtin_amdgcn_mfma_f32_16x16x32_bf16(a1, b1v, acc11, 0, 0, 0);
    }
    __syncthreads();
  }
  int q4 = (lane >> 4) * 4, cix = lane & 15;
  #pragma unroll
  for (int im = 0; im < 2; ++im) {
    #pragma unroll
    for (int rg = 0; rg < 4; ++rg) {
      int ml = wm + im * 16 + q4 + rg;
      if (ml >= rem) continue;
      int tok = sorted[off[e] + mt * 64 + ml];
      #pragma unroll
      for (int in = 0; in < 2; ++in) {
        int gn = nt * 64 + wn + in * 16 + cix;
        float vv = (im == 0 ? (in == 0 ? acc00[rg] : acc01[rg]) : (in == 0 ? acc10[rg] : acc11[rg]));
        out[(size_t)tok * D_ + gn] = vv + b2w[e * D_ + gn] + x1f[(size_t)tok * D_ + gn];
      }
    }
  }
}

// ---------------- MoE GEMM 2, K-split 2: pbuf[ks] = hbuf @ W2[e][:, ks*2048:(ks+1)*2048]^T ----------------
// Grid 4096 (1D): xcd=bid&7, jj=bid>>3; mt=jj&31; combo=(jj>>5)*8+xcd in [0,128);
// ks=combo&1, ec=combo>>1; e=ec>>4, nt=ec&15. Partials stored by SORTED row (no gather here).
__global__ __launch_bounds__(256) void k_moe2s(const u16* __restrict__ hbuf, const u16* __restrict__ W2b,
                                               const int* __restrict__ cnt, const int* __restrict__ off,
                                               float* __restrict__ pbuf) {
  int bid = blockIdx.x;
  int xcd = bid & 7, jj = bid >> 3;
  int mt = jj & 31;
  int combo = (jj >> 5) * 8 + xcd;
  int ks = combo & 1, ec = combo >> 1;
  int e = ec >> 4, nt = ec & 15;
  int rem = cnt[e] - mt * 64;
  if (rem <= 0) return;
  const int KS = DH_ / 2;
  int k0 = ks * KS;
  __shared__ __align__(16) u16 As[64][72];
  __shared__ __align__(16) u16 Bs[64][72];
  int tid = threadIdx.x, lane = tid & 63, wave = tid >> 6;
  int wm = (wave >> 1) * 32, wn = (wave & 1) * 32;
  int lr = tid >> 2, lc = (tid & 3) * 16;
  int rr = lr < rem ? lr : rem - 1;
  const u16* arow = hbuf + (size_t)(off[e] + mt * 64 + rr) * DH_ + k0 + lc;
  const u16* brow = W2b + (size_t)e * D_ * DH_ + (size_t)(nt * 64 + lr) * DH_ + k0 + lc;
  floatx4 z = {0.f, 0.f, 0.f, 0.f};
  floatx4 acc00 = z, acc01 = z, acc10 = z, acc11 = z;
  int fm = lane & 15, fkq = (lane >> 4) * 8;
  uint4 ra0 = *(const uint4*)&arow[0];
  uint4 ra1 = *(const uint4*)&arow[8];
  uint4 rbA = *(const uint4*)&brow[0];
  uint4 rbB = *(const uint4*)&brow[8];
  for (int kb = 0; kb < KS; kb += 64) {
    *(uint4*)&As[lr][lc]     = ra0;
    *(uint4*)&As[lr][lc + 8] = ra1;
    *(uint4*)&Bs[lr][lc]     = rbA;
    *(uint4*)&Bs[lr][lc + 8] = rbB;
    __syncthreads();
    if (kb + 64 < KS) {
      ra0 = *(const uint4*)&arow[kb + 64];
      ra1 = *(const uint4*)&arow[kb + 72];
      rbA = *(const uint4*)&brow[kb + 64];
      rbB = *(const uint4*)&brow[kb + 72];
    }
    #pragma unroll
    for (int kk = 0; kk < 64; kk += 32) {
      shortx8 a0  = *(const shortx8*)&As[wm + fm][kk + fkq];
      shortx8 a1  = *(const shortx8*)&As[wm + 16 + fm][kk + fkq];
      shortx8 b0  = *(const shortx8*)&Bs[wn + fm][kk + fkq];
      shortx8 b1v = *(const shortx8*)&Bs[wn + 16 + fm][kk + fkq];
      acc00 = __builtin_amdgcn_mfma_f32_16x16x32_bf16(a0, b0,  acc00, 0, 0, 0);
      acc01 = __builtin_amdgcn_mfma_f32_16x16x32_bf16(a0, b1v, acc01, 0, 0, 0);
      acc10 = __builtin_amdgcn_mfma_f32_16x16x32_bf16(a1, b0,  acc10, 0, 0, 0);
      acc11 = __builtin_amdgcn_mfma_f32_16x16x32_bf16(a1, b1v, acc11, 0, 0, 0);
    }
    __syncthreads();
  }
  float* pb = pbuf + (size_t)ks * M_ * D_;
  int q4 = (lane >> 4) * 4, cix = lane & 15;
  #pragma unroll
  for (int im = 0; im < 2; ++im) {
    #pragma unroll
    for (int rg = 0; rg < 4; ++rg) {
      int ml = wm + im * 16 + q4 + rg;
      if (ml >= rem) continue;
      size_t srow = (size_t)(off[e] + mt * 64 + ml);
      #pragma unroll
      for (int in = 0; in < 2; ++in) {
        int gn = nt * 64 + wn + in * 16 + cix;
        float vv = (im == 0 ? (in == 0 ? acc00[rg] : acc01[rg]) : (in == 0 ? acc10[rg] : acc11[rg]));
        pb[srow * D_ + gn] = vv;
      }
    }
  }
}

// ---------------- MoE reduce: out[tok] = pbuf0[r] + pbuf1[r] + b2[e] + x1f[tok] ----------------
__global__ __launch_bounds__(256) void k_moered(const float* __restrict__ pbuf, const float* __restrict__ b2w,
                                                const float* __restrict__ x1f, const int* __restrict__ off,
                                                const int* __restrict__ sorted, float* __restrict__ out) {
  int r = blockIdx.x, tid = threadIdx.x;
  int tok = sorted[r];
  int e = (r >= off[3]) ? 3 : (r >= off[2]) ? 2 : (r >= off[1]) ? 1 : 0;
  size_t c = (size_t)tid * 4;
  float4 a = *(const float4*)&pbuf[(size_t)r * D_ + c];
  float4 b = *(const float4*)&pbuf[(size_t)M_ * D_ + (size_t)r * D_ + c];
  float4 bb = *(const float4*)&b2w[(size_t)e * D_ + c];
  float4 xr = *(const float4*)&x1f[(size_t)tok * D_ + c];
  float4 o;
  o.x = a.x + b.x + bb.x + xr.x;
  o.y = a.y + b.y + bb.y + xr.y;
  o.z = a.z + b.z + bb.z + xr.z;
  o.w = a.w + b.w + bb.w + xr.w;
  *(float4*)&out[(size_t)tok * D_ + c] = o;
}

extern "C" void kernel_launch(void* const* d_in, const int* in_sizes, int n_in,
                              void* d_out, int out_size, void* d_ws, size_t ws_size,
                              hipStream_t stream) {
  int map[16];
  for (int i = 0; i < 16; ++i) map[i] = i;
  if (n_in == 16 && in_sizes[0] == 16777216) {
    const int mm[16] = {15, 13, 14, 4, 2, 5, 6, 3, 12, 11, 10, 9, 0, 7, 1, 8};
    for (int i = 0; i < 16; ++i) map[i] = mm[i];
  } else if (n_in == 16 && in_sizes[0] == 4096) {
    for (int i = 0; i < 16; ++i) map[i] = 15 - i;
  }
  const float* x    = (const float*)d_in[map[0]];
  const float* n1w  = (const float*)d_in[map[1]];
  const float* n2w  = (const float*)d_in[map[2]];
  const float* Wq   = (const float*)d_in[map[3]];
  const float* Wdkv = (const float*)d_in[map[4]];
  const float* Wuk  = (const float*)d_in[map[5]];
  const float* Wuv  = (const float*)d_in[map[6]];
  const float* Wo   = (const float*)d_in[map[7]];
  const float* lng  = (const float*)d_in[map[8]];
  const float* lnb  = (const float*)d_in[map[9]];
  const float* gw   = (const float*)d_in[map[10]];
  const float* gb   = (const float*)d_in[map[11]];
  const float* W1   = (const float*)d_in[map[12]];
  const float* b1   = (const float*)d_in[map[13]];
  const float* W2   = (const float*)d_in[map[14]];
  const float* b2w  = (const float*)d_in[map[15]];
  float* out = (float*)d_out;
  char* ws = (char*)d_ws;
  const size_t MB = 1ull << 20;
  // Activation overlay [0,36) MB:
  //  [0,8)  : qf f32 (Wq -> rope)                 -> x1f f32 (Wo out; residual, live to end)
  //  [8,16) : kf f32 (Wuk -> rope)                -> hbuf.lo bf16 (moe1 -> moe2s)
  //  [16,20): latf f32 (Wdkv -> ln)               -> qb bf16 (rope -> fattn)      -> hbuf.mid
  //  [20,24): h1b bf16 (rms1 -> Wq,Wdkv)          -> kb bf16 (rope -> fattn)      -> hbuf.hi
  //  [24,26): latb bf16 (ln -> Wuk,Wuv)           \
  //  [26,30): vb bf16 (Wuv -> fattn)               } -> h2f f32 [24,32) (rms2 -> gate)
  //  [30,34): ab bf16 (fattn -> Wo)               /
  //  [32,36): h2b bf16 (rms2 -> moe1)
  // Big path: bf16 weights [36,107); pbuf[2][2048][1024] f32 [24,40) over dead h2f/h2b/W1b-head
  // (h2f dead after k_gate, h2b after k_moe1, W1b after k_moe1 — all precede k_moe2s).
  float* qf   = (float*)(ws + 0);
  float* x1f  = (float*)(ws + 0);
  float* kf   = (float*)(ws + 8 * MB);
  u16*   hbuf = (u16*)(ws + 8 * MB);       // 16MB: [8,24)
  float* latf = (float*)(ws + 16 * MB);
  u16*   qb   = (u16*)(ws + 16 * MB);
  u16*   h1b  = (u16*)(ws + 20 * MB);
  u16*   kb   = (u16*)(ws + 20 * MB);
  u16*   latb = (u16*)(ws + 24 * MB);
  float* h2f  = (float*)(ws + 24 * MB);
  u16*   vb   = (u16*)(ws + 26 * MB);
  u16*   ab   = (u16*)(ws + 30 * MB);
  u16*   h2b  = (u16*)(ws + 32 * MB);
  float* pbuf = (float*)(ws + 24 * MB);    // 16MB: [24,40), big path only

  bool big = ws_size >= (107ull * MB + (64ull << 10));
  u16* wb = (u16*)(ws + 36 * MB);
  u16* W1b   = wb;
  u16* W2b   = wb + 16777216;
  u16* Wqb   = wb + 33554432;
  u16* Wdkvb = wb + 34603008;
  u16* Wukb  = wb + 35127296;
  u16* Wuvb  = wb + 35651584;
  u16* Wob   = wb + 36175872;
  int* cnt    = (int*)(ws + (big ? 107 * MB : 36 * MB));
  int* off    = cnt + 8;
  int* expert = cnt + 16;
  int* sorted = expert + 2048;

  if (big) {
    k_cvtall<<<2048, 256, 0, stream>>>(W1, W2, Wq, Wdkv, Wuk, Wuv, Wo, wb);
    k_rms1b<<<2048, 256, 0, stream>>>(x, n1w, h1b);
    k_gemm_t<1><<<512, 256, 0, stream>>>(h1b, Wqb, nullptr, qf, nullptr, 1024, 1024);
    k_gemm_t<1><<<256, 256, 0, stream>>>(h1b, Wdkvb, nullptr, latf, nullptr, 512, 1024);
    k_lnb<<<2048, 256, 0, stream>>>(latf, lng, lnb, latb);
    k_gemm_t<1><<<512, 256, 0, stream>>>(latb, Wukb, nullptr, kf, nullptr, 1024, 512);
    k_gemm_t<1><<<512, 256, 0, stream>>>(latb, Wuvb, nullptr, nullptr, vb, 1024, 512);
    k_rope2b<<<4096, 256, 0, stream>>>(qf, kf, qb, kb);
    k_fattn<<<dim3(32, 16), 256, 0, stream>>>(qb, kb, vb, ab);
    k_gemm_t<1><<<512, 256, 0, stream>>>(ab, Wob, x, x1f, nullptr, 1024, 1024);
    k_rms2b<<<2048, 256, 0, stream>>>(x1f, n2w, h2f, h2b);
    k_init<<<1, 64, 0, stream>>>(cnt);
    k_gate<<<512, 256, 0, stream>>>(h2f, gw, gb, expert, cnt);
    k_scatter<<<1, 256, 0, stream>>>(expert, cnt, off, sorted);
    k_moe1_t<1><<<8192, 256, 0, stream>>>(h2b, W1b, b1, cnt, off, sorted, hbuf);
    k_moe2s<<<4096, 256, 0, stream>>>(hbuf, W2b, cnt, off, pbuf);
    k_moered<<<2048, 256, 0, stream>>>(pbuf, b2w, x1f, off, sorted, out);
  } else {
    k_rms1b<<<2048, 256, 0, stream>>>(x, n1w, h1b);
    k_gemm_t<0><<<512, 256, 0, stream>>>(h1b, Wq, nullptr, qf, nullptr, 1024, 1024);
    k_gemm_t<0><<<256, 256, 0, stream>>>(h1b, Wdkv, nullptr, latf, nullptr, 512, 1024);
    k_lnb<<<2048, 256, 0, stream>>>(latf, lng, lnb, latb);
    k_gemm_t<0><<<512, 256, 0, stream>>>(latb, Wuk, nullptr, kf, nullptr, 1024, 512);
    k_gemm_t<0><<<512, 256, 0, stream>>>(latb, Wuv, nullptr, nullptr, vb, 1024, 512);
    k_rope2b<<<4096, 256, 0, stream>>>(qf, kf, qb, kb);
    k_fattn<<<dim3(32, 16), 256, 0, stream>>>(qb, kb, vb, ab);
    k_gemm_t<0><<<512, 256, 0, stream>>>(ab, Wo, x, x1f, nullptr, 1024, 1024);
    k_rms2b<<<2048, 256, 0, stream>>>(x1f, n2w, h2f, h2b);
    k_init<<<1, 64, 0, stream>>>(cnt);
    k_gate<<<512, 256, 0, stream>>>(h2f, gw, gb, expert, cnt);
    k_scatter<<<1, 256, 0, stream>>>(expert, cnt, off, sorted);
    k_moe1_t<0><<<8192, 256, 0, stream>>>(h2b, W1, b1, cnt, off, sorted, hbuf);
    k_moe2_t<0><<<2048, 256, 0, stream>>>(hbuf, W2, b2w, x1f, cnt, off, sorted, out);
  }
}

// Round 7
// 436.767 us; speedup vs baseline: 2.3383x; 1.0732x over previous
//
#include <hip/hip_runtime.h>
#include <hip/hip_bf16.h>
#include <math.h>

typedef unsigned short u16;
typedef __attribute__((ext_vector_type(4))) float floatx4;
typedef __attribute__((ext_vector_type(8))) short shortx8;

#define DEVI static __device__ __forceinline__

DEVI u16 f2b(float f) {
  union { float f; unsigned int i; } v; v.f = f;
  unsigned int x = v.i;
  return (u16)((x + 0x7fffu + ((x >> 16) & 1u)) >> 16);
}

constexpr int T_ = 1024, D_ = 1024, HD_ = 64, KV_ = 512, DH_ = 4096, M_ = 2048;
#define NEGBIG (-1e30f)

// ---------------- RMSNorm (f32 in -> bf16 out) ----------------
__global__ __launch_bounds__(256) void k_rms1b(const float* __restrict__ x, const float* __restrict__ w,
                                               u16* __restrict__ outb) {
  int row = blockIdx.x, tid = threadIdx.x;
  float4 v = *(const float4*)&x[(size_t)row * D_ + tid * 4];
  float ss = v.x*v.x + v.y*v.y + v.z*v.z + v.w*v.w;
  #pragma unroll
  for (int m = 32; m >= 1; m >>= 1) ss += __shfl_xor(ss, m, 64);
  __shared__ float red[4];
  if ((tid & 63) == 0) red[tid >> 6] = ss;
  __syncthreads();
  ss = red[0] + red[1] + red[2] + red[3];
  float sc = 1.0f / sqrtf(ss * (1.0f / 1024.0f) + 1e-6f);
  float4 wv = *(const float4*)&w[tid * 4];
  ushort4 ob;
  ob.x = f2b(wv.x*v.x*sc); ob.y = f2b(wv.y*v.y*sc);
  ob.z = f2b(wv.z*v.z*sc); ob.w = f2b(wv.w*v.w*sc);
  *(ushort4*)&outb[(size_t)row * D_ + tid * 4] = ob;
}

// ---------------- RMSNorm (f32 in -> f32 out + bf16 out) ----------------
__global__ __launch_bounds__(256) void k_rms2b(const float* __restrict__ x, const float* __restrict__ w,
                                               float* __restrict__ outf, u16* __restrict__ outb) {
  int row = blockIdx.x, tid = threadIdx.x;
  float4 v = *(const float4*)&x[(size_t)row * D_ + tid * 4];
  float ss = v.x*v.x + v.y*v.y + v.z*v.z + v.w*v.w;
  #pragma unroll
  for (int m = 32; m >= 1; m >>= 1) ss += __shfl_xor(ss, m, 64);
  __shared__ float red[4];
  if ((tid & 63) == 0) red[tid >> 6] = ss;
  __syncthreads();
  ss = red[0] + red[1] + red[2] + red[3];
  float sc = 1.0f / sqrtf(ss * (1.0f / 1024.0f) + 1e-6f);
  float4 wv = *(const float4*)&w[tid * 4];
  float4 o; o.x = wv.x*v.x*sc; o.y = wv.y*v.y*sc; o.z = wv.z*v.z*sc; o.w = wv.w*v.w*sc;
  *(float4*)&outf[(size_t)row * D_ + tid * 4] = o;
  ushort4 ob; ob.x = f2b(o.x); ob.y = f2b(o.y); ob.z = f2b(o.z); ob.w = f2b(o.w);
  *(ushort4*)&outb[(size_t)row * D_ + tid * 4] = ob;
}

// ---------------- LayerNorm on latent (f32 in -> bf16 out, 512 cols) ----------------
__global__ __launch_bounds__(256) void k_lnb(const float* __restrict__ lat, const float* __restrict__ g,
                                             const float* __restrict__ bb, u16* __restrict__ ob) {
  int row = blockIdx.x, tid = threadIdx.x;
  const float* r = lat + (size_t)row * KV_;
  float v0 = r[tid], v1 = r[tid + 256];
  float s = v0 + v1;
  #pragma unroll
  for (int m = 32; m >= 1; m >>= 1) s += __shfl_xor(s, m, 64);
  __shared__ float red[4];
  if ((tid & 63) == 0) red[tid >> 6] = s;
  __syncthreads();
  float mu = (red[0] + red[1] + red[2] + red[3]) * (1.0f / 512.0f);
  __syncthreads();
  float d0 = v0 - mu, d1 = v1 - mu;
  float ss = d0*d0 + d1*d1;
  #pragma unroll
  for (int m = 32; m >= 1; m >>= 1) ss += __shfl_xor(ss, m, 64);
  if ((tid & 63) == 0) red[tid >> 6] = ss;
  __syncthreads();
  float var = (red[0] + red[1] + red[2] + red[3]) * (1.0f / 512.0f);
  float sc = 1.0f / sqrtf(var + 1e-5f);
  ob[(size_t)row * KV_ + tid]       = f2b(d0 * sc * g[tid]       + bb[tid]);
  ob[(size_t)row * KV_ + tid + 256] = f2b(d1 * sc * g[tid + 256] + bb[tid + 256]);
}

// ---------------- One-shot weight conversion f32 -> bf16 (concatenated dst) ----------------
__global__ __launch_bounds__(256) void k_cvtall(const float* __restrict__ W1, const float* __restrict__ W2,
                                                const float* __restrict__ Wq, const float* __restrict__ Wdkv,
                                                const float* __restrict__ Wuk, const float* __restrict__ Wuv,
                                                const float* __restrict__ Wo, u16* __restrict__ dst) {
  for (size_t i = (size_t)blockIdx.x * 256 + threadIdx.x; i < 9306112ull; i += (size_t)gridDim.x * 256) {
    const float* s;
    if      (i < 4194304ull) s = W1   + i * 4;
    else if (i < 8388608ull) s = W2   + (i - 4194304ull) * 4;
    else if (i < 8650752ull) s = Wq   + (i - 8388608ull) * 4;
    else if (i < 8781824ull) s = Wdkv + (i - 8650752ull) * 4;
    else if (i < 8912896ull) s = Wuk  + (i - 8781824ull) * 4;
    else if (i < 9043968ull) s = Wuv  + (i - 8912896ull) * 4;
    else                     s = Wo   + (i - 9043968ull) * 4;
    float4 f = *(const float4*)s;
    ushort4 u; u.x = f2b(f.x); u.y = f2b(f.y); u.z = f2b(f.z); u.w = f2b(f.w);
    *(ushort4*)(dst + i * 4) = u;
  }
}

// ---------------- bf16 MFMA GEMM (templated on B dtype): C[M,N] = A_bf16 @ B[N,K]^T ----------------
template<int BF16B>
__global__ __launch_bounds__(256) void k_gemm_t(const u16* __restrict__ A, const void* __restrict__ Bp,
                                                const float* __restrict__ resid, float* __restrict__ Cf,
                                                u16* __restrict__ Cb, int N, int K) {
  int bid = blockIdx.x;
  int xcd = bid & 7, jj = bid >> 3;
  int mt = jj & 31, nt = (jj >> 5) * 8 + xcd;
  __shared__ __align__(16) u16 As[64][72];
  __shared__ __align__(16) u16 Bs[64][72];
  int tid = threadIdx.x, lane = tid & 63, wave = tid >> 6;
  int wm = (wave >> 1) * 32, wn = (wave & 1) * 32;
  int lr = tid >> 2, lc = (tid & 3) * 16;
  const u16* arow = A + (size_t)(mt * 64 + lr) * K + lc;
  const u16* browb = (const u16*)Bp + (size_t)(nt * 64 + lr) * K + lc;
  const float* browf = (const float*)Bp + (size_t)(nt * 64 + lr) * K + lc;
  floatx4 z = {0.f, 0.f, 0.f, 0.f};
  floatx4 acc00 = z, acc01 = z, acc10 = z, acc11 = z;
  int fm = lane & 15, fkq = (lane >> 4) * 8;
  uint4 ra0 = *(const uint4*)&arow[0];
  uint4 ra1 = *(const uint4*)&arow[8];
  uint4 rbA, rbB; float4 rb0, rb1, rb2, rb3;
  if constexpr (BF16B) {
    rbA = *(const uint4*)&browb[0]; rbB = *(const uint4*)&browb[8];
  } else {
    rb0 = *(const float4*)&browf[0];  rb1 = *(const float4*)&browf[4];
    rb2 = *(const float4*)&browf[8];  rb3 = *(const float4*)&browf[12];
  }
  for (int kb = 0; kb < K; kb += 64) {
    *(uint4*)&As[lr][lc]     = ra0;
    *(uint4*)&As[lr][lc + 8] = ra1;
    if constexpr (BF16B) {
      *(uint4*)&Bs[lr][lc]     = rbA;
      *(uint4*)&Bs[lr][lc + 8] = rbB;
    } else {
      ushort4 u;
      u.x = f2b(rb0.x); u.y = f2b(rb0.y); u.z = f2b(rb0.z); u.w = f2b(rb0.w); *(ushort4*)&Bs[lr][lc]      = u;
      u.x = f2b(rb1.x); u.y = f2b(rb1.y); u.z = f2b(rb1.z); u.w = f2b(rb1.w); *(ushort4*)&Bs[lr][lc + 4]  = u;
      u.x = f2b(rb2.x); u.y = f2b(rb2.y); u.z = f2b(rb2.z); u.w = f2b(rb2.w); *(ushort4*)&Bs[lr][lc + 8]  = u;
      u.x = f2b(rb3.x); u.y = f2b(rb3.y); u.z = f2b(rb3.z); u.w = f2b(rb3.w); *(ushort4*)&Bs[lr][lc + 12] = u;
    }
    __syncthreads();
    if (kb + 64 < K) {
      ra0 = *(const uint4*)&arow[kb + 64];
      ra1 = *(const uint4*)&arow[kb + 72];
      if constexpr (BF16B) {
        rbA = *(const uint4*)&browb[kb + 64]; rbB = *(const uint4*)&browb[kb + 72];
      } else {
        rb0 = *(const float4*)&browf[kb + 64]; rb1 = *(const float4*)&browf[kb + 68];
        rb2 = *(const float4*)&browf[kb + 72]; rb3 = *(const float4*)&browf[kb + 76];
      }
    }
    #pragma unroll
    for (int ks = 0; ks < 64; ks += 32) {
      shortx8 a0  = *(const shortx8*)&As[wm + fm][ks + fkq];
      shortx8 a1  = *(const shortx8*)&As[wm + 16 + fm][ks + fkq];
      shortx8 b0  = *(const shortx8*)&Bs[wn + fm][ks + fkq];
      shortx8 b1v = *(const shortx8*)&Bs[wn + 16 + fm][ks + fkq];
      acc00 = __builtin_amdgcn_mfma_f32_16x16x32_bf16(a0, b0,  acc00, 0, 0, 0);
      acc01 = __builtin_amdgcn_mfma_f32_16x16x32_bf16(a0, b1v, acc01, 0, 0, 0);
      acc10 = __builtin_amdgcn_mfma_f32_16x16x32_bf16(a1, b0,  acc10, 0, 0, 0);
      acc11 = __builtin_amdgcn_mfma_f32_16x16x32_bf16(a1, b1v, acc11, 0, 0, 0);
    }
    __syncthreads();
  }
  int q4 = (lane >> 4) * 4, cix = lane & 15;
  #pragma unroll
  for (int im = 0; im < 2; ++im) {
    #pragma unroll
    for (int rg = 0; rg < 4; ++rg) {
      int row = mt * 64 + wm + im * 16 + q4 + rg;
      #pragma unroll
      for (int in = 0; in < 2; ++in) {
        int gn = nt * 64 + wn + in * 16 + cix;
        float vv = (im == 0 ? (in == 0 ? acc00[rg] : acc01[rg]) : (in == 0 ? acc10[rg] : acc11[rg]));
        size_t idx = (size_t)row * N + gn;
        if (Cb) {
          Cb[idx] = f2b(vv);
        } else {
          if (resid) vv += resid[idx];
          Cf[idx] = vv;
        }
      }
    }
  }
}

// ---------------- RoPE: f32 q,k in -> bf16 qb (pre-scaled 1/8), kb out ----------------
__global__ __launch_bounds__(256) void k_rope2b(const float* __restrict__ q, const float* __restrict__ k,
                                                u16* __restrict__ qb, u16* __restrict__ kb) {
  int g = blockIdx.x * 256 + threadIdx.x;
  int j = g & 31;
  int h = (g >> 5) & 15;
  int row = g >> 9;
  int t = row & (T_ - 1);
  float p = (float)pow(10000.0, (double)j * (1.0 / 32.0));
  float ang = (float)t / p;
  float sn, cs; sincosf(ang, &sn, &cs);
  size_t base = (size_t)row * D_ + h * 64 + j;
  float x1 = q[base], x2 = q[base + 32];
  qb[base]      = f2b((x1 * cs - x2 * sn) * 0.125f);
  qb[base + 32] = f2b((x1 * sn + x2 * cs) * 0.125f);
  x1 = k[base]; x2 = k[base + 32];
  kb[base]      = f2b(x1 * cs - x2 * sn);
  kb[base + 32] = f2b(x1 * sn + x2 * cs);
}

// ---------------- Flash attention, bf16 MFMA, wave-owns-16-rows, 2 syncs/tile ----------------
// Grid: (32 [qt x b], 16 heads), 256 threads = 4 waves; wave w owns q-rows [w*16,(w+1)*16).
// Softmax fully wave-local (no cross-wave reductions, no barrier between S and PV).
__global__ __launch_bounds__(256) void k_fattn(const u16* __restrict__ qbp, const u16* __restrict__ kbp,
                                               const u16* __restrict__ vbp, u16* __restrict__ ob) {
  int idx = blockIdx.x, h = blockIdx.y;
  int b = idx >> 4;
  int qt = idx & 15;
  if (b) qt = 15 - qt;  // complementary pairing: co-resident pair sums to 17 k-tiles
  __shared__ __align__(16) u16 Qs[64][72];   // [q][d] bf16, pre-scaled 1/8
  __shared__ __align__(16) u16 Ks[64][72];   // [k][d]
  __shared__ __align__(16) u16 Vs[64][72];   // [d][k] transposed (B-operand for PV)
  __shared__ __align__(16) u16 Ps[64][72];   // [q][k] bf16 (A-operand for PV; rows wave-private)
  int tid = threadIdx.x, lane = tid & 63, wave = tid >> 6;
  int fm = lane & 15, fkq = (lane >> 4) * 8;
  int q4 = (lane >> 4) * 4, cix = lane & 15;
  int w16 = wave * 16;
  size_t rowbase = (size_t)b * T_;
  int colbase = h * HD_;
  int q0 = qt * 64;
  int lr = tid >> 2, ld = (tid & 3) * 16;
  {
    const u16* qr = qbp + (rowbase + q0 + lr) * D_ + colbase + ld;
    *(uint4*)&Qs[lr][ld]     = *(const uint4*)&qr[0];
    *(uint4*)&Qs[lr][ld + 8] = *(const uint4*)&qr[8];
  }
  floatx4 z = {0.f, 0.f, 0.f, 0.f};
  floatx4 s[4], o[4];
  o[0] = z; o[1] = z; o[2] = z; o[3] = z;
  float m[4], l[4];
  #pragma unroll
  for (int rg = 0; rg < 4; ++rg) { m[rg] = NEGBIG; l[rg] = 0.f; }
  // register prefetch of K/V tile 0
  const u16* kr = kbp + (rowbase + lr) * D_ + colbase + ld;
  const u16* vr = vbp + (rowbase + lr) * D_ + colbase + ld;
  uint4 rk0 = *(const uint4*)&kr[0], rk1 = *(const uint4*)&kr[8];
  uint4 rv0 = *(const uint4*)&vr[0], rv1 = *(const uint4*)&vr[8];
  for (int kt = 0; kt <= qt; ++kt) {
    __syncthreads();  // prev tile's Ks/Vs reads done (also covers Q staging on iter 0)
    *(uint4*)&Ks[lr][ld]     = rk0;
    *(uint4*)&Ks[lr][ld + 8] = rk1;
    {
      union { uint4 v4[2]; u16 e[16]; } vv;
      vv.v4[0] = rv0; vv.v4[1] = rv1;
      #pragma unroll
      for (int c = 0; c < 16; ++c) Vs[ld + c][lr] = vv.e[c];
    }
    __syncthreads();  // staging visible
    if (kt < qt) {    // prefetch next tile; latency hides under S/softmax/PV below
      kr += 64 * D_; vr += 64 * D_;
      rk0 = *(const uint4*)&kr[0]; rk1 = *(const uint4*)&kr[8];
      rv0 = *(const uint4*)&vr[0]; rv1 = *(const uint4*)&vr[8];
    }
    s[0] = z; s[1] = z; s[2] = z; s[3] = z;
    #pragma unroll
    for (int ks = 0; ks < 64; ks += 32) {
      shortx8 a = *(const shortx8*)&Qs[w16 + fm][ks + fkq];
      #pragma unroll
      for (int nb = 0; nb < 4; ++nb) {
        shortx8 bb = *(const shortx8*)&Ks[nb * 16 + fm][ks + fkq];
        s[nb] = __builtin_amdgcn_mfma_f32_16x16x32_bf16(a, bb, s[nb], 0, 0, 0);
      }
    }
    if (kt == qt) {  // diagonal tile: local causal mask (row = w16+q4+rg, col = nb*16+cix)
      #pragma unroll
      for (int nb = 0; nb < 4; ++nb)
        #pragma unroll
        for (int rg = 0; rg < 4; ++rg)
          if (nb * 16 + cix > w16 + q4 + rg) s[nb][rg] = NEGBIG;
    }
    #pragma unroll
    for (int rg = 0; rg < 4; ++rg) {
      float mx = fmaxf(fmaxf(s[0][rg], s[1][rg]), fmaxf(s[2][rg], s[3][rg]));
      #pragma unroll
      for (int mk = 8; mk >= 1; mk >>= 1) mx = fmaxf(mx, __shfl_xor(mx, mk, 64));
      float mn = fmaxf(m[rg], mx);
      float f = __expf(m[rg] - mn);
      m[rg] = mn;
      float p0 = __expf(s[0][rg] - mn);
      float p1 = __expf(s[1][rg] - mn);
      float p2 = __expf(s[2][rg] - mn);
      float p3 = __expf(s[3][rg] - mn);
      float rs = (p0 + p1) + (p2 + p3);
      #pragma unroll
      for (int mk = 8; mk >= 1; mk >>= 1) rs += __shfl_xor(rs, mk, 64);
      l[rg] = l[rg] * f + rs;
      o[0][rg] *= f; o[1][rg] *= f; o[2][rg] *= f; o[3][rg] *= f;
      int prow = w16 + q4 + rg;
      Ps[prow][cix]      = f2b(p0);
      Ps[prow][16 + cix] = f2b(p1);
      Ps[prow][32 + cix] = f2b(p2);
      Ps[prow][48 + cix] = f2b(p3);
    }
    // PV: A = own Ps rows (wave-private -> no barrier), B = Vs
    #pragma unroll
    for (int ks = 0; ks < 64; ks += 32) {
      shortx8 a = *(const shortx8*)&Ps[w16 + fm][ks + fkq];
      #pragma unroll
      for (int db = 0; db < 4; ++db) {
        shortx8 bb = *(const shortx8*)&Vs[db * 16 + fm][ks + fkq];
        o[db] = __builtin_amdgcn_mfma_f32_16x16x32_bf16(a, bb, o[db], 0, 0, 0);
      }
    }
  }
  #pragma unroll
  for (int rg = 0; rg < 4; ++rg) {
    float inv = 1.0f / l[rg];
    size_t base = (rowbase + q0 + w16 + q4 + rg) * D_ + colbase;
    #pragma unroll
    for (int db = 0; db < 4; ++db)
      ob[base + db * 16 + cix] = f2b(o[db][rg] * inv);
  }
}

// ---------------- MoE gate ----------------
__global__ __launch_bounds__(256) void k_init(int* cnt) { if (threadIdx.x < 4) cnt[threadIdx.x] = 0; }

__global__ __launch_bounds__(256) void k_gate(const float* __restrict__ h2, const float* __restrict__ gw,
                                              const float* __restrict__ gb, int* __restrict__ expert,
                                              int* __restrict__ cnt) {
  int wid = threadIdx.x >> 6, lane = threadIdx.x & 63;
  int t = blockIdx.x * 4 + wid;
  const float* hr = h2 + (size_t)t * D_;
  float a0 = 0, a1 = 0, a2 = 0, a3 = 0;
  for (int c = lane; c < D_; c += 64) {
    float xv = hr[c];
    a0 += xv * gw[c];
    a1 += xv * gw[D_ + c];
    a2 += xv * gw[2 * D_ + c];
    a3 += xv * gw[3 * D_ + c];
  }
  #pragma unroll
  for (int m = 32; m >= 1; m >>= 1) {
    a0 += __shfl_xor(a0, m, 64); a1 += __shfl_xor(a1, m, 64);
    a2 += __shfl_xor(a2, m, 64); a3 += __shfl_xor(a3, m, 64);
  }
  if (lane == 0) {
    float l0 = a0 + gb[0], l1 = a1 + gb[1], l2 = a2 + gb[2], l3 = a3 + gb[3];
    int best = 0; float bv = l0;
    if (l1 > bv) { bv = l1; best = 1; }
    if (l2 > bv) { bv = l2; best = 2; }
    if (l3 > bv) { bv = l3; best = 3; }
    expert[t] = best;
    atomicAdd(&cnt[best], 1);
  }
}

__global__ __launch_bounds__(256) void k_scatter(const int* __restrict__ expert, const int* __restrict__ cnt,
                                                 int* __restrict__ off, int* __restrict__ sorted) {
  __shared__ int cur[4];
  if (threadIdx.x == 0) {
    int o0 = 0, o1 = cnt[0], o2 = o1 + cnt[1], o3 = o2 + cnt[2];
    off[0] = o0; off[1] = o1; off[2] = o2; off[3] = o3;
    cur[0] = o0; cur[1] = o1; cur[2] = o2; cur[3] = o3;
  }
  __syncthreads();
  for (int t = threadIdx.x; t < M_; t += 256) {
    int e = expert[t];
    int p = atomicAdd(&cur[e], 1);
    sorted[p] = t;
  }
}

// ---------------- MoE MFMA GEMM 1 (templated B): hbuf = bf16(relu(A[gather] @ W1[e]^T + b1[e])) ----------------
template<int BF16B>
__global__ __launch_bounds__(256) void k_moe1_t(const u16* __restrict__ A, const void* __restrict__ W1p,
                                                const float* __restrict__ b1, const int* __restrict__ cnt,
                                                const int* __restrict__ off, const int* __restrict__ sorted,
                                                u16* __restrict__ hbuf) {
  int bid = blockIdx.x;
  int xcd = bid & 7, jj = bid >> 3;
  int mt = jj & 31, combo = (jj >> 5) * 8 + xcd;   // combo in [0,256)
  int e = combo >> 6, nt = combo & 63;
  int rem = cnt[e] - mt * 64;
  if (rem <= 0) return;
  __shared__ __align__(16) u16 As[64][72];
  __shared__ __align__(16) u16 Bs[64][72];
  int tid = threadIdx.x, lane = tid & 63, wave = tid >> 6;
  int wm = (wave >> 1) * 32, wn = (wave & 1) * 32;
  int lr = tid >> 2, lc = (tid & 3) * 16;
  int rr = lr < rem ? lr : rem - 1;
  const u16* arow = A + (size_t)sorted[off[e] + mt * 64 + rr] * D_ + lc;
  const u16* browb = (const u16*)W1p + (size_t)e * DH_ * D_ + (size_t)(nt * 64 + lr) * D_ + lc;
  const float* browf = (const float*)W1p + (size_t)e * DH_ * D_ + (size_t)(nt * 64 + lr) * D_ + lc;
  floatx4 z = {0.f, 0.f, 0.f, 0.f};
  floatx4 acc00 = z, acc01 = z, acc10 = z, acc11 = z;
  int fm = lane & 15, fkq = (lane >> 4) * 8;
  uint4 ra0 = *(const uint4*)&arow[0];
  uint4 ra1 = *(const uint4*)&arow[8];
  uint4 rbA, rbB; float4 rb0, rb1, rb2, rb3;
  if constexpr (BF16B) {
    rbA = *(const uint4*)&browb[0]; rbB = *(const uint4*)&browb[8];
  } else {
    rb0 = *(const float4*)&browf[0];  rb1 = *(const float4*)&browf[4];
    rb2 = *(const float4*)&browf[8];  rb3 = *(const float4*)&browf[12];
  }
  for (int kb = 0; kb < D_; kb += 64) {
    *(uint4*)&As[lr][lc]     = ra0;
    *(uint4*)&As[lr][lc + 8] = ra1;
    if constexpr (BF16B) {
      *(uint4*)&Bs[lr][lc]     = rbA;
      *(uint4*)&Bs[lr][lc + 8] = rbB;
    } else {
      ushort4 u;
      u.x = f2b(rb0.x); u.y = f2b(rb0.y); u.z = f2b(rb0.z); u.w = f2b(rb0.w); *(ushort4*)&Bs[lr][lc]      = u;
      u.x = f2b(rb1.x); u.y = f2b(rb1.y); u.z = f2b(rb1.z); u.w = f2b(rb1.w); *(ushort4*)&Bs[lr][lc + 4]  = u;
      u.x = f2b(rb2.x); u.y = f2b(rb2.y); u.z = f2b(rb2.z); u.w = f2b(rb2.w); *(ushort4*)&Bs[lr][lc + 8]  = u;
      u.x = f2b(rb3.x); u.y = f2b(rb3.y); u.z = f2b(rb3.z); u.w = f2b(rb3.w); *(ushort4*)&Bs[lr][lc + 12] = u;
    }
    __syncthreads();
    if (kb + 64 < D_) {
      ra0 = *(const uint4*)&arow[kb + 64];
      ra1 = *(const uint4*)&arow[kb + 72];
      if constexpr (BF16B) {
        rbA = *(const uint4*)&browb[kb + 64]; rbB = *(const uint4*)&browb[kb + 72];
      } else {
        rb0 = *(const float4*)&browf[kb + 64]; rb1 = *(const float4*)&browf[kb + 68];
        rb2 = *(const float4*)&browf[kb + 72]; rb3 = *(const float4*)&browf[kb + 76];
      }
    }
    #pragma unroll
    for (int ks = 0; ks < 64; ks += 32) {
      shortx8 a0  = *(const shortx8*)&As[wm + fm][ks + fkq];
      shortx8 a1  = *(const shortx8*)&As[wm + 16 + fm][ks + fkq];
      shortx8 b0  = *(const shortx8*)&Bs[wn + fm][ks + fkq];
      shortx8 b1v = *(const shortx8*)&Bs[wn + 16 + fm][ks + fkq];
      acc00 = __builtin_amdgcn_mfma_f32_16x16x32_bf16(a0, b0,  acc00, 0, 0, 0);
      acc01 = __builtin_amdgcn_mfma_f32_16x16x32_bf16(a0, b1v, acc01, 0, 0, 0);
      acc10 = __builtin_amdgcn_mfma_f32_16x16x32_bf16(a1, b0,  acc10, 0, 0, 0);
      acc11 = __builtin_amdgcn_mfma_f32_16x16x32_bf16(a1, b1v, acc11, 0, 0, 0);
    }
    __syncthreads();
  }
  int q4 = (lane >> 4) * 4, cix = lane & 15;
  #pragma unroll
  for (int im = 0; im < 2; ++im) {
    #pragma unroll
    for (int rg = 0; rg < 4; ++rg) {
      int ml = wm + im * 16 + q4 + rg;
      if (ml >= rem) continue;
      size_t grow = (size_t)(off[e] + mt * 64 + ml);
      #pragma unroll
      for (int in = 0; in < 2; ++in) {
        int gn = nt * 64 + wn + in * 16 + cix;
        float vv = (im == 0 ? (in == 0 ? acc00[rg] : acc01[rg]) : (in == 0 ? acc10[rg] : acc11[rg]));
        vv += b1[e * DH_ + gn];
        hbuf[grow * DH_ + gn] = f2b(fmaxf(vv, 0.f));
      }
    }
  }
}

// ---------------- MoE MFMA GEMM 2 (unsplit, small-ws fallback) ----------------
template<int BF16B>
__global__ __launch_bounds__(256) void k_moe2_t(const u16* __restrict__ hbuf, const void* __restrict__ W2p,
                                                const float* __restrict__ b2w, const float* __restrict__ x1f,
                                                const int* __restrict__ cnt, const int* __restrict__ off,
                                                const int* __restrict__ sorted, float* __restrict__ out) {
  int bid = blockIdx.x;
  int xcd = bid & 7, jj = bid >> 3;
  int mt = jj & 31, combo = (jj >> 5) * 8 + xcd;   // combo in [0,64)
  int e = combo >> 4, nt = combo & 15;
  int rem = cnt[e] - mt * 64;
  if (rem <= 0) return;
  __shared__ __align__(16) u16 As[64][72];
  __shared__ __align__(16) u16 Bs[64][72];
  int tid = threadIdx.x, lane = tid & 63, wave = tid >> 6;
  int wm = (wave >> 1) * 32, wn = (wave & 1) * 32;
  int lr = tid >> 2, lc = (tid & 3) * 16;
  int rr = lr < rem ? lr : rem - 1;
  const u16* arow = hbuf + (size_t)(off[e] + mt * 64 + rr) * DH_ + lc;
  const u16* browb = (const u16*)W2p + (size_t)e * D_ * DH_ + (size_t)(nt * 64 + lr) * DH_ + lc;
  const float* browf = (const float*)W2p + (size_t)e * D_ * DH_ + (size_t)(nt * 64 + lr) * DH_ + lc;
  floatx4 z = {0.f, 0.f, 0.f, 0.f};
  floatx4 acc00 = z, acc01 = z, acc10 = z, acc11 = z;
  int fm = lane & 15, fkq = (lane >> 4) * 8;
  uint4 ra0 = *(const uint4*)&arow[0];
  uint4 ra1 = *(const uint4*)&arow[8];
  uint4 rbA, rbB; float4 rb0, rb1, rb2, rb3;
  if constexpr (BF16B) {
    rbA = *(const uint4*)&browb[0]; rbB = *(const uint4*)&browb[8];
  } else {
    rb0 = *(const float4*)&browf[0];  rb1 = *(const float4*)&browf[4];
    rb2 = *(const float4*)&browf[8];  rb3 = *(const float4*)&browf[12];
  }
  for (int kb = 0; kb < DH_; kb += 64) {
    *(uint4*)&As[lr][lc]     = ra0;
    *(uint4*)&As[lr][lc + 8] = ra1;
    if constexpr (BF16B) {
      *(uint4*)&Bs[lr][lc]     = rbA;
      *(uint4*)&Bs[lr][lc + 8] = rbB;
    } else {
      ushort4 u;
      u.x = f2b(rb0.x); u.y = f2b(rb0.y); u.z = f2b(rb0.z); u.w = f2b(rb0.w); *(ushort4*)&Bs[lr][lc]      = u;
      u.x = f2b(rb1.x); u.y = f2b(rb1.y); u.z = f2b(rb1.z); u.w = f2b(rb1.w); *(ushort4*)&Bs[lr][lc + 4]  = u;
      u.x = f2b(rb2.x); u.y = f2b(rb2.y); u.z = f2b(rb2.z); u.w = f2b(rb2.w); *(ushort4*)&Bs[lr][lc + 8]  = u;
      u.x = f2b(rb3.x); u.y = f2b(rb3.y); u.z = f2b(rb3.z); u.w = f2b(rb3.w); *(ushort4*)&Bs[lr][lc + 12] = u;
    }
    __syncthreads();
    if (kb + 64 < DH_) {
      ra0 = *(const uint4*)&arow[kb + 64];
      ra1 = *(const uint4*)&arow[kb + 72];
      if constexpr (BF16B) {
        rbA = *(const uint4*)&browb[kb + 64]; rbB = *(const uint4*)&browb[kb + 72];
      } else {
        rb0 = *(const float4*)&browf[kb + 64]; rb1 = *(const float4*)&browf[kb + 68];
        rb2 = *(const float4*)&browf[kb + 72]; rb3 = *(const float4*)&browf[kb + 76];
      }
    }
    #pragma unroll
    for (int ks = 0; ks < 64; ks += 32) {
      shortx8 a0  = *(const shortx8*)&As[wm + fm][ks + fkq];
      shortx8 a1  = *(const shortx8*)&As[wm + 16 + fm][ks + fkq];
      shortx8 b0  = *(const shortx8*)&Bs[wn + fm][ks + fkq];
      shortx8 b1v = *(const shortx8*)&Bs[wn + 16 + fm][ks + fkq];
      acc00 = __builtin_amdgcn_mfma_f32_16x16x32_bf16(a0, b0,  acc00, 0, 0, 0);
      acc01 = __builtin_amdgcn_mfma_f32_16x16x32_bf16(a0, b1v, acc01, 0, 0, 0);
      acc10 = __builtin_amdgcn_mfma_f32_16x16x32_bf16(a1, b0,  acc10, 0, 0, 0);
      acc11 = __builtin_amdgcn_mfma_f32_16x16x32_bf16(a1, b1v, acc11, 0, 0, 0);
    }
    __syncthreads();
  }
  int q4 = (lane >> 4) * 4, cix = lane & 15;
  #pragma unroll
  for (int im = 0; im < 2; ++im) {
    #pragma unroll
    for (int rg = 0; rg < 4; ++rg) {
      int ml = wm + im * 16 + q4 + rg;
      if (ml >= rem) continue;
      int tok = sorted[off[e] + mt * 64 + ml];
      #pragma unroll
      for (int in = 0; in < 2; ++in) {
        int gn = nt * 64 + wn + in * 16 + cix;
        float vv = (im == 0 ? (in == 0 ? acc00[rg] : acc01[rg]) : (in == 0 ? acc10[rg] : acc11[rg]));
        out[(size_t)tok * D_ + gn] = vv + b2w[e * D_ + gn] + x1f[(size_t)tok * D_ + gn];
      }
    }
  }
}

// ---------------- MoE GEMM 2, K-split 2: pbuf[ks] = hbuf @ W2[e][:, ks*2048:(ks+1)*2048]^T ----------------
__global__ __launch_bounds__(256) void k_moe2s(const u16* __restrict__ hbuf, const u16* __restrict__ W2b,
                                               const int* __restrict__ cnt, const int* __restrict__ off,
                                               float* __restrict__ pbuf) {
  int bid = blockIdx.x;
  int xcd = bid & 7, jj = bid >> 3;
  int mt = jj & 31;
  int combo = (jj >> 5) * 8 + xcd;
  int ks = combo & 1, ec = combo >> 1;
  int e = ec >> 4, nt = ec & 15;
  int rem = cnt[e] - mt * 64;
  if (rem <= 0) return;
  const int KS = DH_ / 2;
  int k0 = ks * KS;
  __shared__ __align__(16) u16 As[64][72];
  __shared__ __align__(16) u16 Bs[64][72];
  int tid = threadIdx.x, lane = tid & 63, wave = tid >> 6;
  int wm = (wave >> 1) * 32, wn = (wave & 1) * 32;
  int lr = tid >> 2, lc = (tid & 3) * 16;
  int rr = lr < rem ? lr : rem - 1;
  const u16* arow = hbuf + (size_t)(off[e] + mt * 64 + rr) * DH_ + k0 + lc;
  const u16* brow = W2b + (size_t)e * D_ * DH_ + (size_t)(nt * 64 + lr) * DH_ + k0 + lc;
  floatx4 z = {0.f, 0.f, 0.f, 0.f};
  floatx4 acc00 = z, acc01 = z, acc10 = z, acc11 = z;
  int fm = lane & 15, fkq = (lane >> 4) * 8;
  uint4 ra0 = *(const uint4*)&arow[0];
  uint4 ra1 = *(const uint4*)&arow[8];
  uint4 rbA = *(const uint4*)&brow[0];
  uint4 rbB = *(const uint4*)&brow[8];
  for (int kb = 0; kb < KS; kb += 64) {
    *(uint4*)&As[lr][lc]     = ra0;
    *(uint4*)&As[lr][lc + 8] = ra1;
    *(uint4*)&Bs[lr][lc]     = rbA;
    *(uint4*)&Bs[lr][lc + 8] = rbB;
    __syncthreads();
    if (kb + 64 < KS) {
      ra0 = *(const uint4*)&arow[kb + 64];
      ra1 = *(const uint4*)&arow[kb + 72];
      rbA = *(const uint4*)&brow[kb + 64];
      rbB = *(const uint4*)&brow[kb + 72];
    }
    #pragma unroll
    for (int kk = 0; kk < 64; kk += 32) {
      shortx8 a0  = *(const shortx8*)&As[wm + fm][kk + fkq];
      shortx8 a1  = *(const shortx8*)&As[wm + 16 + fm][kk + fkq];
      shortx8 b0  = *(const shortx8*)&Bs[wn + fm][kk + fkq];
      shortx8 b1v = *(const shortx8*)&Bs[wn + 16 + fm][kk + fkq];
      acc00 = __builtin_amdgcn_mfma_f32_16x16x32_bf16(a0, b0,  acc00, 0, 0, 0);
      acc01 = __builtin_amdgcn_mfma_f32_16x16x32_bf16(a0, b1v, acc01, 0, 0, 0);
      acc10 = __builtin_amdgcn_mfma_f32_16x16x32_bf16(a1, b0,  acc10, 0, 0, 0);
      acc11 = __builtin_amdgcn_mfma_f32_16x16x32_bf16(a1, b1v, acc11, 0, 0, 0);
    }
    __syncthreads();
  }
  float* pb = pbuf + (size_t)ks * M_ * D_;
  int q4 = (lane >> 4) * 4, cix = lane & 15;
  #pragma unroll
  for (int im = 0; im < 2; ++im) {
    #pragma unroll
    for (int rg = 0; rg < 4; ++rg) {
      int ml = wm + im * 16 + q4 + rg;
      if (ml >= rem) continue;
      size_t srow = (size_t)(off[e] + mt * 64 + ml);
      #pragma unroll
      for (int in = 0; in < 2; ++in) {
        int gn = nt * 64 + wn + in * 16 + cix;
        float vv = (im == 0 ? (in == 0 ? acc00[rg] : acc01[rg]) : (in == 0 ? acc10[rg] : acc11[rg]));
        pb[srow * D_ + gn] = vv;
      }
    }
  }
}

// ---------------- MoE reduce: out[tok] = pbuf0[r] + pbuf1[r] + b2[e] + x1f[tok] ----------------
__global__ __launch_bounds__(256) void k_moered(const float* __restrict__ pbuf, const float* __restrict__ b2w,
                                                const float* __restrict__ x1f, const int* __restrict__ off,
                                                const int* __restrict__ sorted, float* __restrict__ out) {
  int r = blockIdx.x, tid = threadIdx.x;
  int tok = sorted[r];
  int e = (r >= off[3]) ? 3 : (r >= off[2]) ? 2 : (r >= off[1]) ? 1 : 0;
  size_t c = (size_t)tid * 4;
  float4 a = *(const float4*)&pbuf[(size_t)r * D_ + c];
  float4 b = *(const float4*)&pbuf[(size_t)M_ * D_ + (size_t)r * D_ + c];
  float4 bb = *(const float4*)&b2w[(size_t)e * D_ + c];
  float4 xr = *(const float4*)&x1f[(size_t)tok * D_ + c];
  float4 o;
  o.x = a.x + b.x + bb.x + xr.x;
  o.y = a.y + b.y + bb.y + xr.y;
  o.z = a.z + b.z + bb.z + xr.z;
  o.w = a.w + b.w + bb.w + xr.w;
  *(float4*)&out[(size_t)tok * D_ + c] = o;
}

extern "C" void kernel_launch(void* const* d_in, const int* in_sizes, int n_in,
                              void* d_out, int out_size, void* d_ws, size_t ws_size,
                              hipStream_t stream) {
  int map[16];
  for (int i = 0; i < 16; ++i) map[i] = i;
  if (n_in == 16 && in_sizes[0] == 16777216) {
    const int mm[16] = {15, 13, 14, 4, 2, 5, 6, 3, 12, 11, 10, 9, 0, 7, 1, 8};
    for (int i = 0; i < 16; ++i) map[i] = mm[i];
  } else if (n_in == 16 && in_sizes[0] == 4096) {
    for (int i = 0; i < 16; ++i) map[i] = 15 - i;
  }
  const float* x    = (const float*)d_in[map[0]];
  const float* n1w  = (const float*)d_in[map[1]];
  const float* n2w  = (const float*)d_in[map[2]];
  const float* Wq   = (const float*)d_in[map[3]];
  const float* Wdkv = (const float*)d_in[map[4]];
  const float* Wuk  = (const float*)d_in[map[5]];
  const float* Wuv  = (const float*)d_in[map[6]];
  const float* Wo   = (const float*)d_in[map[7]];
  const float* lng  = (const float*)d_in[map[8]];
  const float* lnb  = (const float*)d_in[map[9]];
  const float* gw   = (const float*)d_in[map[10]];
  const float* gb   = (const float*)d_in[map[11]];
  const float* W1   = (const float*)d_in[map[12]];
  const float* b1   = (const float*)d_in[map[13]];
  const float* W2   = (const float*)d_in[map[14]];
  const float* b2w  = (const float*)d_in[map[15]];
  float* out = (float*)d_out;
  char* ws = (char*)d_ws;
  const size_t MB = 1ull << 20;
  // Activation overlay [0,36) MB (unchanged from round 6):
  //  [0,8)  : qf f32 (Wq -> rope)                 -> x1f f32 (Wo out; residual, live to end)
  //  [8,16) : kf f32 (Wuk -> rope)                -> hbuf.lo bf16 (moe1 -> moe2s)
  //  [16,20): latf f32 (Wdkv -> ln)               -> qb bf16 (rope -> fattn)      -> hbuf.mid
  //  [20,24): h1b bf16 (rms1 -> Wq,Wdkv)          -> kb bf16 (rope -> fattn)      -> hbuf.hi
  //  [24,26): latb bf16 (ln -> Wuk,Wuv)           \
  //  [26,30): vb bf16 (Wuv -> fattn)               } -> h2f f32 [24,32) (rms2 -> gate)
  //  [30,34): ab bf16 (fattn -> Wo)               /
  //  [32,36): h2b bf16 (rms2 -> moe1)
  // Big path: bf16 weights [36,107); pbuf[2][2048][1024] f32 [24,40) over dead h2f/h2b/W1b-head.
  float* qf   = (float*)(ws + 0);
  float* x1f  = (float*)(ws + 0);
  float* kf   = (float*)(ws + 8 * MB);
  u16*   hbuf = (u16*)(ws + 8 * MB);       // 16MB: [8,24)
  float* latf = (float*)(ws + 16 * MB);
  u16*   qb   = (u16*)(ws + 16 * MB);
  u16*   h1b  = (u16*)(ws + 20 * MB);
  u16*   kb   = (u16*)(ws + 20 * MB);
  u16*   latb = (u16*)(ws + 24 * MB);
  float* h2f  = (float*)(ws + 24 * MB);
  u16*   vb   = (u16*)(ws + 26 * MB);
  u16*   ab   = (u16*)(ws + 30 * MB);
  u16*   h2b  = (u16*)(ws + 32 * MB);
  float* pbuf = (float*)(ws + 24 * MB);    // 16MB: [24,40), big path only

  bool big = ws_size >= (107ull * MB + (64ull << 10));
  u16* wb = (u16*)(ws + 36 * MB);
  u16* W1b   = wb;
  u16* W2b   = wb + 16777216;
  u16* Wqb   = wb + 33554432;
  u16* Wdkvb = wb + 34603008;
  u16* Wukb  = wb + 35127296;
  u16* Wuvb  = wb + 35651584;
  u16* Wob   = wb + 36175872;
  int* cnt    = (int*)(ws + (big ? 107 * MB : 36 * MB));
  int* off    = cnt + 8;
  int* expert = cnt + 16;
  int* sorted = expert + 2048;

  if (big) {
    k_cvtall<<<2048, 256, 0, stream>>>(W1, W2, Wq, Wdkv, Wuk, Wuv, Wo, wb);
    k_rms1b<<<2048, 256, 0, stream>>>(x, n1w, h1b);
    k_gemm_t<1><<<512, 256, 0, stream>>>(h1b, Wqb, nullptr, qf, nullptr, 1024, 1024);
    k_gemm_t<1><<<256, 256, 0, stream>>>(h1b, Wdkvb, nullptr, latf, nullptr, 512, 1024);
    k_lnb<<<2048, 256, 0, stream>>>(latf, lng, lnb, latb);
    k_gemm_t<1><<<512, 256, 0, stream>>>(latb, Wukb, nullptr, kf, nullptr, 1024, 512);
    k_gemm_t<1><<<512, 256, 0, stream>>>(latb, Wuvb, nullptr, nullptr, vb, 1024, 512);
    k_rope2b<<<4096, 256, 0, stream>>>(qf, kf, qb, kb);
    k_fattn<<<dim3(32, 16), 256, 0, stream>>>(qb, kb, vb, ab);
    k_gemm_t<1><<<512, 256, 0, stream>>>(ab, Wob, x, x1f, nullptr, 1024, 1024);
    k_rms2b<<<2048, 256, 0, stream>>>(x1f, n2w, h2f, h2b);
    k_init<<<1, 64, 0, stream>>>(cnt);
    k_gate<<<512, 256, 0, stream>>>(h2f, gw, gb, expert, cnt);
    k_scatter<<<1, 256, 0, stream>>>(expert, cnt, off, sorted);
    k_moe1_t<1><<<8192, 256, 0, stream>>>(h2b, W1b, b1, cnt, off, sorted, hbuf);
    k_moe2s<<<4096, 256, 0, stream>>>(hbuf, W2b, cnt, off, pbuf);
    k_moered<<<2048, 256, 0, stream>>>(pbuf, b2w, x1f, off, sorted, out);
  } else {
    k_rms1b<<<2048, 256, 0, stream>>>(x, n1w, h1b);
    k_gemm_t<0><<<512, 256, 0, stream>>>(h1b, Wq, nullptr, qf, nullptr, 1024, 1024);
    k_gemm_t<0><<<256, 256, 0, stream>>>(h1b, Wdkv, nullptr, latf, nullptr, 512, 1024);
    k_lnb<<<2048, 256, 0, stream>>>(latf, lng, lnb, latb);
    k_gemm_t<0><<<512, 256, 0, stream>>>(latb, Wuk, nullptr, kf, nullptr, 1024, 512);
    k_gemm_t<0><<<512, 256, 0, stream>>>(latb, Wuv, nullptr, nullptr, vb, 1024, 512);
    k_rope2b<<<4096, 256, 0, stream>>>(qf, kf, qb, kb);
    k_fattn<<<dim3(32, 16), 256, 0, stream>>>(qb, kb, vb, ab);
    k_gemm_t<0><<<512, 256, 0, stream>>>(ab, Wo, x, x1f, nullptr, 1024, 1024);
    k_rms2b<<<2048, 256, 0, stream>>>(x1f, n2w, h2f, h2b);
    k_init<<<1, 64, 0, stream>>>(cnt);
    k_gate<<<512, 256, 0, stream>>>(h2f, gw, gb, expert, cnt);
    k_scatter<<<1, 256, 0, stream>>>(expert, cnt, off, sorted);
    k_moe1_t<0><<<8192, 256, 0, stream>>>(h2b, W1, b1, cnt, off, sorted, hbuf);
    k_moe2_t<0><<<2048, 256, 0, stream>>>(hbuf, W2, b2w, x1f, cnt, off, sorted, out);
  }
}

// Round 8
// 416.812 us; speedup vs baseline: 2.4503x; 1.0479x over previous
//
#include <hip/hip_runtime.h>
#include <hip/hip_bf16.h>
#include <math.h>

typedef unsigned short u16;
typedef __attribute__((ext_vector_type(4))) float floatx4;
typedef __attribute__((ext_vector_type(8))) short shortx8;

#define DEVI static __device__ __forceinline__

DEVI u16 f2b(float f) {
  union { float f; unsigned int i; } v; v.f = f;
  unsigned int x = v.i;
  return (u16)((x + 0x7fffu + ((x >> 16) & 1u)) >> 16);
}

constexpr int T_ = 1024, D_ = 1024, HD_ = 64, KV_ = 512, DH_ = 4096, M_ = 2048;
#define NEGBIG (-1e30f)

// ---------------- RMSNorm (f32 in -> bf16 out) ----------------
__global__ __launch_bounds__(256) void k_rms1b(const float* __restrict__ x, const float* __restrict__ w,
                                               u16* __restrict__ outb) {
  int row = blockIdx.x, tid = threadIdx.x;
  float4 v = *(const float4*)&x[(size_t)row * D_ + tid * 4];
  float ss = v.x*v.x + v.y*v.y + v.z*v.z + v.w*v.w;
  #pragma unroll
  for (int m = 32; m >= 1; m >>= 1) ss += __shfl_xor(ss, m, 64);
  __shared__ float red[4];
  if ((tid & 63) == 0) red[tid >> 6] = ss;
  __syncthreads();
  ss = red[0] + red[1] + red[2] + red[3];
  float sc = 1.0f / sqrtf(ss * (1.0f / 1024.0f) + 1e-6f);
  float4 wv = *(const float4*)&w[tid * 4];
  ushort4 ob;
  ob.x = f2b(wv.x*v.x*sc); ob.y = f2b(wv.y*v.y*sc);
  ob.z = f2b(wv.z*v.z*sc); ob.w = f2b(wv.w*v.w*sc);
  *(ushort4*)&outb[(size_t)row * D_ + tid * 4] = ob;
}

// ---------------- RMSNorm (f32 in -> f32 out + bf16 out) ----------------
__global__ __launch_bounds__(256) void k_rms2b(const float* __restrict__ x, const float* __restrict__ w,
                                               float* __restrict__ outf, u16* __restrict__ outb) {
  int row = blockIdx.x, tid = threadIdx.x;
  float4 v = *(const float4*)&x[(size_t)row * D_ + tid * 4];
  float ss = v.x*v.x + v.y*v.y + v.z*v.z + v.w*v.w;
  #pragma unroll
  for (int m = 32; m >= 1; m >>= 1) ss += __shfl_xor(ss, m, 64);
  __shared__ float red[4];
  if ((tid & 63) == 0) red[tid >> 6] = ss;
  __syncthreads();
  ss = red[0] + red[1] + red[2] + red[3];
  float sc = 1.0f / sqrtf(ss * (1.0f / 1024.0f) + 1e-6f);
  float4 wv = *(const float4*)&w[tid * 4];
  float4 o; o.x = wv.x*v.x*sc; o.y = wv.y*v.y*sc; o.z = wv.z*v.z*sc; o.w = wv.w*v.w*sc;
  *(float4*)&outf[(size_t)row * D_ + tid * 4] = o;
  ushort4 ob; ob.x = f2b(o.x); ob.y = f2b(o.y); ob.z = f2b(o.z); ob.w = f2b(o.w);
  *(ushort4*)&outb[(size_t)row * D_ + tid * 4] = ob;
}

// ---------------- LayerNorm on latent (f32 in -> bf16 out, 512 cols) ----------------
__global__ __launch_bounds__(256) void k_lnb(const float* __restrict__ lat, const float* __restrict__ g,
                                             const float* __restrict__ bb, u16* __restrict__ ob) {
  int row = blockIdx.x, tid = threadIdx.x;
  const float* r = lat + (size_t)row * KV_;
  float v0 = r[tid], v1 = r[tid + 256];
  float s = v0 + v1;
  #pragma unroll
  for (int m = 32; m >= 1; m >>= 1) s += __shfl_xor(s, m, 64);
  __shared__ float red[4];
  if ((tid & 63) == 0) red[tid >> 6] = s;
  __syncthreads();
  float mu = (red[0] + red[1] + red[2] + red[3]) * (1.0f / 512.0f);
  __syncthreads();
  float d0 = v0 - mu, d1 = v1 - mu;
  float ss = d0*d0 + d1*d1;
  #pragma unroll
  for (int m = 32; m >= 1; m >>= 1) ss += __shfl_xor(ss, m, 64);
  if ((tid & 63) == 0) red[tid >> 6] = ss;
  __syncthreads();
  float var = (red[0] + red[1] + red[2] + red[3]) * (1.0f / 512.0f);
  float sc = 1.0f / sqrtf(var + 1e-5f);
  ob[(size_t)row * KV_ + tid]       = f2b(d0 * sc * g[tid]       + bb[tid]);
  ob[(size_t)row * KV_ + tid + 256] = f2b(d1 * sc * g[tid + 256] + bb[tid + 256]);
}

// ---------------- Small-weight conversion f32 -> bf16 (Wq,Wdkv,Wuk,Wuv,Wo only) ----------------
// float4-unit indices in concatenated dst: Wq[8388608,8650752) Wdkv[..8781824)
// Wuk[..8912896) Wuv[..9043968) Wo[..9306112)
__global__ __launch_bounds__(256) void k_cvt_small(const float* __restrict__ Wq, const float* __restrict__ Wdkv,
                                                   const float* __restrict__ Wuk, const float* __restrict__ Wuv,
                                                   const float* __restrict__ Wo, u16* __restrict__ dst) {
  for (size_t i = 8388608ull + (size_t)blockIdx.x * 256 + threadIdx.x; i < 9306112ull;
       i += (size_t)gridDim.x * 256) {
    const float* s;
    if      (i < 8650752ull) s = Wq   + (i - 8388608ull) * 4;
    else if (i < 8781824ull) s = Wdkv + (i - 8650752ull) * 4;
    else if (i < 8912896ull) s = Wuk  + (i - 8781824ull) * 4;
    else if (i < 9043968ull) s = Wuv  + (i - 8912896ull) * 4;
    else                     s = Wo   + (i - 9043968ull) * 4;
    float4 f = *(const float4*)s;
    ushort4 u; u.x = f2b(f.x); u.y = f2b(f.y); u.z = f2b(f.z); u.w = f2b(f.w);
    *(ushort4*)(dst + i * 4) = u;
  }
}

// ---------------- bf16 MFMA GEMM (templated on B dtype): C[M,N] = A_bf16 @ B[N,K]^T ----------------
template<int BF16B>
__global__ __launch_bounds__(256) void k_gemm_t(const u16* __restrict__ A, const void* __restrict__ Bp,
                                                const float* __restrict__ resid, float* __restrict__ Cf,
                                                u16* __restrict__ Cb, int N, int K) {
  int bid = blockIdx.x;
  int xcd = bid & 7, jj = bid >> 3;
  int mt = jj & 31, nt = (jj >> 5) * 8 + xcd;
  __shared__ __align__(16) u16 As[64][72];
  __shared__ __align__(16) u16 Bs[64][72];
  int tid = threadIdx.x, lane = tid & 63, wave = tid >> 6;
  int wm = (wave >> 1) * 32, wn = (wave & 1) * 32;
  int lr = tid >> 2, lc = (tid & 3) * 16;
  const u16* arow = A + (size_t)(mt * 64 + lr) * K + lc;
  const u16* browb = (const u16*)Bp + (size_t)(nt * 64 + lr) * K + lc;
  const float* browf = (const float*)Bp + (size_t)(nt * 64 + lr) * K + lc;
  floatx4 z = {0.f, 0.f, 0.f, 0.f};
  floatx4 acc00 = z, acc01 = z, acc10 = z, acc11 = z;
  int fm = lane & 15, fkq = (lane >> 4) * 8;
  uint4 ra0 = *(const uint4*)&arow[0];
  uint4 ra1 = *(const uint4*)&arow[8];
  uint4 rbA, rbB; float4 rb0, rb1, rb2, rb3;
  if constexpr (BF16B) {
    rbA = *(const uint4*)&browb[0]; rbB = *(const uint4*)&browb[8];
  } else {
    rb0 = *(const float4*)&browf[0];  rb1 = *(const float4*)&browf[4];
    rb2 = *(const float4*)&browf[8];  rb3 = *(const float4*)&browf[12];
  }
  for (int kb = 0; kb < K; kb += 64) {
    *(uint4*)&As[lr][lc]     = ra0;
    *(uint4*)&As[lr][lc + 8] = ra1;
    if constexpr (BF16B) {
      *(uint4*)&Bs[lr][lc]     = rbA;
      *(uint4*)&Bs[lr][lc + 8] = rbB;
    } else {
      ushort4 u;
      u.x = f2b(rb0.x); u.y = f2b(rb0.y); u.z = f2b(rb0.z); u.w = f2b(rb0.w); *(ushort4*)&Bs[lr][lc]      = u;
      u.x = f2b(rb1.x); u.y = f2b(rb1.y); u.z = f2b(rb1.z); u.w = f2b(rb1.w); *(ushort4*)&Bs[lr][lc + 4]  = u;
      u.x = f2b(rb2.x); u.y = f2b(rb2.y); u.z = f2b(rb2.z); u.w = f2b(rb2.w); *(ushort4*)&Bs[lr][lc + 8]  = u;
      u.x = f2b(rb3.x); u.y = f2b(rb3.y); u.z = f2b(rb3.z); u.w = f2b(rb3.w); *(ushort4*)&Bs[lr][lc + 12] = u;
    }
    __syncthreads();
    if (kb + 64 < K) {
      ra0 = *(const uint4*)&arow[kb + 64];
      ra1 = *(const uint4*)&arow[kb + 72];
      if constexpr (BF16B) {
        rbA = *(const uint4*)&browb[kb + 64]; rbB = *(const uint4*)&browb[kb + 72];
      } else {
        rb0 = *(const float4*)&browf[kb + 64]; rb1 = *(const float4*)&browf[kb + 68];
        rb2 = *(const float4*)&browf[kb + 72]; rb3 = *(const float4*)&browf[kb + 76];
      }
    }
    #pragma unroll
    for (int ks = 0; ks < 64; ks += 32) {
      shortx8 a0  = *(const shortx8*)&As[wm + fm][ks + fkq];
      shortx8 a1  = *(const shortx8*)&As[wm + 16 + fm][ks + fkq];
      shortx8 b0  = *(const shortx8*)&Bs[wn + fm][ks + fkq];
      shortx8 b1v = *(const shortx8*)&Bs[wn + 16 + fm][ks + fkq];
      acc00 = __builtin_amdgcn_mfma_f32_16x16x32_bf16(a0, b0,  acc00, 0, 0, 0);
      acc01 = __builtin_amdgcn_mfma_f32_16x16x32_bf16(a0, b1v, acc01, 0, 0, 0);
      acc10 = __builtin_amdgcn_mfma_f32_16x16x32_bf16(a1, b0,  acc10, 0, 0, 0);
      acc11 = __builtin_amdgcn_mfma_f32_16x16x32_bf16(a1, b1v, acc11, 0, 0, 0);
    }
    __syncthreads();
  }
  int q4 = (lane >> 4) * 4, cix = lane & 15;
  #pragma unroll
  for (int im = 0; im < 2; ++im) {
    #pragma unroll
    for (int rg = 0; rg < 4; ++rg) {
      int row = mt * 64 + wm + im * 16 + q4 + rg;
      #pragma unroll
      for (int in = 0; in < 2; ++in) {
        int gn = nt * 64 + wn + in * 16 + cix;
        float vv = (im == 0 ? (in == 0 ? acc00[rg] : acc01[rg]) : (in == 0 ? acc10[rg] : acc11[rg]));
        size_t idx = (size_t)row * N + gn;
        if (Cb) {
          Cb[idx] = f2b(vv);
        } else {
          if (resid) vv += resid[idx];
          Cf[idx] = vv;
        }
      }
    }
  }
}

// ---------------- RoPE: f32 q,k in -> bf16 qb (pre-scaled 1/8), kb out ----------------
__global__ __launch_bounds__(256) void k_rope2b(const float* __restrict__ q, const float* __restrict__ k,
                                                u16* __restrict__ qb, u16* __restrict__ kb) {
  int g = blockIdx.x * 256 + threadIdx.x;
  int j = g & 31;
  int h = (g >> 5) & 15;
  int row = g >> 9;
  int t = row & (T_ - 1);
  float p = (float)pow(10000.0, (double)j * (1.0 / 32.0));
  float ang = (float)t / p;
  float sn, cs; sincosf(ang, &sn, &cs);
  size_t base = (size_t)row * D_ + h * 64 + j;
  float x1 = q[base], x2 = q[base + 32];
  qb[base]      = f2b((x1 * cs - x2 * sn) * 0.125f);
  qb[base + 32] = f2b((x1 * sn + x2 * cs) * 0.125f);
  x1 = k[base]; x2 = k[base + 32];
  kb[base]      = f2b(x1 * cs - x2 * sn);
  kb[base + 32] = f2b(x1 * sn + x2 * cs);
}

// ---------------- Flash attention (wave-owns-16-rows) + fused W1/W2 bf16 conversion ----------------
// 1D grid: blocks [0,512) = attention (idx=gid&31 -> [qt x b], h=gid>>5);
// blocks [512,512+ncvt) = grid-stride converter over W1+W2 (8388608 float4 units).
// Converter output (W1b/W2b) is consumed by k_moe1 3 kernels later; the attention blocks
// dispatch first so the sync-bound attention path overlaps the HBM-bound conversion.
__global__ __launch_bounds__(256) void k_fattn(const u16* __restrict__ qbp, const u16* __restrict__ kbp,
                                               const u16* __restrict__ vbp, u16* __restrict__ ob,
                                               const float* __restrict__ W1c, const float* __restrict__ W2c,
                                               u16* __restrict__ wdst, int ncvt) {
  int gid = blockIdx.x;
  if (gid >= 512) {
    size_t start = (size_t)(gid - 512) * 256 + threadIdx.x;
    size_t stride = (size_t)ncvt * 256;
    for (size_t i = start; i < 8388608ull; i += stride) {
      const float* s = (i < 4194304ull) ? W1c + i * 4 : W2c + (i - 4194304ull) * 4;
      float4 f = *(const float4*)s;
      ushort4 u; u.x = f2b(f.x); u.y = f2b(f.y); u.z = f2b(f.z); u.w = f2b(f.w);
      *(ushort4*)(wdst + i * 4) = u;
    }
    return;
  }
  int idx = gid & 31, h = gid >> 5;
  int b = idx >> 4;
  int qt = idx & 15;
  if (b) qt = 15 - qt;  // complementary pairing: co-resident pair sums to 17 k-tiles
  __shared__ __align__(16) u16 Qs[64][72];   // [q][d] bf16, pre-scaled 1/8
  __shared__ __align__(16) u16 Ks[64][72];   // [k][d]
  __shared__ __align__(16) u16 Vs[64][72];   // [d][k] transposed (B-operand for PV)
  __shared__ __align__(16) u16 Ps[64][72];   // [q][k] bf16 (A-operand for PV; rows wave-private)
  int tid = threadIdx.x, lane = tid & 63, wave = tid >> 6;
  int fm = lane & 15, fkq = (lane >> 4) * 8;
  int q4 = (lane >> 4) * 4, cix = lane & 15;
  int w16 = wave * 16;
  size_t rowbase = (size_t)b * T_;
  int colbase = h * HD_;
  int q0 = qt * 64;
  int lr = tid >> 2, ld = (tid & 3) * 16;
  {
    const u16* qr = qbp + (rowbase + q0 + lr) * D_ + colbase + ld;
    *(uint4*)&Qs[lr][ld]     = *(const uint4*)&qr[0];
    *(uint4*)&Qs[lr][ld + 8] = *(const uint4*)&qr[8];
  }
  floatx4 z = {0.f, 0.f, 0.f, 0.f};
  floatx4 s[4], o[4];
  o[0] = z; o[1] = z; o[2] = z; o[3] = z;
  float m[4], l[4];
  #pragma unroll
  for (int rg = 0; rg < 4; ++rg) { m[rg] = NEGBIG; l[rg] = 0.f; }
  // register prefetch of K/V tile 0
  const u16* kr = kbp + (rowbase + lr) * D_ + colbase + ld;
  const u16* vr = vbp + (rowbase + lr) * D_ + colbase + ld;
  uint4 rk0 = *(const uint4*)&kr[0], rk1 = *(const uint4*)&kr[8];
  uint4 rv0 = *(const uint4*)&vr[0], rv1 = *(const uint4*)&vr[8];
  for (int kt = 0; kt <= qt; ++kt) {
    __syncthreads();  // prev tile's Ks/Vs reads done (also covers Q staging on iter 0)
    *(uint4*)&Ks[lr][ld]     = rk0;
    *(uint4*)&Ks[lr][ld + 8] = rk1;
    {
      union { uint4 v4[2]; u16 e[16]; } vv;
      vv.v4[0] = rv0; vv.v4[1] = rv1;
      #pragma unroll
      for (int c = 0; c < 16; ++c) Vs[ld + c][lr] = vv.e[c];
    }
    __syncthreads();  // staging visible
    if (kt < qt) {    // prefetch next tile; latency hides under S/softmax/PV below
      kr += 64 * D_; vr += 64 * D_;
      rk0 = *(const uint4*)&kr[0]; rk1 = *(const uint4*)&kr[8];
      rv0 = *(const uint4*)&vr[0]; rv1 = *(const uint4*)&vr[8];
    }
    s[0] = z; s[1] = z; s[2] = z; s[3] = z;
    #pragma unroll
    for (int ks = 0; ks < 64; ks += 32) {
      shortx8 a = *(const shortx8*)&Qs[w16 + fm][ks + fkq];
      #pragma unroll
      for (int nb = 0; nb < 4; ++nb) {
        shortx8 bb = *(const shortx8*)&Ks[nb * 16 + fm][ks + fkq];
        s[nb] = __builtin_amdgcn_mfma_f32_16x16x32_bf16(a, bb, s[nb], 0, 0, 0);
      }
    }
    if (kt == qt) {  // diagonal tile: local causal mask (row = w16+q4+rg, col = nb*16+cix)
      #pragma unroll
      for (int nb = 0; nb < 4; ++nb)
        #pragma unroll
        for (int rg = 0; rg < 4; ++rg)
          if (nb * 16 + cix > w16 + q4 + rg) s[nb][rg] = NEGBIG;
    }
    #pragma unroll
    for (int rg = 0; rg < 4; ++rg) {
      float mx = fmaxf(fmaxf(s[0][rg], s[1][rg]), fmaxf(s[2][rg], s[3][rg]));
      #pragma unroll
      for (int mk = 8; mk >= 1; mk >>= 1) mx = fmaxf(mx, __shfl_xor(mx, mk, 64));
      float mn = fmaxf(m[rg], mx);
      float f = __expf(m[rg] - mn);
      m[rg] = mn;
      float p0 = __expf(s[0][rg] - mn);
      float p1 = __expf(s[1][rg] - mn);
      float p2 = __expf(s[2][rg] - mn);
      float p3 = __expf(s[3][rg] - mn);
      float rs = (p0 + p1) + (p2 + p3);
      #pragma unroll
      for (int mk = 8; mk >= 1; mk >>= 1) rs += __shfl_xor(rs, mk, 64);
      l[rg] = l[rg] * f + rs;
      o[0][rg] *= f; o[1][rg] *= f; o[2][rg] *= f; o[3][rg] *= f;
      int prow = w16 + q4 + rg;
      Ps[prow][cix]      = f2b(p0);
      Ps[prow][16 + cix] = f2b(p1);
      Ps[prow][32 + cix] = f2b(p2);
      Ps[prow][48 + cix] = f2b(p3);
    }
    // PV: A = own Ps rows (wave-private -> no barrier), B = Vs
    #pragma unroll
    for (int ks = 0; ks < 64; ks += 32) {
      shortx8 a = *(const shortx8*)&Ps[w16 + fm][ks + fkq];
      #pragma unroll
      for (int db = 0; db < 4; ++db) {
        shortx8 bb = *(const shortx8*)&Vs[db * 16 + fm][ks + fkq];
        o[db] = __builtin_amdgcn_mfma_f32_16x16x32_bf16(a, bb, o[db], 0, 0, 0);
      }
    }
  }
  #pragma unroll
  for (int rg = 0; rg < 4; ++rg) {
    float inv = 1.0f / l[rg];
    size_t base = (rowbase + q0 + w16 + q4 + rg) * D_ + colbase;
    #pragma unroll
    for (int db = 0; db < 4; ++db)
      ob[base + db * 16 + cix] = f2b(o[db][rg] * inv);
  }
}

// ---------------- MoE gate ----------------
__global__ __launch_bounds__(256) void k_init(int* cnt) { if (threadIdx.x < 4) cnt[threadIdx.x] = 0; }

__global__ __launch_bounds__(256) void k_gate(const float* __restrict__ h2, const float* __restrict__ gw,
                                              const float* __restrict__ gb, int* __restrict__ expert,
                                              int* __restrict__ cnt) {
  int wid = threadIdx.x >> 6, lane = threadIdx.x & 63;
  int t = blockIdx.x * 4 + wid;
  const float* hr = h2 + (size_t)t * D_;
  float a0 = 0, a1 = 0, a2 = 0, a3 = 0;
  for (int c = lane; c < D_; c += 64) {
    float xv = hr[c];
    a0 += xv * gw[c];
    a1 += xv * gw[D_ + c];
    a2 += xv * gw[2 * D_ + c];
    a3 += xv * gw[3 * D_ + c];
  }
  #pragma unroll
  for (int m = 32; m >= 1; m >>= 1) {
    a0 += __shfl_xor(a0, m, 64); a1 += __shfl_xor(a1, m, 64);
    a2 += __shfl_xor(a2, m, 64); a3 += __shfl_xor(a3, m, 64);
  }
  if (lane == 0) {
    float l0 = a0 + gb[0], l1 = a1 + gb[1], l2 = a2 + gb[2], l3 = a3 + gb[3];
    int best = 0; float bv = l0;
    if (l1 > bv) { bv = l1; best = 1; }
    if (l2 > bv) { bv = l2; best = 2; }
    if (l3 > bv) { bv = l3; best = 3; }
    expert[t] = best;
    atomicAdd(&cnt[best], 1);
  }
}

__global__ __launch_bounds__(256) void k_scatter(const int* __restrict__ expert, const int* __restrict__ cnt,
                                                 int* __restrict__ off, int* __restrict__ sorted) {
  __shared__ int cur[4];
  if (threadIdx.x == 0) {
    int o0 = 0, o1 = cnt[0], o2 = o1 + cnt[1], o3 = o2 + cnt[2];
    off[0] = o0; off[1] = o1; off[2] = o2; off[3] = o3;
    cur[0] = o0; cur[1] = o1; cur[2] = o2; cur[3] = o3;
  }
  __syncthreads();
  for (int t = threadIdx.x; t < M_; t += 256) {
    int e = expert[t];
    int p = atomicAdd(&cur[e], 1);
    sorted[p] = t;
  }
}

// ---------------- MoE MFMA GEMM 1 (templated B): hbuf = bf16(relu(A[gather] @ W1[e]^T + b1[e])) ----------------
template<int BF16B>
__global__ __launch_bounds__(256) void k_moe1_t(const u16* __restrict__ A, const void* __restrict__ W1p,
                                                const float* __restrict__ b1, const int* __restrict__ cnt,
                                                const int* __restrict__ off, const int* __restrict__ sorted,
                                                u16* __restrict__ hbuf) {
  int bid = blockIdx.x;
  int xcd = bid & 7, jj = bid >> 3;
  int mt = jj & 31, combo = (jj >> 5) * 8 + xcd;   // combo in [0,256)
  int e = combo >> 6, nt = combo & 63;
  int rem = cnt[e] - mt * 64;
  if (rem <= 0) return;
  __shared__ __align__(16) u16 As[64][72];
  __shared__ __align__(16) u16 Bs[64][72];
  int tid = threadIdx.x, lane = tid & 63, wave = tid >> 6;
  int wm = (wave >> 1) * 32, wn = (wave & 1) * 32;
  int lr = tid >> 2, lc = (tid & 3) * 16;
  int rr = lr < rem ? lr : rem - 1;
  const u16* arow = A + (size_t)sorted[off[e] + mt * 64 + rr] * D_ + lc;
  const u16* browb = (const u16*)W1p + (size_t)e * DH_ * D_ + (size_t)(nt * 64 + lr) * D_ + lc;
  const float* browf = (const float*)W1p + (size_t)e * DH_ * D_ + (size_t)(nt * 64 + lr) * D_ + lc;
  floatx4 z = {0.f, 0.f, 0.f, 0.f};
  floatx4 acc00 = z, acc01 = z, acc10 = z, acc11 = z;
  int fm = lane & 15, fkq = (lane >> 4) * 8;
  uint4 ra0 = *(const uint4*)&arow[0];
  uint4 ra1 = *(const uint4*)&arow[8];
  uint4 rbA, rbB; float4 rb0, rb1, rb2, rb3;
  if constexpr (BF16B) {
    rbA = *(const uint4*)&browb[0]; rbB = *(const uint4*)&browb[8];
  } else {
    rb0 = *(const float4*)&browf[0];  rb1 = *(const float4*)&browf[4];
    rb2 = *(const float4*)&browf[8];  rb3 = *(const float4*)&browf[12];
  }
  for (int kb = 0; kb < D_; kb += 64) {
    *(uint4*)&As[lr][lc]     = ra0;
    *(uint4*)&As[lr][lc + 8] = ra1;
    if constexpr (BF16B) {
      *(uint4*)&Bs[lr][lc]     = rbA;
      *(uint4*)&Bs[lr][lc + 8] = rbB;
    } else {
      ushort4 u;
      u.x = f2b(rb0.x); u.y = f2b(rb0.y); u.z = f2b(rb0.z); u.w = f2b(rb0.w); *(ushort4*)&Bs[lr][lc]      = u;
      u.x = f2b(rb1.x); u.y = f2b(rb1.y); u.z = f2b(rb1.z); u.w = f2b(rb1.w); *(ushort4*)&Bs[lr][lc + 4]  = u;
      u.x = f2b(rb2.x); u.y = f2b(rb2.y); u.z = f2b(rb2.z); u.w = f2b(rb2.w); *(ushort4*)&Bs[lr][lc + 8]  = u;
      u.x = f2b(rb3.x); u.y = f2b(rb3.y); u.z = f2b(rb3.z); u.w = f2b(rb3.w); *(ushort4*)&Bs[lr][lc + 12] = u;
    }
    __syncthreads();
    if (kb + 64 < D_) {
      ra0 = *(const uint4*)&arow[kb + 64];
      ra1 = *(const uint4*)&arow[kb + 72];
      if constexpr (BF16B) {
        rbA = *(const uint4*)&browb[kb + 64]; rbB = *(const uint4*)&browb[kb + 72];
      } else {
        rb0 = *(const float4*)&browf[kb + 64]; rb1 = *(const float4*)&browf[kb + 68];
        rb2 = *(const float4*)&browf[kb + 72]; rb3 = *(const float4*)&browf[kb + 76];
      }
    }
    #pragma unroll
    for (int ks = 0; ks < 64; ks += 32) {
      shortx8 a0  = *(const shortx8*)&As[wm + fm][ks + fkq];
      shortx8 a1  = *(const shortx8*)&As[wm + 16 + fm][ks + fkq];
      shortx8 b0  = *(const shortx8*)&Bs[wn + fm][ks + fkq];
      shortx8 b1v = *(const shortx8*)&Bs[wn + 16 + fm][ks + fkq];
      acc00 = __builtin_amdgcn_mfma_f32_16x16x32_bf16(a0, b0,  acc00, 0, 0, 0);
      acc01 = __builtin_amdgcn_mfma_f32_16x16x32_bf16(a0, b1v, acc01, 0, 0, 0);
      acc10 = __builtin_amdgcn_mfma_f32_16x16x32_bf16(a1, b0,  acc10, 0, 0, 0);
      acc11 = __builtin_amdgcn_mfma_f32_16x16x32_bf16(a1, b1v, acc11, 0, 0, 0);
    }
    __syncthreads();
  }
  int q4 = (lane >> 4) * 4, cix = lane & 15;
  #pragma unroll
  for (int im = 0; im < 2; ++im) {
    #pragma unroll
    for (int rg = 0; rg < 4; ++rg) {
      int ml = wm + im * 16 + q4 + rg;
      if (ml >= rem) continue;
      size_t grow = (size_t)(off[e] + mt * 64 + ml);
      #pragma unroll
      for (int in = 0; in < 2; ++in) {
        int gn = nt * 64 + wn + in * 16 + cix;
        float vv = (im == 0 ? (in == 0 ? acc00[rg] : acc01[rg]) : (in == 0 ? acc10[rg] : acc11[rg]));
        vv += b1[e * DH_ + gn];
        hbuf[grow * DH_ + gn] = f2b(fmaxf(vv, 0.f));
      }
    }
  }
}

// ---------------- MoE MFMA GEMM 2 (unsplit, small-ws fallback) ----------------
template<int BF16B>
__global__ __launch_bounds__(256) void k_moe2_t(const u16* __restrict__ hbuf, const void* __restrict__ W2p,
                                                const float* __restrict__ b2w, const float* __restrict__ x1f,
                                                const int* __restrict__ cnt, const int* __restrict__ off,
                                                const int* __restrict__ sorted, float* __restrict__ out) {
  int bid = blockIdx.x;
  int xcd = bid & 7, jj = bid >> 3;
  int mt = jj & 31, combo = (jj >> 5) * 8 + xcd;   // combo in [0,64)
  int e = combo >> 4, nt = combo & 15;
  int rem = cnt[e] - mt * 64;
  if (rem <= 0) return;
  __shared__ __align__(16) u16 As[64][72];
  __shared__ __align__(16) u16 Bs[64][72];
  int tid = threadIdx.x, lane = tid & 63, wave = tid >> 6;
  int wm = (wave >> 1) * 32, wn = (wave & 1) * 32;
  int lr = tid >> 2, lc = (tid & 3) * 16;
  int rr = lr < rem ? lr : rem - 1;
  const u16* arow = hbuf + (size_t)(off[e] + mt * 64 + rr) * DH_ + lc;
  const u16* browb = (const u16*)W2p + (size_t)e * D_ * DH_ + (size_t)(nt * 64 + lr) * DH_ + lc;
  const float* browf = (const float*)W2p + (size_t)e * D_ * DH_ + (size_t)(nt * 64 + lr) * DH_ + lc;
  floatx4 z = {0.f, 0.f, 0.f, 0.f};
  floatx4 acc00 = z, acc01 = z, acc10 = z, acc11 = z;
  int fm = lane & 15, fkq = (lane >> 4) * 8;
  uint4 ra0 = *(const uint4*)&arow[0];
  uint4 ra1 = *(const uint4*)&arow[8];
  uint4 rbA, rbB; float4 rb0, rb1, rb2, rb3;
  if constexpr (BF16B) {
    rbA = *(const uint4*)&browb[0]; rbB = *(const uint4*)&browb[8];
  } else {
    rb0 = *(const float4*)&browf[0];  rb1 = *(const float4*)&browf[4];
    rb2 = *(const float4*)&browf[8];  rb3 = *(const float4*)&browf[12];
  }
  for (int kb = 0; kb < DH_; kb += 64) {
    *(uint4*)&As[lr][lc]     = ra0;
    *(uint4*)&As[lr][lc + 8] = ra1;
    if constexpr (BF16B) {
      *(uint4*)&Bs[lr][lc]     = rbA;
      *(uint4*)&Bs[lr][lc + 8] = rbB;
    } else {
      ushort4 u;
      u.x = f2b(rb0.x); u.y = f2b(rb0.y); u.z = f2b(rb0.z); u.w = f2b(rb0.w); *(ushort4*)&Bs[lr][lc]      = u;
      u.x = f2b(rb1.x); u.y = f2b(rb1.y); u.z = f2b(rb1.z); u.w = f2b(rb1.w); *(ushort4*)&Bs[lr][lc + 4]  = u;
      u.x = f2b(rb2.x); u.y = f2b(rb2.y); u.z = f2b(rb2.z); u.w = f2b(rb2.w); *(ushort4*)&Bs[lr][lc + 8]  = u;
      u.x = f2b(rb3.x); u.y = f2b(rb3.y); u.z = f2b(rb3.z); u.w = f2b(rb3.w); *(ushort4*)&Bs[lr][lc + 12] = u;
    }
    __syncthreads();
    if (kb + 64 < DH_) {
      ra0 = *(const uint4*)&arow[kb + 64];
      ra1 = *(const uint4*)&arow[kb + 72];
      if constexpr (BF16B) {
        rbA = *(const uint4*)&browb[kb + 64]; rbB = *(const uint4*)&browb[kb + 72];
      } else {
        rb0 = *(const float4*)&browf[kb + 64]; rb1 = *(const float4*)&browf[kb + 68];
        rb2 = *(const float4*)&browf[kb + 72]; rb3 = *(const float4*)&browf[kb + 76];
      }
    }
    #pragma unroll
    for (int ks = 0; ks < 64; ks += 32) {
      shortx8 a0  = *(const shortx8*)&As[wm + fm][ks + fkq];
      shortx8 a1  = *(const shortx8*)&As[wm + 16 + fm][ks + fkq];
      shortx8 b0  = *(const shortx8*)&Bs[wn + fm][ks + fkq];
      shortx8 b1v = *(const shortx8*)&Bs[wn + 16 + fm][ks + fkq];
      acc00 = __builtin_amdgcn_mfma_f32_16x16x32_bf16(a0, b0,  acc00, 0, 0, 0);
      acc01 = __builtin_amdgcn_mfma_f32_16x16x32_bf16(a0, b1v, acc01, 0, 0, 0);
      acc10 = __builtin_amdgcn_mfma_f32_16x16x32_bf16(a1, b0,  acc10, 0, 0, 0);
      acc11 = __builtin_amdgcn_mfma_f32_16x16x32_bf16(a1, b1v, acc11, 0, 0, 0);
    }
    __syncthreads();
  }
  int q4 = (lane >> 4) * 4, cix = lane & 15;
  #pragma unroll
  for (int im = 0; im < 2; ++im) {
    #pragma unroll
    for (int rg = 0; rg < 4; ++rg) {
      int ml = wm + im * 16 + q4 + rg;
      if (ml >= rem) continue;
      int tok = sorted[off[e] + mt * 64 + ml];
      #pragma unroll
      for (int in = 0; in < 2; ++in) {
        int gn = nt * 64 + wn + in * 16 + cix;
        float vv = (im == 0 ? (in == 0 ? acc00[rg] : acc01[rg]) : (in == 0 ? acc10[rg] : acc11[rg]));
        out[(size_t)tok * D_ + gn] = vv + b2w[e * D_ + gn] + x1f[(size_t)tok * D_ + gn];
      }
    }
  }
}

// ---------------- MoE GEMM 2, K-split 2: pbuf[ks] = hbuf @ W2[e][:, ks*2048:(ks+1)*2048]^T ----------------
__global__ __launch_bounds__(256) void k_moe2s(const u16* __restrict__ hbuf, const u16* __restrict__ W2b,
                                               const int* __restrict__ cnt, const int* __restrict__ off,
                                               float* __restrict__ pbuf) {
  int bid = blockIdx.x;
  int xcd = bid & 7, jj = bid >> 3;
  int mt = jj & 31;
  int combo = (jj >> 5) * 8 + xcd;
  int ks = combo & 1, ec = combo >> 1;
  int e = ec >> 4, nt = ec & 15;
  int rem = cnt[e] - mt * 64;
  if (rem <= 0) return;
  const int KS = DH_ / 2;
  int k0 = ks * KS;
  __shared__ __align__(16) u16 As[64][72];
  __shared__ __align__(16) u16 Bs[64][72];
  int tid = threadIdx.x, lane = tid & 63, wave = tid >> 6;
  int wm = (wave >> 1) * 32, wn = (wave & 1) * 32;
  int lr = tid >> 2, lc = (tid & 3) * 16;
  int rr = lr < rem ? lr : rem - 1;
  const u16* arow = hbuf + (size_t)(off[e] + mt * 64 + rr) * DH_ + k0 + lc;
  const u16* brow = W2b + (size_t)e * D_ * DH_ + (size_t)(nt * 64 + lr) * DH_ + k0 + lc;
  floatx4 z = {0.f, 0.f, 0.f, 0.f};
  floatx4 acc00 = z, acc01 = z, acc10 = z, acc11 = z;
  int fm = lane & 15, fkq = (lane >> 4) * 8;
  uint4 ra0 = *(const uint4*)&arow[0];
  uint4 ra1 = *(const uint4*)&arow[8];
  uint4 rbA = *(const uint4*)&brow[0];
  uint4 rbB = *(const uint4*)&brow[8];
  for (int kb = 0; kb < KS; kb += 64) {
    *(uint4*)&As[lr][lc]     = ra0;
    *(uint4*)&As[lr][lc + 8] = ra1;
    *(uint4*)&Bs[lr][lc]     = rbA;
    *(uint4*)&Bs[lr][lc + 8] = rbB;
    __syncthreads();
    if (kb + 64 < KS) {
      ra0 = *(const uint4*)&arow[kb + 64];
      ra1 = *(const uint4*)&arow[kb + 72];
      rbA = *(const uint4*)&brow[kb + 64];
      rbB = *(const uint4*)&brow[kb + 72];
    }
    #pragma unroll
    for (int kk = 0; kk < 64; kk += 32) {
      shortx8 a0  = *(const shortx8*)&As[wm + fm][kk + fkq];
      shortx8 a1  = *(const shortx8*)&As[wm + 16 + fm][kk + fkq];
      shortx8 b0  = *(const shortx8*)&Bs[wn + fm][kk + fkq];
      shortx8 b1v = *(const shortx8*)&Bs[wn + 16 + fm][kk + fkq];
      acc00 = __builtin_amdgcn_mfma_f32_16x16x32_bf16(a0, b0,  acc00, 0, 0, 0);
      acc01 = __builtin_amdgcn_mfma_f32_16x16x32_bf16(a0, b1v, acc01, 0, 0, 0);
      acc10 = __builtin_amdgcn_mfma_f32_16x16x32_bf16(a1, b0,  acc10, 0, 0, 0);
      acc11 = __builtin_amdgcn_mfma_f32_16x16x32_bf16(a1, b1v, acc11, 0, 0, 0);
    }
    __syncthreads();
  }
  float* pb = pbuf + (size_t)ks * M_ * D_;
  int q4 = (lane >> 4) * 4, cix = lane & 15;
  #pragma unroll
  for (int im = 0; im < 2; ++im) {
    #pragma unroll
    for (int rg = 0; rg < 4; ++rg) {
      int ml = wm + im * 16 + q4 + rg;
      if (ml >= rem) continue;
      size_t srow = (size_t)(off[e] + mt * 64 + ml);
      #pragma unroll
      for (int in = 0; in < 2; ++in) {
        int gn = nt * 64 + wn + in * 16 + cix;
        float vv = (im == 0 ? (in == 0 ? acc00[rg] : acc01[rg]) : (in == 0 ? acc10[rg] : acc11[rg]));
        pb[srow * D_ + gn] = vv;
      }
    }
  }
}

// ---------------- MoE reduce: out[tok] = pbuf0[r] + pbuf1[r] + b2[e] + x1f[tok] ----------------
__global__ __launch_bounds__(256) void k_moered(const float* __restrict__ pbuf, const float* __restrict__ b2w,
                                                const float* __restrict__ x1f, const int* __restrict__ off,
                                                const int* __restrict__ sorted, float* __restrict__ out) {
  int r = blockIdx.x, tid = threadIdx.x;
  int tok = sorted[r];
  int e = (r >= off[3]) ? 3 : (r >= off[2]) ? 2 : (r >= off[1]) ? 1 : 0;
  size_t c = (size_t)tid * 4;
  float4 a = *(const float4*)&pbuf[(size_t)r * D_ + c];
  float4 b = *(const float4*)&pbuf[(size_t)M_ * D_ + (size_t)r * D_ + c];
  float4 bb = *(const float4*)&b2w[(size_t)e * D_ + c];
  float4 xr = *(const float4*)&x1f[(size_t)tok * D_ + c];
  float4 o;
  o.x = a.x + b.x + bb.x + xr.x;
  o.y = a.y + b.y + bb.y + xr.y;
  o.z = a.z + b.z + bb.z + xr.z;
  o.w = a.w + b.w + bb.w + xr.w;
  *(float4*)&out[(size_t)tok * D_ + c] = o;
}

extern "C" void kernel_launch(void* const* d_in, const int* in_sizes, int n_in,
                              void* d_out, int out_size, void* d_ws, size_t ws_size,
                              hipStream_t stream) {
  int map[16];
  for (int i = 0; i < 16; ++i) map[i] = i;
  if (n_in == 16 && in_sizes[0] == 16777216) {
    const int mm[16] = {15, 13, 14, 4, 2, 5, 6, 3, 12, 11, 10, 9, 0, 7, 1, 8};
    for (int i = 0; i < 16; ++i) map[i] = mm[i];
  } else if (n_in == 16 && in_sizes[0] == 4096) {
    for (int i = 0; i < 16; ++i) map[i] = 15 - i;
  }
  const float* x    = (const float*)d_in[map[0]];
  const float* n1w  = (const float*)d_in[map[1]];
  const float* n2w  = (const float*)d_in[map[2]];
  const float* Wq   = (const float*)d_in[map[3]];
  const float* Wdkv = (const float*)d_in[map[4]];
  const float* Wuk  = (const float*)d_in[map[5]];
  const float* Wuv  = (const float*)d_in[map[6]];
  const float* Wo   = (const float*)d_in[map[7]];
  const float* lng  = (const float*)d_in[map[8]];
  const float* lnb  = (const float*)d_in[map[9]];
  const float* gw   = (const float*)d_in[map[10]];
  const float* gb   = (const float*)d_in[map[11]];
  const float* W1   = (const float*)d_in[map[12]];
  const float* b1   = (const float*)d_in[map[13]];
  const float* W2   = (const float*)d_in[map[14]];
  const float* b2w  = (const float*)d_in[map[15]];
  float* out = (float*)d_out;
  char* ws = (char*)d_ws;
  const size_t MB = 1ull << 20;
  // Activation overlay [0,36) MB (unchanged from round 7):
  //  [0,8)  : qf f32 (Wq -> rope)                 -> x1f f32 (Wo out; residual, live to end)
  //  [8,16) : kf f32 (Wuk -> rope)                -> hbuf.lo bf16 (moe1 -> moe2s)
  //  [16,20): latf f32 (Wdkv -> ln)               -> qb bf16 (rope -> fattn)      -> hbuf.mid
  //  [20,24): h1b bf16 (rms1 -> Wq,Wdkv)          -> kb bf16 (rope -> fattn)      -> hbuf.hi
  //  [24,26): latb bf16 (ln -> Wuk,Wuv)           \
  //  [26,30): vb bf16 (Wuv -> fattn)               } -> h2f f32 [24,32) (rms2 -> gate)
  //  [30,34): ab bf16 (fattn -> Wo)               /
  //  [32,36): h2b bf16 (rms2 -> moe1)
  // Big path: bf16 weights [36,107); pbuf[2][2048][1024] f32 [24,40) over dead h2f/h2b/W1b-head.
  // W1b/W2b written by converter blocks fused into the fattn launch (fattn reads/writes only
  // [16,34) — disjoint from wb [36,107); moe1 runs 3 kernels later, same-stream ordering).
  float* qf   = (float*)(ws + 0);
  float* x1f  = (float*)(ws + 0);
  float* kf   = (float*)(ws + 8 * MB);
  u16*   hbuf = (u16*)(ws + 8 * MB);       // 16MB: [8,24)
  float* latf = (float*)(ws + 16 * MB);
  u16*   qb   = (u16*)(ws + 16 * MB);
  u16*   h1b  = (u16*)(ws + 20 * MB);
  u16*   kb   = (u16*)(ws + 20 * MB);
  u16*   latb = (u16*)(ws + 24 * MB);
  float* h2f  = (float*)(ws + 24 * MB);
  u16*   vb   = (u16*)(ws + 26 * MB);
  u16*   ab   = (u16*)(ws + 30 * MB);
  u16*   h2b  = (u16*)(ws + 32 * MB);
  float* pbuf = (float*)(ws + 24 * MB);    // 16MB: [24,40), big path only

  bool big = ws_size >= (107ull * MB + (64ull << 10));
  u16* wb = (u16*)(ws + 36 * MB);
  u16* W1b   = wb;
  u16* W2b   = wb + 16777216;
  u16* Wqb   = wb + 33554432;
  u16* Wdkvb = wb + 34603008;
  u16* Wukb  = wb + 35127296;
  u16* Wuvb  = wb + 35651584;
  u16* Wob   = wb + 36175872;
  int* cnt    = (int*)(ws + (big ? 107 * MB : 36 * MB));
  int* off    = cnt + 8;
  int* expert = cnt + 16;
  int* sorted = expert + 2048;

  if (big) {
    k_cvt_small<<<1024, 256, 0, stream>>>(Wq, Wdkv, Wuk, Wuv, Wo, wb);
    k_rms1b<<<2048, 256, 0, stream>>>(x, n1w, h1b);
    k_gemm_t<1><<<512, 256, 0, stream>>>(h1b, Wqb, nullptr, qf, nullptr, 1024, 1024);
    k_gemm_t<1><<<256, 256, 0, stream>>>(h1b, Wdkvb, nullptr, latf, nullptr, 512, 1024);
    k_lnb<<<2048, 256, 0, stream>>>(latf, lng, lnb, latb);
    k_gemm_t<1><<<512, 256, 0, stream>>>(latb, Wukb, nullptr, kf, nullptr, 1024, 512);
    k_gemm_t<1><<<512, 256, 0, stream>>>(latb, Wuvb, nullptr, nullptr, vb, 1024, 512);
    k_rope2b<<<4096, 256, 0, stream>>>(qf, kf, qb, kb);
    k_fattn<<<1024, 256, 0, stream>>>(qb, kb, vb, ab, W1, W2, wb, 512);  // 512 attn + 512 cvt blocks
    k_gemm_t<1><<<512, 256, 0, stream>>>(ab, Wob, x, x1f, nullptr, 1024, 1024);
    k_rms2b<<<2048, 256, 0, stream>>>(x1f, n2w, h2f, h2b);
    k_init<<<1, 64, 0, stream>>>(cnt);
    k_gate<<<512, 256, 0, stream>>>(h2f, gw, gb, expert, cnt);
    k_scatter<<<1, 256, 0, stream>>>(expert, cnt, off, sorted);
    k_moe1_t<1><<<8192, 256, 0, stream>>>(h2b, W1b, b1, cnt, off, sorted, hbuf);
    k_moe2s<<<4096, 256, 0, stream>>>(hbuf, W2b, cnt, off, pbuf);
    k_moered<<<2048, 256, 0, stream>>>(pbuf, b2w, x1f, off, sorted, out);
  } else {
    k_rms1b<<<2048, 256, 0, stream>>>(x, n1w, h1b);
    k_gemm_t<0><<<512, 256, 0, stream>>>(h1b, Wq, nullptr, qf, nullptr, 1024, 1024);
    k_gemm_t<0><<<256, 256, 0, stream>>>(h1b, Wdkv, nullptr, latf, nullptr, 512, 1024);
    k_lnb<<<2048, 256, 0, stream>>>(latf, lng, lnb, latb);
    k_gemm_t<0><<<512, 256, 0, stream>>>(latb, Wuk, nullptr, kf, nullptr, 1024, 512);
    k_gemm_t<0><<<512, 256, 0, stream>>>(latb, Wuv, nullptr, nullptr, vb, 1024, 512);
    k_rope2b<<<4096, 256, 0, stream>>>(qf, kf, qb, kb);
    k_fattn<<<512, 256, 0, stream>>>(qb, kb, vb, ab, nullptr, nullptr, nullptr, 0);
    k_gemm_t<0><<<512, 256, 0, stream>>>(ab, Wo, x, x1f, nullptr, 1024, 1024);
    k_rms2b<<<2048, 256, 0, stream>>>(x1f, n2w, h2f, h2b);
    k_init<<<1, 64, 0, stream>>>(cnt);
    k_gate<<<512, 256, 0, stream>>>(h2f, gw, gb, expert, cnt);
    k_scatter<<<1, 256, 0, stream>>>(expert, cnt, off, sorted);
    k_moe1_t<0><<<8192, 256, 0, stream>>>(h2b, W1, b1, cnt, off, sorted, hbuf);
    k_moe2_t<0><<<2048, 256, 0, stream>>>(hbuf, W2, b2w, x1f, cnt, off, sorted, out);
  }
}